// Round 10
// baseline (310.682 us; speedup 1.0000x reference)
//
#include <hip/hip_runtime.h>
#include <cstddef>

// Problem constants (from reference)
#define QN 10000
#define DD 64
#define MM 50
#define BB 64
#define TT 512
#define WPAD 52   // padded w row stride in floats (208 B -> 16B-aligned rows)

// Pin a float array in VGPRs (k3 only; proven -17us there in R9).
#define PIN(arr, n)                                        \
  _Pragma("unroll") for (int _p = 0; _p < (n); ++_p)       \
      asm volatile("" : "+v"((arr)[_p]));

// ===========================================================================
// kPre: R6 version VERBATIM (proven <=44us; R8's waves hint made it 57-63,
// R9's per-lane+LDS+PIN made it 72-74 -- both reverted).
// Roles: w = softmax(k@Mk^T); e = sigmoid(v@e_W+e_b)*mask;
// a = tanh(v@a_W+a_b)*mask. 4 rows per iteration (4 independent s_load
// chains). Mask folded into e/a => scan update is branchless identity when
// mask != 1.
// ===========================================================================
__global__ __launch_bounds__(256) void kPre(
    const int* __restrict__ question, const int* __restrict__ response,
    const float* __restrict__ mask,
    const float* __restrict__ k_emb, const float* __restrict__ v_emb,
    const float* __restrict__ Mk,
    const float* __restrict__ e_W, const float* __restrict__ e_b,
    const float* __restrict__ a_W, const float* __restrict__ a_b,
    float* __restrict__ w_buf, float* __restrict__ e_buf,
    float* __restrict__ a_buf) {
  const int lane = (int)(threadIdx.x & 63);
  const int wslot = __builtin_amdgcn_readfirstlane((int)(threadIdx.x >> 6));
  const int gw = blockIdx.x * 4 + wslot;
  const int NW = gridDim.x * 4;
  const int third = NW / 3;
  if (gw >= 3 * third) return;
  const int role = gw / third;
  const int idx = gw - role * third;
  const int stride4 = third * 4;

  if (role == 0) {                        // ---- role: w (softmax), 4 rows/iter
    float mk[64];
    const int mrow = lane < MM ? lane : (MM - 1);
#pragma unroll
    for (int i = 0; i < 64; i += 4) {
      const float4 t4 = *(const float4*)(Mk + mrow * 64 + i);
      mk[i] = t4.x; mk[i + 1] = t4.y; mk[i + 2] = t4.z; mk[i + 3] = t4.w;
    }
    for (int base = idx * 4; base < BB * TT; base += stride4) {
      const int4 q4 = *(const int4*)(question + base);   // 4 indices, 1 load
      const float* __restrict__ kr0 = k_emb + (size_t)q4.x * 64;
      const float* __restrict__ kr1 = k_emb + (size_t)q4.y * 64;
      const float* __restrict__ kr2 = k_emb + (size_t)q4.z * 64;
      const float* __restrict__ kr3 = k_emb + (size_t)q4.w * 64;
      float l00=0.f,l01=0.f,l02=0.f,l03=0.f;   // row 0, 4-way split
      float l10=0.f,l11=0.f,l12=0.f,l13=0.f;   // row 1
      float l20=0.f,l21=0.f,l22=0.f,l23=0.f;   // row 2
      float l30=0.f,l31=0.f,l32=0.f,l33=0.f;   // row 3
#pragma unroll
      for (int i = 0; i < 64; i += 4) {
        const float4 k0 = *(const float4*)(kr0 + i);     // 4 independent
        const float4 k1 = *(const float4*)(kr1 + i);     // s_load chains
        const float4 k2 = *(const float4*)(kr2 + i);
        const float4 k3 = *(const float4*)(kr3 + i);
        l00 = fmaf(k0.x, mk[i], l00); l01 = fmaf(k0.y, mk[i+1], l01);
        l02 = fmaf(k0.z, mk[i+2], l02); l03 = fmaf(k0.w, mk[i+3], l03);
        l10 = fmaf(k1.x, mk[i], l10); l11 = fmaf(k1.y, mk[i+1], l11);
        l12 = fmaf(k1.z, mk[i+2], l12); l13 = fmaf(k1.w, mk[i+3], l13);
        l20 = fmaf(k2.x, mk[i], l20); l21 = fmaf(k2.y, mk[i+1], l21);
        l22 = fmaf(k2.z, mk[i+2], l22); l23 = fmaf(k2.w, mk[i+3], l23);
        l30 = fmaf(k3.x, mk[i], l30); l31 = fmaf(k3.y, mk[i+1], l31);
        l32 = fmaf(k3.z, mk[i+2], l32); l33 = fmaf(k3.w, mk[i+3], l33);
      }
      float lm[4];
      lm[0] = (l00 + l01) + (l02 + l03);
      lm[1] = (l10 + l11) + (l12 + l13);
      lm[2] = (l20 + l21) + (l22 + l23);
      lm[3] = (l30 + l31) + (l32 + l33);
#pragma unroll
      for (int r = 0; r < 4; ++r) {
        float lv = (lane < MM) ? lm[r] : -3.4e38f;
#pragma unroll
        for (int off = 32; off > 0; off >>= 1) lv = fmaxf(lv, __shfl_xor(lv, off));
        float pe = (lane < MM) ? __expf(lm[r] - lv) : 0.f;
        float ss = pe;
#pragma unroll
        for (int off = 32; off > 0; off >>= 1) ss += __shfl_xor(ss, off);
        if (lane < MM) w_buf[(size_t)(base + r) * WPAD + lane] = pe / ss;
      }
    }
  } else if (role == 1) {                 // ---- role: e, 4 rows/iter
    float ew[64];
#pragma unroll
    for (int i = 0; i < 64; ++i) ew[i] = e_W[i * 64 + lane];
    const float eb = e_b[lane];
    for (int base = idx * 4; base < BB * TT; base += stride4) {
      const int4 q4 = *(const int4*)(question + base);
      const int4 r4 = *(const int4*)(response + base);
      const float4 m4 = *(const float4*)(mask + base);
      const float* __restrict__ v0 = v_emb + ((size_t)q4.x + (size_t)QN * r4.x) * 64;
      const float* __restrict__ v1 = v_emb + ((size_t)q4.y + (size_t)QN * r4.y) * 64;
      const float* __restrict__ v2 = v_emb + ((size_t)q4.z + (size_t)QN * r4.z) * 64;
      const float* __restrict__ v3 = v_emb + ((size_t)q4.w + (size_t)QN * r4.w) * 64;
      float e00 = eb, e01 = 0.f, e10 = eb, e11 = 0.f;
      float e20 = eb, e21 = 0.f, e30 = eb, e31 = 0.f;
#pragma unroll
      for (int i = 0; i < 64; i += 2) {
        const float2 a0 = *(const float2*)(v0 + i);      // 4 independent
        const float2 a1 = *(const float2*)(v1 + i);      // s_load chains
        const float2 a2 = *(const float2*)(v2 + i);
        const float2 a3 = *(const float2*)(v3 + i);
        e00 = fmaf(a0.x, ew[i], e00); e01 = fmaf(a0.y, ew[i+1], e01);
        e10 = fmaf(a1.x, ew[i], e10); e11 = fmaf(a1.y, ew[i+1], e11);
        e20 = fmaf(a2.x, ew[i], e20); e21 = fmaf(a2.y, ew[i+1], e21);
        e30 = fmaf(a3.x, ew[i], e30); e31 = fmaf(a3.y, ew[i+1], e31);
      }
      const float mf0 = (m4.x == 1.0f) ? 1.0f : 0.0f;
      const float mf1 = (m4.y == 1.0f) ? 1.0f : 0.0f;
      const float mf2 = (m4.z == 1.0f) ? 1.0f : 0.0f;
      const float mf3 = (m4.w == 1.0f) ? 1.0f : 0.0f;
      e_buf[(size_t)(base + 0) * 64 + lane] = mf0 / (1.f + __expf(-(e00 + e01)));
      e_buf[(size_t)(base + 1) * 64 + lane] = mf1 / (1.f + __expf(-(e10 + e11)));
      e_buf[(size_t)(base + 2) * 64 + lane] = mf2 / (1.f + __expf(-(e20 + e21)));
      e_buf[(size_t)(base + 3) * 64 + lane] = mf3 / (1.f + __expf(-(e30 + e31)));
    }
  } else {                                // ---- role: a, 4 rows/iter
    float aw[64];
#pragma unroll
    for (int i = 0; i < 64; ++i) aw[i] = a_W[i * 64 + lane];
    const float ab = a_b[lane];
    for (int base = idx * 4; base < BB * TT; base += stride4) {
      const int4 q4 = *(const int4*)(question + base);
      const int4 r4 = *(const int4*)(response + base);
      const float4 m4 = *(const float4*)(mask + base);
      const float* __restrict__ v0 = v_emb + ((size_t)q4.x + (size_t)QN * r4.x) * 64;
      const float* __restrict__ v1 = v_emb + ((size_t)q4.y + (size_t)QN * r4.y) * 64;
      const float* __restrict__ v2 = v_emb + ((size_t)q4.z + (size_t)QN * r4.z) * 64;
      const float* __restrict__ v3 = v_emb + ((size_t)q4.w + (size_t)QN * r4.w) * 64;
      float a00 = ab, a01 = 0.f, a10 = ab, a11 = 0.f;
      float a20 = ab, a21 = 0.f, a30 = ab, a31 = 0.f;
#pragma unroll
      for (int i = 0; i < 64; i += 2) {
        const float2 x0 = *(const float2*)(v0 + i);
        const float2 x1 = *(const float2*)(v1 + i);
        const float2 x2 = *(const float2*)(v2 + i);
        const float2 x3 = *(const float2*)(v3 + i);
        a00 = fmaf(x0.x, aw[i], a00); a01 = fmaf(x0.y, aw[i+1], a01);
        a10 = fmaf(x1.x, aw[i], a10); a11 = fmaf(x1.y, aw[i+1], a11);
        a20 = fmaf(x2.x, aw[i], a20); a21 = fmaf(x2.y, aw[i+1], a21);
        a30 = fmaf(x3.x, aw[i], a30); a31 = fmaf(x3.y, aw[i+1], a31);
      }
      const float mf0 = (m4.x == 1.0f) ? 1.0f : 0.0f;
      const float mf1 = (m4.y == 1.0f) ? 1.0f : 0.0f;
      const float mf2 = (m4.z == 1.0f) ? 1.0f : 0.0f;
      const float mf3 = (m4.w == 1.0f) ? 1.0f : 0.0f;
      const float s0 = a00 + a01, s1 = a10 + a11, s2 = a20 + a21, s3 = a30 + a31;
      a_buf[(size_t)(base + 0) * 64 + lane] = mf0 * (1.f - 2.f / (__expf(2.f * s0) + 1.f));
      a_buf[(size_t)(base + 1) * 64 + lane] = mf1 * (1.f - 2.f / (__expf(2.f * s1) + 1.f));
      a_buf[(size_t)(base + 2) * 64 + lane] = mf2 * (1.f - 2.f / (__expf(2.f * s2) + 1.f));
      a_buf[(size_t)(base + 3) * 64 + lane] = mf3 * (1.f - 2.f / (__expf(2.f * s3) + 1.f));
    }
  }
}

// ===========================================================================
// kScan: the ENTIRE T=512 scan + read emission in ONE kernel.
// Replaces kA16+kB_entry+kC16 (which materialized 156MB of AB/entry traffic
// over 3 dispatches). One block per batch b (64 blocks x 8 waves):
//   waves 0-3 : compute. m-split 13/13/12/12 (12-groups padded with wm=0).
//               State s[13] in registers; per step: read-dot -> p_lds,
//               then branchless update (mask pre-folded into e/a).
//   waves 4-6 : loaders. Double-buffered 16-step chunks of e / a / w into
//               LDS (producer-consumer; loads for chunk c+1 issue during
//               compute of chunk c; one barrier per chunk).
//   wave  7   : reducer. Sums the 4 partial read-rows of chunk c-1 from
//               p_lds and writes the SINGLE read_buf row (halves k3's
//               input traffic vs the old 2-partial read2).
// Wave placement puts 1 compute + 1 light wave per SIMD. 512 steps x ~39
// fma/step ~= 25-30us expected.
// ===========================================================================
__global__ __launch_bounds__(512) void kScan(
    const float* __restrict__ w_buf, const float* __restrict__ e_buf,
    const float* __restrict__ a_buf, const float* __restrict__ Mv0,
    float* __restrict__ read_buf) {
  __shared__ float e_lds[2][16][64];          // 8 KB
  __shared__ float a_lds[2][16][64];          // 8 KB
  __shared__ float w_lds[2][4][16][16];       // 8 KB  (16-slot pad, 16B-aligned)
  __shared__ float p_lds[2][4][16][64];       // 32 KB (partial read rows)
  const int lane = (int)(threadIdx.x & 63);
  const int ws = __builtin_amdgcn_readfirstlane((int)(threadIdx.x >> 6));
  const int b = blockIdx.x;
  const size_t bbase = (size_t)b * TT;

  // compute-wave state (groups: base 0,13,26,38; counts 13,13,12,12)
  float s[13];
  if (ws < 4) {
    const int gbase = (ws < 2) ? ws * 13 : 26 + (ws - 2) * 12;
    const int gcnt  = (ws < 2) ? 13 : 12;
#pragma unroll
    for (int m = 0; m < 13; ++m)
      s[m] = (m < gcnt) ? Mv0[(gbase + m) * 64 + lane] : 0.f;
  }

  // ---- prologue: load chunk 0 into buffer 0
  if (ws == 4) {
#pragma unroll
    for (int j = 0; j < 16; ++j)
      e_lds[0][j][lane] = e_buf[(bbase + j) * 64 + lane];
  } else if (ws == 5) {
#pragma unroll
    for (int j = 0; j < 16; ++j)
      a_lds[0][j][lane] = a_buf[(bbase + j) * 64 + lane];
  } else if (ws == 6) {
#pragma unroll
    for (int j = 0; j < 16; ++j) {
      if (lane < MM) {
        const float v = w_buf[(bbase + j) * WPAD + lane];
        const int grp = (lane < 13) ? 0 : (lane < 26) ? 1 : (lane < 38) ? 2 : 3;
        const int gb = (grp < 2) ? grp * 13 : 26 + (grp - 2) * 12;
        w_lds[0][grp][j][lane - gb] = v;
      } else if (lane == 50) w_lds[0][2][j][12] = 0.f;   // pad: wm=0 => identity
      else if (lane == 51) w_lds[0][3][j][12] = 0.f;
    }
  }
  __syncthreads();

  for (int c = 0; c < 32; ++c) {
    const int p = c & 1;
    if (ws < 4) {                           // ---- compute chunk c
      const int g = ws;
#pragma unroll
      for (int j = 0; j < 16; ++j) {
        const float4 q0 = *(const float4*)&w_lds[p][g][j][0];   // uniform bcast
        const float4 q1 = *(const float4*)&w_lds[p][g][j][4];
        const float4 q2 = *(const float4*)&w_lds[p][g][j][8];
        const float4 q3 = *(const float4*)&w_lds[p][g][j][12];  // .x only
        const float ed = e_lds[p][j][lane];
        const float ad = a_lds[p][j][lane];
        const float wm[13] = {q0.x, q0.y, q0.z, q0.w, q1.x, q1.y, q1.z, q1.w,
                              q2.x, q2.y, q2.z, q2.w, q3.x};
        float d0 = 0.f, d1 = 0.f;
#pragma unroll
        for (int m = 0; m < 12; m += 2) {
          d0 = fmaf(wm[m], s[m], d0);
          d1 = fmaf(wm[m + 1], s[m + 1], d1);
        }
        d0 = fmaf(wm[12], s[12], d0);
        p_lds[p][g][j][lane] = d0 + d1;     // pre-update read partial
#pragma unroll
        for (int m = 0; m < 13; ++m)
          s[m] = fmaf(wm[m], fmaf(-s[m], ed, ad), s[m]);
      }
    } else if (ws == 4) {                   // ---- load e chunk c+1
      if (c + 1 < 32) {
        const size_t rb = bbase + (size_t)(c + 1) * 16;
#pragma unroll
        for (int j = 0; j < 16; ++j)
          e_lds[1 - p][j][lane] = e_buf[(rb + j) * 64 + lane];
      }
    } else if (ws == 5) {                   // ---- load a chunk c+1
      if (c + 1 < 32) {
        const size_t rb = bbase + (size_t)(c + 1) * 16;
#pragma unroll
        for (int j = 0; j < 16; ++j)
          a_lds[1 - p][j][lane] = a_buf[(rb + j) * 64 + lane];
      }
    } else if (ws == 6) {                   // ---- load w chunk c+1
      if (c + 1 < 32) {
        const size_t rb = bbase + (size_t)(c + 1) * 16;
#pragma unroll
        for (int j = 0; j < 16; ++j) {
          if (lane < MM) {
            const float v = w_buf[(rb + j) * WPAD + lane];
            const int grp = (lane < 13) ? 0 : (lane < 26) ? 1 : (lane < 38) ? 2 : 3;
            const int gb = (grp < 2) ? grp * 13 : 26 + (grp - 2) * 12;
            w_lds[1 - p][grp][j][lane - gb] = v;
          } else if (lane == 50) w_lds[1 - p][2][j][12] = 0.f;
          else if (lane == 51) w_lds[1 - p][3][j][12] = 0.f;
        }
      }
    } else {                                // ---- ws==7: reduce chunk c-1
      if (c >= 1) {
        const int cc = c - 1, q = 1 - p;
        const int j0 = (cc == 0) ? 1 : 0;   // t=0 emits no read
        for (int j = j0; j < 16; ++j) {
          const int t = cc * 16 + j;
          const float r = (p_lds[q][0][j][lane] + p_lds[q][1][j][lane]) +
                          (p_lds[q][2][j][lane] + p_lds[q][3][j][lane]);
          read_buf[((size_t)b * (TT - 1) + (t - 1)) * 64 + lane] = r;
        }
      }
    }
    __syncthreads();
  }
  // ---- epilogue: reduce chunk 31 (parity 31&1 = 1)
  if (ws == 7) {
    for (int j = 0; j < 16; ++j) {
      const int t = 31 * 16 + j;
      const float r = (p_lds[1][0][j][lane] + p_lds[1][1][j][lane]) +
                      (p_lds[1][2][j][lane] + p_lds[1][3][j][lane]);
      read_buf[((size_t)b * (TT - 1) + (t - 1)) * 64 + lane] = r;
    }
  }
}

// ===========================================================================
// k3: f = tanh([read | k_{t+1}] @ f_W + f_b); p = f @ p_W + p_b.
// R9 version (proven ~-17us vs R6): per-lane loads + LDS broadcast + 1-deep
// cross-row prefetch + PIN'd fw[128]. Changed to the SINGLE read buffer
// (kScan pre-sums the partials).
// ===========================================================================
__global__ __launch_bounds__(256) void k3_out(
    const int* __restrict__ question, const float* __restrict__ k_emb,
    const float* __restrict__ read_buf,
    const float* __restrict__ f_W, const float* __restrict__ f_b,
    const float* __restrict__ p_W, const float* __restrict__ p_b,
    float* __restrict__ out) {
  __shared__ float stg[4][2][64];                      // [wave][{x,k}][i]
  const int lane = (int)(threadIdx.x & 63);
  const int ws = __builtin_amdgcn_readfirstlane((int)(threadIdx.x >> 6));
  const int NW = gridDim.x * 4;
  const int R = BB * (TT - 1);

  float fw[128];
#pragma unroll
  for (int i = 0; i < 128; ++i) fw[i] = f_W[i * 64 + lane];
  PIN(fw, 128)
  const float fb = f_b[lane];
  const float pw = p_W[lane];
  const float pb = p_b[0];

  int row = blockIdx.x * 4 + ws;
  float rd = 0.f, kl = 0.f;
  if (row < R) {                                       // prologue loads
    rd = read_buf[(size_t)row * 64 + lane];
    const int b = row / (TT - 1);
    const int tp = row - b * (TT - 1);
    const int qn = question[b * TT + tp + 1];
    kl = k_emb[(size_t)qn * 64 + lane];
  }
  while (row < R) {
    const int nrow = row + NW;
    float nrd = 0.f, nkl = 0.f;
    if (nrow < R) {                                    // issue next-row loads
      nrd = read_buf[(size_t)nrow * 64 + lane];
      const int nb = nrow / (TT - 1);
      const int ntp = nrow - nb * (TT - 1);
      const int nqn = question[nb * TT + ntp + 1];
      nkl = k_emb[(size_t)nqn * 64 + lane];
    }
    stg[ws][0][lane] = rd;
    stg[ws][1][lane] = kl;                             // wave-private slots
    float f0 = fb, f1 = 0.f, f2 = 0.f, f3 = 0.f;
#pragma unroll
    for (int i = 0; i < 64; i += 4) {
      const float4 xv = *(const float4*)&stg[ws][0][i]; // LDS broadcast
      f0 = fmaf(xv.x, fw[i], f0);
      f1 = fmaf(xv.y, fw[i + 1], f1);
      f2 = fmaf(xv.z, fw[i + 2], f2);
      f3 = fmaf(xv.w, fw[i + 3], f3);
    }
#pragma unroll
    for (int i = 0; i < 64; i += 4) {
      const float4 kv = *(const float4*)&stg[ws][1][i];
      f0 = fmaf(kv.x, fw[64 + i], f0);
      f1 = fmaf(kv.y, fw[64 + i + 1], f1);
      f2 = fmaf(kv.z, fw[64 + i + 2], f2);
      f3 = fmaf(kv.w, fw[64 + i + 3], f3);
    }
    const float f = (f0 + f1) + (f2 + f3);
    const float t2 = __expf(2.f * f);
    const float fv = 1.f - 2.f / (t2 + 1.f);           // tanh
    float acc = fv * pw;
#pragma unroll
    for (int off = 32; off > 0; off >>= 1) acc += __shfl_xor(acc, off);
    if (lane == 0) out[row] = acc + pb;

    rd = nrd; kl = nkl; row = nrow;
  }
}

// ---------------------------------------------------------------------------
extern "C" void kernel_launch(void* const* d_in, const int* in_sizes, int n_in,
                              void* d_out, int out_size, void* d_ws, size_t ws_size,
                              hipStream_t stream) {
  const int*   question = (const int*)d_in[0];
  const int*   response = (const int*)d_in[1];
  const float* mask     = (const float*)d_in[2];
  const float* k_emb    = (const float*)d_in[3];
  const float* v_emb    = (const float*)d_in[4];
  const float* Mk       = (const float*)d_in[5];
  const float* Mv0      = (const float*)d_in[6];
  const float* e_W      = (const float*)d_in[7];
  const float* e_b      = (const float*)d_in[8];
  const float* a_W      = (const float*)d_in[9];
  const float* a_b      = (const float*)d_in[10];
  const float* f_W      = (const float*)d_in[11];
  const float* f_b      = (const float*)d_in[12];
  const float* p_W      = (const float*)d_in[13];
  const float* p_b      = (const float*)d_in[14];
  float* out = (float*)d_out;

  // workspace layout (floats): 32.5 MB total (prev rounds used ~102 MB OK)
  const size_t wN  = (size_t)BB * TT * WPAD;       // 1,703,936
  const size_t eN  = (size_t)BB * TT * 64;         // 2,097,152
  float* ws = (float*)d_ws;
  float* w_buf    = ws;
  float* e_buf    = w_buf + wN;
  float* a_buf    = e_buf + eN;
  float* read_buf = a_buf + eN;                    // BB*(TT-1)*64

  // 3 dispatches: precompute -> fused scan -> output MLP
  hipLaunchKernelGGL(kPre, dim3(2048), dim3(256), 0, stream,
                     question, response, mask, k_emb, v_emb, Mk,
                     e_W, e_b, a_W, a_b, w_buf, e_buf, a_buf);
  hipLaunchKernelGGL(kScan, dim3(BB), dim3(512), 0, stream,
                     w_buf, e_buf, a_buf, Mv0, read_buf);
  hipLaunchKernelGGL(k3_out, dim3(1024), dim3(256), 0, stream,
                     question, k_emb, read_buf, f_W, f_b, p_W, p_b, out);
}

// Round 11
// 196.226 us; speedup vs baseline: 1.5833x; 1.5833x over previous
//
#include <hip/hip_runtime.h>
#include <cstddef>

// Problem constants (from reference)
#define QN 10000
#define DD 64
#define MM 50
#define BB 64
#define TT 512
#define WPAD 52   // padded w row stride in floats (208 B -> 16B-aligned rows)
#define MG 25     // m's per wave in the 2-way m-split scan kernels

// Pin a float array in VGPRs (k3 only; proven -17us there in R9).
#define PIN(arr, n)                                        \
  _Pragma("unroll") for (int _p = 0; _p < (n); ++_p)       \
      asm volatile("" : "+v"((arr)[_p]));

// ===========================================================================
// kPre: R6 version VERBATIM (best measured: ~43us). No occupancy hints
// (R8: hint -> 57-63us), no per-lane LDS rework (R9: -> 72-74us).
// Roles: w = softmax(k@Mk^T); e = sigmoid(v@e_W+e_b)*mask;
// a = tanh(v@a_W+a_b)*mask. 4 rows/iter (4 independent s_load chains).
// Mask folded into e/a => downstream scan updates are branchless.
// ===========================================================================
__global__ __launch_bounds__(256) void kPre(
    const int* __restrict__ question, const int* __restrict__ response,
    const float* __restrict__ mask,
    const float* __restrict__ k_emb, const float* __restrict__ v_emb,
    const float* __restrict__ Mk,
    const float* __restrict__ e_W, const float* __restrict__ e_b,
    const float* __restrict__ a_W, const float* __restrict__ a_b,
    float* __restrict__ w_buf, float* __restrict__ e_buf,
    float* __restrict__ a_buf) {
  const int lane = (int)(threadIdx.x & 63);
  const int wslot = __builtin_amdgcn_readfirstlane((int)(threadIdx.x >> 6));
  const int gw = blockIdx.x * 4 + wslot;
  const int NW = gridDim.x * 4;
  const int third = NW / 3;
  if (gw >= 3 * third) return;
  const int role = gw / third;
  const int idx = gw - role * third;
  const int stride4 = third * 4;

  if (role == 0) {                        // ---- role: w (softmax), 4 rows/iter
    float mk[64];
    const int mrow = lane < MM ? lane : (MM - 1);
#pragma unroll
    for (int i = 0; i < 64; i += 4) {
      const float4 t4 = *(const float4*)(Mk + mrow * 64 + i);
      mk[i] = t4.x; mk[i + 1] = t4.y; mk[i + 2] = t4.z; mk[i + 3] = t4.w;
    }
    for (int base = idx * 4; base < BB * TT; base += stride4) {
      const int4 q4 = *(const int4*)(question + base);   // 4 indices, 1 load
      const float* __restrict__ kr0 = k_emb + (size_t)q4.x * 64;
      const float* __restrict__ kr1 = k_emb + (size_t)q4.y * 64;
      const float* __restrict__ kr2 = k_emb + (size_t)q4.z * 64;
      const float* __restrict__ kr3 = k_emb + (size_t)q4.w * 64;
      float l00=0.f,l01=0.f,l02=0.f,l03=0.f;   // row 0, 4-way split
      float l10=0.f,l11=0.f,l12=0.f,l13=0.f;   // row 1
      float l20=0.f,l21=0.f,l22=0.f,l23=0.f;   // row 2
      float l30=0.f,l31=0.f,l32=0.f,l33=0.f;   // row 3
#pragma unroll
      for (int i = 0; i < 64; i += 4) {
        const float4 k0 = *(const float4*)(kr0 + i);     // 4 independent
        const float4 k1 = *(const float4*)(kr1 + i);     // s_load chains
        const float4 k2 = *(const float4*)(kr2 + i);
        const float4 k3 = *(const float4*)(kr3 + i);
        l00 = fmaf(k0.x, mk[i], l00); l01 = fmaf(k0.y, mk[i+1], l01);
        l02 = fmaf(k0.z, mk[i+2], l02); l03 = fmaf(k0.w, mk[i+3], l03);
        l10 = fmaf(k1.x, mk[i], l10); l11 = fmaf(k1.y, mk[i+1], l11);
        l12 = fmaf(k1.z, mk[i+2], l12); l13 = fmaf(k1.w, mk[i+3], l13);
        l20 = fmaf(k2.x, mk[i], l20); l21 = fmaf(k2.y, mk[i+1], l21);
        l22 = fmaf(k2.z, mk[i+2], l22); l23 = fmaf(k2.w, mk[i+3], l23);
        l30 = fmaf(k3.x, mk[i], l30); l31 = fmaf(k3.y, mk[i+1], l31);
        l32 = fmaf(k3.z, mk[i+2], l32); l33 = fmaf(k3.w, mk[i+3], l33);
      }
      float lm[4];
      lm[0] = (l00 + l01) + (l02 + l03);
      lm[1] = (l10 + l11) + (l12 + l13);
      lm[2] = (l20 + l21) + (l22 + l23);
      lm[3] = (l30 + l31) + (l32 + l33);
#pragma unroll
      for (int r = 0; r < 4; ++r) {
        float lv = (lane < MM) ? lm[r] : -3.4e38f;
#pragma unroll
        for (int off = 32; off > 0; off >>= 1) lv = fmaxf(lv, __shfl_xor(lv, off));
        float pe = (lane < MM) ? __expf(lm[r] - lv) : 0.f;
        float ss = pe;
#pragma unroll
        for (int off = 32; off > 0; off >>= 1) ss += __shfl_xor(ss, off);
        if (lane < MM) w_buf[(size_t)(base + r) * WPAD + lane] = pe / ss;
      }
    }
  } else if (role == 1) {                 // ---- role: e, 4 rows/iter
    float ew[64];
#pragma unroll
    for (int i = 0; i < 64; ++i) ew[i] = e_W[i * 64 + lane];
    const float eb = e_b[lane];
    for (int base = idx * 4; base < BB * TT; base += stride4) {
      const int4 q4 = *(const int4*)(question + base);
      const int4 r4 = *(const int4*)(response + base);
      const float4 m4 = *(const float4*)(mask + base);
      const float* __restrict__ v0 = v_emb + ((size_t)q4.x + (size_t)QN * r4.x) * 64;
      const float* __restrict__ v1 = v_emb + ((size_t)q4.y + (size_t)QN * r4.y) * 64;
      const float* __restrict__ v2 = v_emb + ((size_t)q4.z + (size_t)QN * r4.z) * 64;
      const float* __restrict__ v3 = v_emb + ((size_t)q4.w + (size_t)QN * r4.w) * 64;
      float e00 = eb, e01 = 0.f, e10 = eb, e11 = 0.f;
      float e20 = eb, e21 = 0.f, e30 = eb, e31 = 0.f;
#pragma unroll
      for (int i = 0; i < 64; i += 2) {
        const float2 a0 = *(const float2*)(v0 + i);      // 4 independent
        const float2 a1 = *(const float2*)(v1 + i);      // s_load chains
        const float2 a2 = *(const float2*)(v2 + i);
        const float2 a3 = *(const float2*)(v3 + i);
        e00 = fmaf(a0.x, ew[i], e00); e01 = fmaf(a0.y, ew[i+1], e01);
        e10 = fmaf(a1.x, ew[i], e10); e11 = fmaf(a1.y, ew[i+1], e11);
        e20 = fmaf(a2.x, ew[i], e20); e21 = fmaf(a2.y, ew[i+1], e21);
        e30 = fmaf(a3.x, ew[i], e30); e31 = fmaf(a3.y, ew[i+1], e31);
      }
      const float mf0 = (m4.x == 1.0f) ? 1.0f : 0.0f;
      const float mf1 = (m4.y == 1.0f) ? 1.0f : 0.0f;
      const float mf2 = (m4.z == 1.0f) ? 1.0f : 0.0f;
      const float mf3 = (m4.w == 1.0f) ? 1.0f : 0.0f;
      e_buf[(size_t)(base + 0) * 64 + lane] = mf0 / (1.f + __expf(-(e00 + e01)));
      e_buf[(size_t)(base + 1) * 64 + lane] = mf1 / (1.f + __expf(-(e10 + e11)));
      e_buf[(size_t)(base + 2) * 64 + lane] = mf2 / (1.f + __expf(-(e20 + e21)));
      e_buf[(size_t)(base + 3) * 64 + lane] = mf3 / (1.f + __expf(-(e30 + e31)));
    }
  } else {                                // ---- role: a, 4 rows/iter
    float aw[64];
#pragma unroll
    for (int i = 0; i < 64; ++i) aw[i] = a_W[i * 64 + lane];
    const float ab = a_b[lane];
    for (int base = idx * 4; base < BB * TT; base += stride4) {
      const int4 q4 = *(const int4*)(question + base);
      const int4 r4 = *(const int4*)(response + base);
      const float4 m4 = *(const float4*)(mask + base);
      const float* __restrict__ v0 = v_emb + ((size_t)q4.x + (size_t)QN * r4.x) * 64;
      const float* __restrict__ v1 = v_emb + ((size_t)q4.y + (size_t)QN * r4.y) * 64;
      const float* __restrict__ v2 = v_emb + ((size_t)q4.z + (size_t)QN * r4.z) * 64;
      const float* __restrict__ v3 = v_emb + ((size_t)q4.w + (size_t)QN * r4.w) * 64;
      float a00 = ab, a01 = 0.f, a10 = ab, a11 = 0.f;
      float a20 = ab, a21 = 0.f, a30 = ab, a31 = 0.f;
#pragma unroll
      for (int i = 0; i < 64; i += 2) {
        const float2 x0 = *(const float2*)(v0 + i);
        const float2 x1 = *(const float2*)(v1 + i);
        const float2 x2 = *(const float2*)(v2 + i);
        const float2 x3 = *(const float2*)(v3 + i);
        a00 = fmaf(x0.x, aw[i], a00); a01 = fmaf(x0.y, aw[i+1], a01);
        a10 = fmaf(x1.x, aw[i], a10); a11 = fmaf(x1.y, aw[i+1], a11);
        a20 = fmaf(x2.x, aw[i], a20); a21 = fmaf(x2.y, aw[i+1], a21);
        a30 = fmaf(x3.x, aw[i], a30); a31 = fmaf(x3.y, aw[i+1], a31);
      }
      const float mf0 = (m4.x == 1.0f) ? 1.0f : 0.0f;
      const float mf1 = (m4.y == 1.0f) ? 1.0f : 0.0f;
      const float mf2 = (m4.z == 1.0f) ? 1.0f : 0.0f;
      const float mf3 = (m4.w == 1.0f) ? 1.0f : 0.0f;
      const float s0 = a00 + a01, s1 = a10 + a11, s2 = a20 + a21, s3 = a30 + a31;
      a_buf[(size_t)(base + 0) * 64 + lane] = mf0 * (1.f - 2.f / (__expf(2.f * s0) + 1.f));
      a_buf[(size_t)(base + 1) * 64 + lane] = mf1 * (1.f - 2.f / (__expf(2.f * s1) + 1.f));
      a_buf[(size_t)(base + 2) * 64 + lane] = mf2 * (1.f - 2.f / (__expf(2.f * s2) + 1.f));
      a_buf[(size_t)(base + 3) * 64 + lane] = mf3 * (1.f - 2.f / (__expf(2.f * s3) + 1.f));
    }
  }
}

// ===========================================================================
// kA16: C=32 specialized compose (L=16, fully unrolled), prefetch-all ev/av.
// (R6 verbatim)
// ===========================================================================
__global__ __launch_bounds__(256) void kA16(
    const float* __restrict__ w_buf, const float* __restrict__ e_buf,
    const float* __restrict__ a_buf, float* __restrict__ AB) {
  const int lane = (int)(threadIdx.x & 63);
  const int wslot = __builtin_amdgcn_readfirstlane((int)(threadIdx.x >> 6));
  const int u2 = blockIdx.x * 4 + wslot;
  if (u2 >= BB * 32 * 2) return;
  const int g = u2 & 1;
  const int unit = u2 >> 1;                            // b*32 + c
  const int b = unit >> 5;
  const int c = unit & 31;
  const size_t rowbase = (size_t)b * TT + c * 16;
  const size_t eb0 = rowbase * 64 + lane;

  float ev[16], av[16];
#pragma unroll
  for (int j = 0; j < 16; ++j) {
    ev[j] = e_buf[eb0 + (size_t)j * 64];
    av[j] = a_buf[eb0 + (size_t)j * 64];
  }

  float Am[MG], Bm[MG];
#pragma unroll
  for (int m = 0; m < MG; ++m) { Am[m] = 1.f; Bm[m] = 0.f; }

#pragma unroll
  for (int j = 0; j < 16; ++j) {
    const float* __restrict__ wr = w_buf + (rowbase + j) * WPAD + g * MG;
#pragma unroll
    for (int m = 0; m < MG; ++m) {
      const float wm = wr[m];
      const float al = fmaf(-wm, ev[j], 1.0f);
      const float be = wm * av[j];
      Am[m] *= al;
      Bm[m] = fmaf(Bm[m], al, be);
    }
  }
  float* __restrict__ abp = AB + (size_t)unit * 6400 + (g * MG) * 128 + lane * 2;
#pragma unroll
  for (int m = 0; m < MG; ++m) {
    float2 o; o.x = Am[m]; o.y = Bm[m];
    *(float2*)(abp + m * 128) = o;
  }
}

// ===========================================================================
// kB: sequential over C chunks, parallel over B*M*D. (R6 verbatim)
// ===========================================================================
__global__ __launch_bounds__(256) void kB_entry(
    const float* __restrict__ AB, const float* __restrict__ Mv0,
    float* __restrict__ entry, int C) {
  const int NT = gridDim.x * 256;
  for (int idx = blockIdx.x * 256 + (int)threadIdx.x; idx < BB * MM * 64;
       idx += NT) {
    const int b = idx / (MM * 64);
    const int r = idx - b * (MM * 64);                 // m*64 + d
    float s = Mv0[r];
    const float* __restrict__ abp = AB + (size_t)b * C * 6400 + (size_t)r * 2;
    float* __restrict__ ep = entry + (size_t)b * C * 3200 + r;
    if (C == 32) {
      float2 ab[32];
#pragma unroll
      for (int c = 0; c < 32; ++c)
        ab[c] = *(const float2*)(abp + (size_t)c * 6400);
#pragma unroll
      for (int c = 0; c < 32; ++c) {
        ep[(size_t)c * 3200] = s;
        s = fmaf(ab[c].x, s, ab[c].y);
      }
    } else {
      float2 cur = *(const float2*)(abp);
      for (int c = 0; c < C; ++c) {
        ep[(size_t)c * 3200] = s;
        float2 nxt; nxt.x = 1.f; nxt.y = 0.f;
        if (c + 1 < C) nxt = *(const float2*)(abp + (size_t)(c + 1) * 6400);
        s = fmaf(cur.x, s, cur.y);
        cur = nxt;
      }
    }
  }
}

// ===========================================================================
// kC16: C=32 specialized replay, partial reads to read2. (R6 verbatim)
// ===========================================================================
__global__ __launch_bounds__(256) void kC16(
    const float* __restrict__ w_buf, const float* __restrict__ e_buf,
    const float* __restrict__ a_buf, const float* __restrict__ entry,
    float* __restrict__ read2) {
  const int lane = (int)(threadIdx.x & 63);
  const int wslot = __builtin_amdgcn_readfirstlane((int)(threadIdx.x >> 6));
  const int u2 = blockIdx.x * 4 + wslot;
  if (u2 >= BB * 32 * 2) return;
  const int g = u2 & 1;
  const int unit = u2 >> 1;                            // b*32 + c
  const int b = unit >> 5;
  const int c = unit & 31;
  const size_t RN = (size_t)BB * (TT - 1) * 64;
  const size_t rowbase = (size_t)b * TT + c * 16;
  const size_t eb0 = rowbase * 64 + lane;

  float ev[16], av[16];
#pragma unroll
  for (int j = 0; j < 16; ++j) {
    ev[j] = e_buf[eb0 + (size_t)j * 64];
    av[j] = a_buf[eb0 + (size_t)j * 64];
  }

  float s[MG];
  {
    const float* __restrict__ ep =
        entry + (size_t)unit * 3200 + (g * MG) * 64 + lane;
#pragma unroll
    for (int m = 0; m < MG; ++m) s[m] = ep[m * 64];    // 25 independent loads
  }

  const int t0 = c * 16;
  float* __restrict__ rb = read2 + (size_t)g * RN;
#pragma unroll
  for (int j = 0; j < 16; ++j) {
    const int t = t0 + j;
    const float* __restrict__ wr = w_buf + (rowbase + j) * WPAD + g * MG;
    if (t >= 1) {                                      // false only c==0,j==0
      float a0 = 0.f, a1 = 0.f;
#pragma unroll
      for (int m = 0; m < MG - 1; m += 2) {
        a0 = fmaf(wr[m], s[m], a0);
        a1 = fmaf(wr[m + 1], s[m + 1], a1);
      }
      a0 = fmaf(wr[MG - 1], s[MG - 1], a0);            // MG=25 is odd
      rb[((size_t)b * (TT - 1) + (t - 1)) * 64 + lane] = a0 + a1;
    }
#pragma unroll
    for (int m = 0; m < MG; ++m)
      s[m] = fmaf(wr[m], fmaf(-s[m], ev[j], av[j]), s[m]);
  }
}

// ===========================================================================
// Generic fallback scan kernels (used only if C != 32). (R6 verbatim)
// ===========================================================================
__global__ __launch_bounds__(256) void kA_chunk(
    const float* __restrict__ w_buf, const float* __restrict__ e_buf,
    const float* __restrict__ a_buf, float* __restrict__ AB, int logC, int L) {
  const int lane = (int)(threadIdx.x & 63);
  const int wslot = __builtin_amdgcn_readfirstlane((int)(threadIdx.x >> 6));
  const int NW = gridDim.x * 4;
  const int C = 1 << logC;
  for (int u2 = blockIdx.x * 4 + wslot; u2 < BB * C * 2; u2 += NW) {
    const int g = u2 & 1;
    const int unit = u2 >> 1;
    const int b = unit >> logC;
    const int c = unit & (C - 1);
    float Am[MG], Bm[MG];
#pragma unroll
    for (int m = 0; m < MG; ++m) { Am[m] = 1.f; Bm[m] = 0.f; }
    const size_t rowbase = (size_t)b * TT + c * L;
#pragma unroll 2
    for (int j = 0; j < L; ++j) {
      const size_t row = rowbase + j;
      const float ed = e_buf[row * 64 + lane];
      const float ad = a_buf[row * 64 + lane];
      const float* __restrict__ wr = w_buf + row * WPAD + g * MG;
#pragma unroll
      for (int m = 0; m < MG; ++m) {
        const float wm = wr[m];
        const float al = fmaf(-wm, ed, 1.0f);
        const float be = wm * ad;
        Am[m] *= al;
        Bm[m] = fmaf(Bm[m], al, be);
      }
    }
    float* __restrict__ abp = AB + (size_t)unit * 6400 + (g * MG) * 128 + lane * 2;
#pragma unroll
    for (int m = 0; m < MG; ++m) {
      float2 o; o.x = Am[m]; o.y = Bm[m];
      *(float2*)(abp + m * 128) = o;
    }
  }
}

__global__ __launch_bounds__(256) void kC_read(
    const float* __restrict__ w_buf, const float* __restrict__ e_buf,
    const float* __restrict__ a_buf, const float* __restrict__ entry,
    const float* __restrict__ Mv0, float* __restrict__ read2,
    int logC, int L, int use_mv0) {
  const int lane = (int)(threadIdx.x & 63);
  const int wslot = __builtin_amdgcn_readfirstlane((int)(threadIdx.x >> 6));
  const int NW = gridDim.x * 4;
  const int C = 1 << logC;
  const size_t RN = (size_t)BB * (TT - 1) * 64;
  for (int u2 = blockIdx.x * 4 + wslot; u2 < BB * C * 2; u2 += NW) {
    const int g = u2 & 1;
    const int unit = u2 >> 1;
    const int b = unit >> logC;
    const int c = unit & (C - 1);
    float s[MG];
    if (use_mv0) {
#pragma unroll
      for (int m = 0; m < MG; ++m) s[m] = Mv0[(g * MG + m) * 64 + lane];
    } else {
      const float* __restrict__ ep =
          entry + (size_t)unit * 3200 + (g * MG) * 64 + lane;
#pragma unroll
      for (int m = 0; m < MG; ++m) s[m] = ep[m * 64];
    }
    const int t0 = c * L;
    float* __restrict__ rb = read2 + (size_t)g * RN;
    for (int j = 0; j < L; ++j) {
      const int t = t0 + j;
      const size_t row = (size_t)b * TT + t;
      const float ed = e_buf[row * 64 + lane];
      const float ad = a_buf[row * 64 + lane];
      const float* __restrict__ wr = w_buf + row * WPAD + g * MG;
      if (t >= 1) {
        float a0 = 0.f, a1 = 0.f;
#pragma unroll
        for (int m = 0; m < MG - 1; m += 2) {
          a0 = fmaf(wr[m], s[m], a0);
          a1 = fmaf(wr[m + 1], s[m + 1], a1);
        }
        a0 = fmaf(wr[MG - 1], s[MG - 1], a0);
        rb[((size_t)b * (TT - 1) + (t - 1)) * 64 + lane] = a0 + a1;
      }
#pragma unroll
      for (int m = 0; m < MG; ++m)
        s[m] = fmaf(wr[m], fmaf(-s[m], ed, ad), s[m]);
    }
  }
}

// ===========================================================================
// k3: R9 version VERBATIM (proven -17us vs R6's s_load version): per-lane
// vector loads + LDS float4 broadcast + 1-deep cross-row prefetch; fw[128]
// PIN'd in VGPRs. Reads the two read2 partials and sums in-register.
// ===========================================================================
__global__ __launch_bounds__(256) void k3_out(
    const int* __restrict__ question, const float* __restrict__ k_emb,
    const float* __restrict__ read2,
    const float* __restrict__ f_W, const float* __restrict__ f_b,
    const float* __restrict__ p_W, const float* __restrict__ p_b,
    float* __restrict__ out) {
  __shared__ float stg[4][2][64];                      // [wave][{x,k}][i]
  const int lane = (int)(threadIdx.x & 63);
  const int ws = __builtin_amdgcn_readfirstlane((int)(threadIdx.x >> 6));
  const int NW = gridDim.x * 4;
  const size_t RN = (size_t)BB * (TT - 1) * 64;
  const int R = BB * (TT - 1);

  float fw[128];
#pragma unroll
  for (int i = 0; i < 128; ++i) fw[i] = f_W[i * 64 + lane];
  PIN(fw, 128)
  const float fb = f_b[lane];
  const float pw = p_W[lane];
  const float pb = p_b[0];

  int row = blockIdx.x * 4 + ws;
  float rd = 0.f, kl = 0.f;
  if (row < R) {                                       // prologue loads
    rd = read2[(size_t)row * 64 + lane] + read2[RN + (size_t)row * 64 + lane];
    const int b = row / (TT - 1);
    const int tp = row - b * (TT - 1);
    const int qn = question[b * TT + tp + 1];
    kl = k_emb[(size_t)qn * 64 + lane];
  }
  while (row < R) {
    const int nrow = row + NW;
    float nrd = 0.f, nkl = 0.f;
    if (nrow < R) {                                    // issue next-row loads
      nrd = read2[(size_t)nrow * 64 + lane] +
            read2[RN + (size_t)nrow * 64 + lane];
      const int nb = nrow / (TT - 1);
      const int ntp = nrow - nb * (TT - 1);
      const int nqn = question[nb * TT + ntp + 1];
      nkl = k_emb[(size_t)nqn * 64 + lane];
    }
    stg[ws][0][lane] = rd;
    stg[ws][1][lane] = kl;                             // wave-private slots
    float f0 = fb, f1 = 0.f, f2 = 0.f, f3 = 0.f;
#pragma unroll
    for (int i = 0; i < 64; i += 4) {
      const float4 xv = *(const float4*)&stg[ws][0][i]; // LDS broadcast
      f0 = fmaf(xv.x, fw[i], f0);
      f1 = fmaf(xv.y, fw[i + 1], f1);
      f2 = fmaf(xv.z, fw[i + 2], f2);
      f3 = fmaf(xv.w, fw[i + 3], f3);
    }
#pragma unroll
    for (int i = 0; i < 64; i += 4) {
      const float4 kv = *(const float4*)&stg[ws][1][i];
      f0 = fmaf(kv.x, fw[64 + i], f0);
      f1 = fmaf(kv.y, fw[64 + i + 1], f1);
      f2 = fmaf(kv.z, fw[64 + i + 2], f2);
      f3 = fmaf(kv.w, fw[64 + i + 3], f3);
    }
    const float f = (f0 + f1) + (f2 + f3);
    const float t2 = __expf(2.f * f);
    const float fv = 1.f - 2.f / (t2 + 1.f);           // tanh
    float acc = fv * pw;
#pragma unroll
    for (int off = 32; off > 0; off >>= 1) acc += __shfl_xor(acc, off);
    if (lane == 0) out[row] = acc + pb;

    rd = nrd; kl = nkl; row = nrow;
  }
}

// ---------------------------------------------------------------------------
extern "C" void kernel_launch(void* const* d_in, const int* in_sizes, int n_in,
                              void* d_out, int out_size, void* d_ws, size_t ws_size,
                              hipStream_t stream) {
  const int*   question = (const int*)d_in[0];
  const int*   response = (const int*)d_in[1];
  const float* mask     = (const float*)d_in[2];
  const float* k_emb    = (const float*)d_in[3];
  const float* v_emb    = (const float*)d_in[4];
  const float* Mk       = (const float*)d_in[5];
  const float* Mv0      = (const float*)d_in[6];
  const float* e_W      = (const float*)d_in[7];
  const float* e_b      = (const float*)d_in[8];
  const float* a_W      = (const float*)d_in[9];
  const float* a_b      = (const float*)d_in[10];
  const float* f_W      = (const float*)d_in[11];
  const float* f_b      = (const float*)d_in[12];
  const float* p_W      = (const float*)d_in[13];
  const float* p_b      = (const float*)d_in[14];
  float* out = (float*)d_out;

  // workspace layout (floats)
  const size_t wN  = (size_t)BB * TT * WPAD;       // 1,703,936
  const size_t eN  = (size_t)BB * TT * 64;         // 2,097,152
  const size_t r2N = 2ull * BB * (TT - 1) * 64;    // 4,186,112
  float* ws = (float*)d_ws;
  float* w_buf  = ws;
  float* e_buf  = w_buf + wN;
  float* a_buf  = e_buf + eN;
  float* read2  = a_buf + eN;
  float* AB_arr = read2 + r2N;
  const size_t baseN = wN + 2 * eN + r2N;          // 10,084,352 floats

  // choose the largest chunk count C that fits the workspace
  int C = 32, logC = 5;
  while (C >= 2) {
    const size_t need = (baseN + 9600ull * BB * C) * sizeof(float);
    if (need <= ws_size) break;
    C >>= 1; logC -= 1;
  }
  int useChunks = (C >= 2);
  if (!useChunks) { C = 1; logC = 0; }
  const int L = TT / C;
  float* entry = AB_arr + 6400ull * BB * C;

  hipLaunchKernelGGL(kPre, dim3(2048), dim3(256), 0, stream,
                     question, response, mask, k_emb, v_emb, Mk,
                     e_W, e_b, a_W, a_b, w_buf, e_buf, a_buf);

  if (C == 32) {
    hipLaunchKernelGGL(kA16, dim3(1024), dim3(256), 0, stream,
                       w_buf, e_buf, a_buf, AB_arr);
    hipLaunchKernelGGL(kB_entry, dim3((BB * MM * 64 + 255) / 256), dim3(256),
                       0, stream, AB_arr, Mv0, entry, C);
    hipLaunchKernelGGL(kC16, dim3(1024), dim3(256), 0, stream,
                       w_buf, e_buf, a_buf, entry, read2);
  } else {
    if (useChunks) {
      const int ublocksA = (BB * C * 2 + 3) / 4;
      hipLaunchKernelGGL(kA_chunk, dim3(ublocksA), dim3(256), 0, stream,
                         w_buf, e_buf, a_buf, AB_arr, logC, L);
      hipLaunchKernelGGL(kB_entry, dim3((BB * MM * 64 + 255) / 256), dim3(256),
                         0, stream, AB_arr, Mv0, entry, C);
    }
    const int ublocksC = (BB * C * 2 + 3) / 4;
    hipLaunchKernelGGL(kC_read, dim3(ublocksC), dim3(256), 0, stream,
                       w_buf, e_buf, a_buf, entry, Mv0, read2,
                       logC, L, useChunks ? 0 : 1);
  }

  hipLaunchKernelGGL(k3_out, dim3(1024), dim3(256), 0, stream,
                     question, k_emb, read2, f_W, f_b, p_W, p_b, out);
}

// Round 12
// 194.744 us; speedup vs baseline: 1.5953x; 1.0076x over previous
//
#include <hip/hip_runtime.h>
#include <cstddef>

// Problem constants (from reference)
#define QN 10000
#define DD 64
#define MM 50
#define BB 64
#define TT 512
#define WPAD 52   // padded w row stride in floats (208 B -> 16B-aligned rows)
#define MG 25     // m's per wave in the 2-way m-split scan kernels

// Pin a float array in VGPRs (k3 only; proven -17us there in R9).
#define PIN(arr, n)                                        \
  _Pragma("unroll") for (int _p = 0; _p < (n); ++_p)       \
      asm volatile("" : "+v"((arr)[_p]));

// ===========================================================================
// kPre: R6 version VERBATIM (best measured: ~43us). No occupancy hints
// (R8: hint -> 57-63us), no per-lane LDS rework (R9: -> 72-74us).
// ===========================================================================
__global__ __launch_bounds__(256) void kPre(
    const int* __restrict__ question, const int* __restrict__ response,
    const float* __restrict__ mask,
    const float* __restrict__ k_emb, const float* __restrict__ v_emb,
    const float* __restrict__ Mk,
    const float* __restrict__ e_W, const float* __restrict__ e_b,
    const float* __restrict__ a_W, const float* __restrict__ a_b,
    float* __restrict__ w_buf, float* __restrict__ e_buf,
    float* __restrict__ a_buf) {
  const int lane = (int)(threadIdx.x & 63);
  const int wslot = __builtin_amdgcn_readfirstlane((int)(threadIdx.x >> 6));
  const int gw = blockIdx.x * 4 + wslot;
  const int NW = gridDim.x * 4;
  const int third = NW / 3;
  if (gw >= 3 * third) return;
  const int role = gw / third;
  const int idx = gw - role * third;
  const int stride4 = third * 4;

  if (role == 0) {                        // ---- role: w (softmax), 4 rows/iter
    float mk[64];
    const int mrow = lane < MM ? lane : (MM - 1);
#pragma unroll
    for (int i = 0; i < 64; i += 4) {
      const float4 t4 = *(const float4*)(Mk + mrow * 64 + i);
      mk[i] = t4.x; mk[i + 1] = t4.y; mk[i + 2] = t4.z; mk[i + 3] = t4.w;
    }
    for (int base = idx * 4; base < BB * TT; base += stride4) {
      const int4 q4 = *(const int4*)(question + base);   // 4 indices, 1 load
      const float* __restrict__ kr0 = k_emb + (size_t)q4.x * 64;
      const float* __restrict__ kr1 = k_emb + (size_t)q4.y * 64;
      const float* __restrict__ kr2 = k_emb + (size_t)q4.z * 64;
      const float* __restrict__ kr3 = k_emb + (size_t)q4.w * 64;
      float l00=0.f,l01=0.f,l02=0.f,l03=0.f;   // row 0, 4-way split
      float l10=0.f,l11=0.f,l12=0.f,l13=0.f;   // row 1
      float l20=0.f,l21=0.f,l22=0.f,l23=0.f;   // row 2
      float l30=0.f,l31=0.f,l32=0.f,l33=0.f;   // row 3
#pragma unroll
      for (int i = 0; i < 64; i += 4) {
        const float4 k0 = *(const float4*)(kr0 + i);     // 4 independent
        const float4 k1 = *(const float4*)(kr1 + i);     // s_load chains
        const float4 k2 = *(const float4*)(kr2 + i);
        const float4 k3 = *(const float4*)(kr3 + i);
        l00 = fmaf(k0.x, mk[i], l00); l01 = fmaf(k0.y, mk[i+1], l01);
        l02 = fmaf(k0.z, mk[i+2], l02); l03 = fmaf(k0.w, mk[i+3], l03);
        l10 = fmaf(k1.x, mk[i], l10); l11 = fmaf(k1.y, mk[i+1], l11);
        l12 = fmaf(k1.z, mk[i+2], l12); l13 = fmaf(k1.w, mk[i+3], l13);
        l20 = fmaf(k2.x, mk[i], l20); l21 = fmaf(k2.y, mk[i+1], l21);
        l22 = fmaf(k2.z, mk[i+2], l22); l23 = fmaf(k2.w, mk[i+3], l23);
        l30 = fmaf(k3.x, mk[i], l30); l31 = fmaf(k3.y, mk[i+1], l31);
        l32 = fmaf(k3.z, mk[i+2], l32); l33 = fmaf(k3.w, mk[i+3], l33);
      }
      float lm[4];
      lm[0] = (l00 + l01) + (l02 + l03);
      lm[1] = (l10 + l11) + (l12 + l13);
      lm[2] = (l20 + l21) + (l22 + l23);
      lm[3] = (l30 + l31) + (l32 + l33);
#pragma unroll
      for (int r = 0; r < 4; ++r) {
        float lv = (lane < MM) ? lm[r] : -3.4e38f;
#pragma unroll
        for (int off = 32; off > 0; off >>= 1) lv = fmaxf(lv, __shfl_xor(lv, off));
        float pe = (lane < MM) ? __expf(lm[r] - lv) : 0.f;
        float ss = pe;
#pragma unroll
        for (int off = 32; off > 0; off >>= 1) ss += __shfl_xor(ss, off);
        if (lane < MM) w_buf[(size_t)(base + r) * WPAD + lane] = pe / ss;
      }
    }
  } else if (role == 1) {                 // ---- role: e, 4 rows/iter
    float ew[64];
#pragma unroll
    for (int i = 0; i < 64; ++i) ew[i] = e_W[i * 64 + lane];
    const float eb = e_b[lane];
    for (int base = idx * 4; base < BB * TT; base += stride4) {
      const int4 q4 = *(const int4*)(question + base);
      const int4 r4 = *(const int4*)(response + base);
      const float4 m4 = *(const float4*)(mask + base);
      const float* __restrict__ v0 = v_emb + ((size_t)q4.x + (size_t)QN * r4.x) * 64;
      const float* __restrict__ v1 = v_emb + ((size_t)q4.y + (size_t)QN * r4.y) * 64;
      const float* __restrict__ v2 = v_emb + ((size_t)q4.z + (size_t)QN * r4.z) * 64;
      const float* __restrict__ v3 = v_emb + ((size_t)q4.w + (size_t)QN * r4.w) * 64;
      float e00 = eb, e01 = 0.f, e10 = eb, e11 = 0.f;
      float e20 = eb, e21 = 0.f, e30 = eb, e31 = 0.f;
#pragma unroll
      for (int i = 0; i < 64; i += 2) {
        const float2 a0 = *(const float2*)(v0 + i);      // 4 independent
        const float2 a1 = *(const float2*)(v1 + i);      // s_load chains
        const float2 a2 = *(const float2*)(v2 + i);
        const float2 a3 = *(const float2*)(v3 + i);
        e00 = fmaf(a0.x, ew[i], e00); e01 = fmaf(a0.y, ew[i+1], e01);
        e10 = fmaf(a1.x, ew[i], e10); e11 = fmaf(a1.y, ew[i+1], e11);
        e20 = fmaf(a2.x, ew[i], e20); e21 = fmaf(a2.y, ew[i+1], e21);
        e30 = fmaf(a3.x, ew[i], e30); e31 = fmaf(a3.y, ew[i+1], e31);
      }
      const float mf0 = (m4.x == 1.0f) ? 1.0f : 0.0f;
      const float mf1 = (m4.y == 1.0f) ? 1.0f : 0.0f;
      const float mf2 = (m4.z == 1.0f) ? 1.0f : 0.0f;
      const float mf3 = (m4.w == 1.0f) ? 1.0f : 0.0f;
      e_buf[(size_t)(base + 0) * 64 + lane] = mf0 / (1.f + __expf(-(e00 + e01)));
      e_buf[(size_t)(base + 1) * 64 + lane] = mf1 / (1.f + __expf(-(e10 + e11)));
      e_buf[(size_t)(base + 2) * 64 + lane] = mf2 / (1.f + __expf(-(e20 + e21)));
      e_buf[(size_t)(base + 3) * 64 + lane] = mf3 / (1.f + __expf(-(e30 + e31)));
    }
  } else {                                // ---- role: a, 4 rows/iter
    float aw[64];
#pragma unroll
    for (int i = 0; i < 64; ++i) aw[i] = a_W[i * 64 + lane];
    const float ab = a_b[lane];
    for (int base = idx * 4; base < BB * TT; base += stride4) {
      const int4 q4 = *(const int4*)(question + base);
      const int4 r4 = *(const int4*)(response + base);
      const float4 m4 = *(const float4*)(mask + base);
      const float* __restrict__ v0 = v_emb + ((size_t)q4.x + (size_t)QN * r4.x) * 64;
      const float* __restrict__ v1 = v_emb + ((size_t)q4.y + (size_t)QN * r4.y) * 64;
      const float* __restrict__ v2 = v_emb + ((size_t)q4.z + (size_t)QN * r4.z) * 64;
      const float* __restrict__ v3 = v_emb + ((size_t)q4.w + (size_t)QN * r4.w) * 64;
      float a00 = ab, a01 = 0.f, a10 = ab, a11 = 0.f;
      float a20 = ab, a21 = 0.f, a30 = ab, a31 = 0.f;
#pragma unroll
      for (int i = 0; i < 64; i += 2) {
        const float2 x0 = *(const float2*)(v0 + i);
        const float2 x1 = *(const float2*)(v1 + i);
        const float2 x2 = *(const float2*)(v2 + i);
        const float2 x3 = *(const float2*)(v3 + i);
        a00 = fmaf(x0.x, aw[i], a00); a01 = fmaf(x0.y, aw[i+1], a01);
        a10 = fmaf(x1.x, aw[i], a10); a11 = fmaf(x1.y, aw[i+1], a11);
        a20 = fmaf(x2.x, aw[i], a20); a21 = fmaf(x2.y, aw[i+1], a21);
        a30 = fmaf(x3.x, aw[i], a30); a31 = fmaf(x3.y, aw[i+1], a31);
      }
      const float mf0 = (m4.x == 1.0f) ? 1.0f : 0.0f;
      const float mf1 = (m4.y == 1.0f) ? 1.0f : 0.0f;
      const float mf2 = (m4.z == 1.0f) ? 1.0f : 0.0f;
      const float mf3 = (m4.w == 1.0f) ? 1.0f : 0.0f;
      const float s0 = a00 + a01, s1 = a10 + a11, s2 = a20 + a21, s3 = a30 + a31;
      a_buf[(size_t)(base + 0) * 64 + lane] = mf0 * (1.f - 2.f / (__expf(2.f * s0) + 1.f));
      a_buf[(size_t)(base + 1) * 64 + lane] = mf1 * (1.f - 2.f / (__expf(2.f * s1) + 1.f));
      a_buf[(size_t)(base + 2) * 64 + lane] = mf2 * (1.f - 2.f / (__expf(2.f * s2) + 1.f));
      a_buf[(size_t)(base + 3) * 64 + lane] = mf3 * (1.f - 2.f / (__expf(2.f * s3) + 1.f));
    }
  }
}

// ===========================================================================
// W-tile staging helper (kA16/kC16): each wave copies its 16 w rows into
// wave-private LDS, repacked to 56-float rows so BOTH m-halves start 16B
// aligned: cols[0..24] -> [0..24], cols[25..49] -> [28..52]. 13 coalesced
// per-lane loads replace 16x25 wave-uniform s_loads whose out-of-order SMEM
// returns forced coarse lgkmcnt(0) drains (the kA16/kC16 latency, ~40us
// each -- same mechanism R9 fixed in k3 for -17us). Reads are uniform
// ds_read_b128 broadcasts with fine-grained lgkmcnt.
// ===========================================================================
#define STAGE_W(wl_row, rowbase)                                            \
  {                                                                         \
    const float* __restrict__ wsrc = w_buf + (rowbase) * WPAD;              \
    _Pragma("unroll") for (int k = 0; k < 13; ++k) {                        \
      const int idx = lane + k * 64;               /* 0..831 */             \
      const int row = idx / 52;                                             \
      const int col = idx - row * 52;                                       \
      (wl_row)[row * 56 + col + (col >= 25 ? 3 : 0)] = wsrc[idx];           \
    }                                                                       \
  }

#define LOAD_WM(wm, wl_row, j, g)                                           \
  const float* __restrict__ wj_##j = (wl_row) + (j) * 56 + (g) * 28;        \
  const float4 q0_##j = *(const float4*)(wj_##j + 0);                       \
  const float4 q1_##j = *(const float4*)(wj_##j + 4);                       \
  const float4 q2_##j = *(const float4*)(wj_##j + 8);                       \
  const float4 q3_##j = *(const float4*)(wj_##j + 12);                      \
  const float4 q4_##j = *(const float4*)(wj_##j + 16);                      \
  const float4 q5_##j = *(const float4*)(wj_##j + 20);                      \
  const float4 q6_##j = *(const float4*)(wj_##j + 24);                      \
  const float wm[MG] = {q0_##j.x, q0_##j.y, q0_##j.z, q0_##j.w,             \
                        q1_##j.x, q1_##j.y, q1_##j.z, q1_##j.w,             \
                        q2_##j.x, q2_##j.y, q2_##j.z, q2_##j.w,             \
                        q3_##j.x, q3_##j.y, q3_##j.z, q3_##j.w,             \
                        q4_##j.x, q4_##j.y, q4_##j.z, q4_##j.w,             \
                        q5_##j.x, q5_##j.y, q5_##j.z, q5_##j.w, q6_##j.x};

// ===========================================================================
// kA16: C=32 compose, w read from staged LDS (uniform float4 broadcasts).
// ===========================================================================
__global__ __launch_bounds__(256) void kA16(
    const float* __restrict__ w_buf, const float* __restrict__ e_buf,
    const float* __restrict__ a_buf, float* __restrict__ AB) {
  __shared__ float wl[4][16 * 56];                     // 14,336 B
  const int lane = (int)(threadIdx.x & 63);
  const int wslot = __builtin_amdgcn_readfirstlane((int)(threadIdx.x >> 6));
  const int u2 = blockIdx.x * 4 + wslot;
  if (u2 >= BB * 32 * 2) return;
  const int g = u2 & 1;
  const int unit = u2 >> 1;                            // b*32 + c
  const int b = unit >> 5;
  const int c = unit & 31;
  const size_t rowbase = (size_t)b * TT + c * 16;
  const size_t eb0 = rowbase * 64 + lane;

  float ev[16], av[16];
#pragma unroll
  for (int j = 0; j < 16; ++j) {
    ev[j] = e_buf[eb0 + (size_t)j * 64];
    av[j] = a_buf[eb0 + (size_t)j * 64];
  }
  STAGE_W(wl[wslot], rowbase)                          // wave-private: no barrier

  float Am[MG], Bm[MG];
#pragma unroll
  for (int m = 0; m < MG; ++m) { Am[m] = 1.f; Bm[m] = 0.f; }

#pragma unroll
  for (int j = 0; j < 16; ++j) {
    LOAD_WM(wm, wl[wslot], j, g)
#pragma unroll
    for (int m = 0; m < MG; ++m) {
      const float al = fmaf(-wm[m], ev[j], 1.0f);
      const float be = wm[m] * av[j];
      Am[m] *= al;
      Bm[m] = fmaf(Bm[m], al, be);
    }
  }
  float* __restrict__ abp = AB + (size_t)unit * 6400 + (g * MG) * 128 + lane * 2;
#pragma unroll
  for (int m = 0; m < MG; ++m) {
    float2 o; o.x = Am[m]; o.y = Bm[m];
    *(float2*)(abp + m * 128) = o;
  }
}

// ===========================================================================
// kB: sequential over C chunks, parallel over B*M*D. (R11 verbatim)
// ===========================================================================
__global__ __launch_bounds__(256) void kB_entry(
    const float* __restrict__ AB, const float* __restrict__ Mv0,
    float* __restrict__ entry, int C) {
  const int NT = gridDim.x * 256;
  for (int idx = blockIdx.x * 256 + (int)threadIdx.x; idx < BB * MM * 64;
       idx += NT) {
    const int b = idx / (MM * 64);
    const int r = idx - b * (MM * 64);                 // m*64 + d
    float s = Mv0[r];
    const float* __restrict__ abp = AB + (size_t)b * C * 6400 + (size_t)r * 2;
    float* __restrict__ ep = entry + (size_t)b * C * 3200 + r;
    if (C == 32) {
      float2 ab[32];
#pragma unroll
      for (int c = 0; c < 32; ++c)
        ab[c] = *(const float2*)(abp + (size_t)c * 6400);
#pragma unroll
      for (int c = 0; c < 32; ++c) {
        ep[(size_t)c * 3200] = s;
        s = fmaf(ab[c].x, s, ab[c].y);
      }
    } else {
      float2 cur = *(const float2*)(abp);
      for (int c = 0; c < C; ++c) {
        ep[(size_t)c * 3200] = s;
        float2 nxt; nxt.x = 1.f; nxt.y = 0.f;
        if (c + 1 < C) nxt = *(const float2*)(abp + (size_t)(c + 1) * 6400);
        s = fmaf(cur.x, s, cur.y);
        cur = nxt;
      }
    }
  }
}

// ===========================================================================
// kC16: C=32 replay, w read from staged LDS (same mechanism as kA16).
// ===========================================================================
__global__ __launch_bounds__(256) void kC16(
    const float* __restrict__ w_buf, const float* __restrict__ e_buf,
    const float* __restrict__ a_buf, const float* __restrict__ entry,
    float* __restrict__ read2) {
  __shared__ float wl[4][16 * 56];                     // 14,336 B
  const int lane = (int)(threadIdx.x & 63);
  const int wslot = __builtin_amdgcn_readfirstlane((int)(threadIdx.x >> 6));
  const int u2 = blockIdx.x * 4 + wslot;
  if (u2 >= BB * 32 * 2) return;
  const int g = u2 & 1;
  const int unit = u2 >> 1;                            // b*32 + c
  const int b = unit >> 5;
  const int c = unit & 31;
  const size_t RN = (size_t)BB * (TT - 1) * 64;
  const size_t rowbase = (size_t)b * TT + c * 16;
  const size_t eb0 = rowbase * 64 + lane;

  float ev[16], av[16];
#pragma unroll
  for (int j = 0; j < 16; ++j) {
    ev[j] = e_buf[eb0 + (size_t)j * 64];
    av[j] = a_buf[eb0 + (size_t)j * 64];
  }
  float s[MG];
  {
    const float* __restrict__ ep =
        entry + (size_t)unit * 3200 + (g * MG) * 64 + lane;
#pragma unroll
    for (int m = 0; m < MG; ++m) s[m] = ep[m * 64];    // 25 independent loads
  }
  STAGE_W(wl[wslot], rowbase)                          // wave-private: no barrier

  const int t0 = c * 16;
  float* __restrict__ rb = read2 + (size_t)g * RN;
#pragma unroll
  for (int j = 0; j < 16; ++j) {
    const int t = t0 + j;
    LOAD_WM(wm, wl[wslot], j, g)
    if (t >= 1) {                                      // false only c==0,j==0
      float a0 = 0.f, a1 = 0.f;
#pragma unroll
      for (int m = 0; m < MG - 1; m += 2) {
        a0 = fmaf(wm[m], s[m], a0);
        a1 = fmaf(wm[m + 1], s[m + 1], a1);
      }
      a0 = fmaf(wm[MG - 1], s[MG - 1], a0);            // MG=25 is odd
      rb[((size_t)b * (TT - 1) + (t - 1)) * 64 + lane] = a0 + a1;
    }
#pragma unroll
    for (int m = 0; m < MG; ++m)
      s[m] = fmaf(wm[m], fmaf(-s[m], ev[j], av[j]), s[m]);
  }
}

// ===========================================================================
// Generic fallback scan kernels (used only if C != 32). (R11 verbatim)
// ===========================================================================
__global__ __launch_bounds__(256) void kA_chunk(
    const float* __restrict__ w_buf, const float* __restrict__ e_buf,
    const float* __restrict__ a_buf, float* __restrict__ AB, int logC, int L) {
  const int lane = (int)(threadIdx.x & 63);
  const int wslot = __builtin_amdgcn_readfirstlane((int)(threadIdx.x >> 6));
  const int NW = gridDim.x * 4;
  const int C = 1 << logC;
  for (int u2 = blockIdx.x * 4 + wslot; u2 < BB * C * 2; u2 += NW) {
    const int g = u2 & 1;
    const int unit = u2 >> 1;
    const int b = unit >> logC;
    const int c = unit & (C - 1);
    float Am[MG], Bm[MG];
#pragma unroll
    for (int m = 0; m < MG; ++m) { Am[m] = 1.f; Bm[m] = 0.f; }
    const size_t rowbase = (size_t)b * TT + c * L;
#pragma unroll 2
    for (int j = 0; j < L; ++j) {
      const size_t row = rowbase + j;
      const float ed = e_buf[row * 64 + lane];
      const float ad = a_buf[row * 64 + lane];
      const float* __restrict__ wr = w_buf + row * WPAD + g * MG;
#pragma unroll
      for (int m = 0; m < MG; ++m) {
        const float wm = wr[m];
        const float al = fmaf(-wm, ed, 1.0f);
        const float be = wm * ad;
        Am[m] *= al;
        Bm[m] = fmaf(Bm[m], al, be);
      }
    }
    float* __restrict__ abp = AB + (size_t)unit * 6400 + (g * MG) * 128 + lane * 2;
#pragma unroll
    for (int m = 0; m < MG; ++m) {
      float2 o; o.x = Am[m]; o.y = Bm[m];
      *(float2*)(abp + m * 128) = o;
    }
  }
}

__global__ __launch_bounds__(256) void kC_read(
    const float* __restrict__ w_buf, const float* __restrict__ e_buf,
    const float* __restrict__ a_buf, const float* __restrict__ entry,
    const float* __restrict__ Mv0, float* __restrict__ read2,
    int logC, int L, int use_mv0) {
  const int lane = (int)(threadIdx.x & 63);
  const int wslot = __builtin_amdgcn_readfirstlane((int)(threadIdx.x >> 6));
  const int NW = gridDim.x * 4;
  const int C = 1 << logC;
  const size_t RN = (size_t)BB * (TT - 1) * 64;
  for (int u2 = blockIdx.x * 4 + wslot; u2 < BB * C * 2; u2 += NW) {
    const int g = u2 & 1;
    const int unit = u2 >> 1;
    const int b = unit >> logC;
    const int c = unit & (C - 1);
    float s[MG];
    if (use_mv0) {
#pragma unroll
      for (int m = 0; m < MG; ++m) s[m] = Mv0[(g * MG + m) * 64 + lane];
    } else {
      const float* __restrict__ ep =
          entry + (size_t)unit * 3200 + (g * MG) * 64 + lane;
#pragma unroll
      for (int m = 0; m < MG; ++m) s[m] = ep[m * 64];
    }
    const int t0 = c * L;
    float* __restrict__ rb = read2 + (size_t)g * RN;
    for (int j = 0; j < L; ++j) {
      const int t = t0 + j;
      const size_t row = (size_t)b * TT + t;
      const float ed = e_buf[row * 64 + lane];
      const float ad = a_buf[row * 64 + lane];
      const float* __restrict__ wr = w_buf + row * WPAD + g * MG;
      if (t >= 1) {
        float a0 = 0.f, a1 = 0.f;
#pragma unroll
        for (int m = 0; m < MG - 1; m += 2) {
          a0 = fmaf(wr[m], s[m], a0);
          a1 = fmaf(wr[m + 1], s[m + 1], a1);
        }
        a0 = fmaf(wr[MG - 1], s[MG - 1], a0);
        rb[((size_t)b * (TT - 1) + (t - 1)) * 64 + lane] = a0 + a1;
      }
#pragma unroll
      for (int m = 0; m < MG; ++m)
        s[m] = fmaf(wr[m], fmaf(-s[m], ed, ad), s[m]);
    }
  }
}

// ===========================================================================
// k3: R9/R11 version VERBATIM (proven -17us vs s_load version).
// ===========================================================================
__global__ __launch_bounds__(256) void k3_out(
    const int* __restrict__ question, const float* __restrict__ k_emb,
    const float* __restrict__ read2,
    const float* __restrict__ f_W, const float* __restrict__ f_b,
    const float* __restrict__ p_W, const float* __restrict__ p_b,
    float* __restrict__ out) {
  __shared__ float stg[4][2][64];                      // [wave][{x,k}][i]
  const int lane = (int)(threadIdx.x & 63);
  const int ws = __builtin_amdgcn_readfirstlane((int)(threadIdx.x >> 6));
  const int NW = gridDim.x * 4;
  const size_t RN = (size_t)BB * (TT - 1) * 64;
  const int R = BB * (TT - 1);

  float fw[128];
#pragma unroll
  for (int i = 0; i < 128; ++i) fw[i] = f_W[i * 64 + lane];
  PIN(fw, 128)
  const float fb = f_b[lane];
  const float pw = p_W[lane];
  const float pb = p_b[0];

  int row = blockIdx.x * 4 + ws;
  float rd = 0.f, kl = 0.f;
  if (row < R) {                                       // prologue loads
    rd = read2[(size_t)row * 64 + lane] + read2[RN + (size_t)row * 64 + lane];
    const int b = row / (TT - 1);
    const int tp = row - b * (TT - 1);
    const int qn = question[b * TT + tp + 1];
    kl = k_emb[(size_t)qn * 64 + lane];
  }
  while (row < R) {
    const int nrow = row + NW;
    float nrd = 0.f, nkl = 0.f;
    if (nrow < R) {                                    // issue next-row loads
      nrd = read2[(size_t)nrow * 64 + lane] +
            read2[RN + (size_t)nrow * 64 + lane];
      const int nb = nrow / (TT - 1);
      const int ntp = nrow - nb * (TT - 1);
      const int nqn = question[nb * TT + ntp + 1];
      nkl = k_emb[(size_t)nqn * 64 + lane];
    }
    stg[ws][0][lane] = rd;
    stg[ws][1][lane] = kl;                             // wave-private slots
    float f0 = fb, f1 = 0.f, f2 = 0.f, f3 = 0.f;
#pragma unroll
    for (int i = 0; i < 64; i += 4) {
      const float4 xv = *(const float4*)&stg[ws][0][i]; // LDS broadcast
      f0 = fmaf(xv.x, fw[i], f0);
      f1 = fmaf(xv.y, fw[i + 1], f1);
      f2 = fmaf(xv.z, fw[i + 2], f2);
      f3 = fmaf(xv.w, fw[i + 3], f3);
    }
#pragma unroll
    for (int i = 0; i < 64; i += 4) {
      const float4 kv = *(const float4*)&stg[ws][1][i];
      f0 = fmaf(kv.x, fw[64 + i], f0);
      f1 = fmaf(kv.y, fw[64 + i + 1], f1);
      f2 = fmaf(kv.z, fw[64 + i + 2], f2);
      f3 = fmaf(kv.w, fw[64 + i + 3], f3);
    }
    const float f = (f0 + f1) + (f2 + f3);
    const float t2 = __expf(2.f * f);
    const float fv = 1.f - 2.f / (t2 + 1.f);           // tanh
    float acc = fv * pw;
#pragma unroll
    for (int off = 32; off > 0; off >>= 1) acc += __shfl_xor(acc, off);
    if (lane == 0) out[row] = acc + pb;

    rd = nrd; kl = nkl; row = nrow;
  }
}

// ---------------------------------------------------------------------------
extern "C" void kernel_launch(void* const* d_in, const int* in_sizes, int n_in,
                              void* d_out, int out_size, void* d_ws, size_t ws_size,
                              hipStream_t stream) {
  const int*   question = (const int*)d_in[0];
  const int*   response = (const int*)d_in[1];
  const float* mask     = (const float*)d_in[2];
  const float* k_emb    = (const float*)d_in[3];
  const float* v_emb    = (const float*)d_in[4];
  const float* Mk       = (const float*)d_in[5];
  const float* Mv0      = (const float*)d_in[6];
  const float* e_W      = (const float*)d_in[7];
  const float* e_b      = (const float*)d_in[8];
  const float* a_W      = (const float*)d_in[9];
  const float* a_b      = (const float*)d_in[10];
  const float* f_W      = (const float*)d_in[11];
  const float* f_b      = (const float*)d_in[12];
  const float* p_W      = (const float*)d_in[13];
  const float* p_b      = (const float*)d_in[14];
  float* out = (float*)d_out;

  // workspace layout (floats)
  const size_t wN  = (size_t)BB * TT * WPAD;       // 1,703,936
  const size_t eN  = (size_t)BB * TT * 64;         // 2,097,152
  const size_t r2N = 2ull * BB * (TT - 1) * 64;    // 4,186,112
  float* ws = (float*)d_ws;
  float* w_buf  = ws;
  float* e_buf  = w_buf + wN;
  float* a_buf  = e_buf + eN;
  float* read2  = a_buf + eN;
  float* AB_arr = read2 + r2N;
  const size_t baseN = wN + 2 * eN + r2N;          // 10,084,352 floats

  // choose the largest chunk count C that fits the workspace
  int C = 32, logC = 5;
  while (C >= 2) {
    const size_t need = (baseN + 9600ull * BB * C) * sizeof(float);
    if (need <= ws_size) break;
    C >>= 1; logC -= 1;
  }
  int useChunks = (C >= 2);
  if (!useChunks) { C = 1; logC = 0; }
  const int L = TT / C;
  float* entry = AB_arr + 6400ull * BB * C;

  hipLaunchKernelGGL(kPre, dim3(2048), dim3(256), 0, stream,
                     question, response, mask, k_emb, v_emb, Mk,
                     e_W, e_b, a_W, a_b, w_buf, e_buf, a_buf);

  if (C == 32) {
    hipLaunchKernelGGL(kA16, dim3(1024), dim3(256), 0, stream,
                       w_buf, e_buf, a_buf, AB_arr);
    hipLaunchKernelGGL(kB_entry, dim3((BB * MM * 64 + 255) / 256), dim3(256),
                       0, stream, AB_arr, Mv0, entry, C);
    hipLaunchKernelGGL(kC16, dim3(1024), dim3(256), 0, stream,
                       w_buf, e_buf, a_buf, entry, read2);
  } else {
    if (useChunks) {
      const int ublocksA = (BB * C * 2 + 3) / 4;
      hipLaunchKernelGGL(kA_chunk, dim3(ublocksA), dim3(256), 0, stream,
                         w_buf, e_buf, a_buf, AB_arr, logC, L);
      hipLaunchKernelGGL(kB_entry, dim3((BB * MM * 64 + 255) / 256), dim3(256),
                         0, stream, AB_arr, Mv0, entry, C);
    }
    const int ublocksC = (BB * C * 2 + 3) / 4;
    hipLaunchKernelGGL(kC_read, dim3(ublocksC), dim3(256), 0, stream,
                       w_buf, e_buf, a_buf, entry, Mv0, read2,
                       logC, L, useChunks ? 0 : 1);
  }

  hipLaunchKernelGGL(k3_out, dim3(1024), dim3(256), 0, stream,
                     question, k_emb, read2, f_W, f_b, p_W, p_b, out);
}

// Round 14
// 192.265 us; speedup vs baseline: 1.6159x; 1.0129x over previous
//
#include <hip/hip_runtime.h>
#include <cstddef>

// Problem constants (from reference)
#define QN 10000
#define DD 64
#define MM 50
#define BB 64
#define TT 512
#define WPAD 52   // padded w row stride in floats (208 B -> 16B-aligned rows)
#define MG 25     // m's per wave in the 2-way m-split scan kernels

// Pin a float array in VGPRs (k3 only; proven -17us there in R9).
#define PIN(arr, n)                                        \
  _Pragma("unroll") for (int _p = 0; _p < (n); ++_p)       \
      asm volatile("" : "+v"((arr)[_p]));

// ===========================================================================
// kPre: R6 structure; e/a roles use float4 row loads (16 s_loadx4/row
// instead of 32 s_loadx2 -- half the SMEM issue slots; w-role already
// float4). Accumulator pairing preserved exactly (bit-identical).
// ===========================================================================
__global__ __launch_bounds__(256) void kPre(
    const int* __restrict__ question, const int* __restrict__ response,
    const float* __restrict__ mask,
    const float* __restrict__ k_emb, const float* __restrict__ v_emb,
    const float* __restrict__ Mk,
    const float* __restrict__ e_W, const float* __restrict__ e_b,
    const float* __restrict__ a_W, const float* __restrict__ a_b,
    float* __restrict__ w_buf, float* __restrict__ e_buf,
    float* __restrict__ a_buf) {
  const int lane = (int)(threadIdx.x & 63);
  const int wslot = __builtin_amdgcn_readfirstlane((int)(threadIdx.x >> 6));
  const int gw = blockIdx.x * 4 + wslot;
  const int NW = gridDim.x * 4;
  const int third = NW / 3;
  if (gw >= 3 * third) return;
  const int role = gw / third;
  const int idx = gw - role * third;
  const int stride4 = third * 4;

  if (role == 0) {                        // ---- role: w (softmax), 4 rows/iter
    float mk[64];
    const int mrow = lane < MM ? lane : (MM - 1);
#pragma unroll
    for (int i = 0; i < 64; i += 4) {
      const float4 t4 = *(const float4*)(Mk + mrow * 64 + i);
      mk[i] = t4.x; mk[i + 1] = t4.y; mk[i + 2] = t4.z; mk[i + 3] = t4.w;
    }
    for (int base = idx * 4; base < BB * TT; base += stride4) {
      const int4 q4 = *(const int4*)(question + base);   // 4 indices, 1 load
      const float* __restrict__ kr0 = k_emb + (size_t)q4.x * 64;
      const float* __restrict__ kr1 = k_emb + (size_t)q4.y * 64;
      const float* __restrict__ kr2 = k_emb + (size_t)q4.z * 64;
      const float* __restrict__ kr3 = k_emb + (size_t)q4.w * 64;
      float l00=0.f,l01=0.f,l02=0.f,l03=0.f;   // row 0, 4-way split
      float l10=0.f,l11=0.f,l12=0.f,l13=0.f;   // row 1
      float l20=0.f,l21=0.f,l22=0.f,l23=0.f;   // row 2
      float l30=0.f,l31=0.f,l32=0.f,l33=0.f;   // row 3
#pragma unroll
      for (int i = 0; i < 64; i += 4) {
        const float4 k0 = *(const float4*)(kr0 + i);     // 4 independent
        const float4 k1 = *(const float4*)(kr1 + i);     // s_load chains
        const float4 k2 = *(const float4*)(kr2 + i);
        const float4 k3 = *(const float4*)(kr3 + i);
        l00 = fmaf(k0.x, mk[i], l00); l01 = fmaf(k0.y, mk[i+1], l01);
        l02 = fmaf(k0.z, mk[i+2], l02); l03 = fmaf(k0.w, mk[i+3], l03);
        l10 = fmaf(k1.x, mk[i], l10); l11 = fmaf(k1.y, mk[i+1], l11);
        l12 = fmaf(k1.z, mk[i+2], l12); l13 = fmaf(k1.w, mk[i+3], l13);
        l20 = fmaf(k2.x, mk[i], l20); l21 = fmaf(k2.y, mk[i+1], l21);
        l22 = fmaf(k2.z, mk[i+2], l22); l23 = fmaf(k2.w, mk[i+3], l23);
        l30 = fmaf(k3.x, mk[i], l30); l31 = fmaf(k3.y, mk[i+1], l31);
        l32 = fmaf(k3.z, mk[i+2], l32); l33 = fmaf(k3.w, mk[i+3], l33);
      }
      float lm[4];
      lm[0] = (l00 + l01) + (l02 + l03);
      lm[1] = (l10 + l11) + (l12 + l13);
      lm[2] = (l20 + l21) + (l22 + l23);
      lm[3] = (l30 + l31) + (l32 + l33);
#pragma unroll
      for (int r = 0; r < 4; ++r) {
        float lv = (lane < MM) ? lm[r] : -3.4e38f;
#pragma unroll
        for (int off = 32; off > 0; off >>= 1) lv = fmaxf(lv, __shfl_xor(lv, off));
        float pe = (lane < MM) ? __expf(lm[r] - lv) : 0.f;
        float ss = pe;
#pragma unroll
        for (int off = 32; off > 0; off >>= 1) ss += __shfl_xor(ss, off);
        if (lane < MM) w_buf[(size_t)(base + r) * WPAD + lane] = pe / ss;
      }
    }
  } else if (role == 1) {                 // ---- role: e, 4 rows/iter, float4
    float ew[64];
#pragma unroll
    for (int i = 0; i < 64; ++i) ew[i] = e_W[i * 64 + lane];
    const float eb = e_b[lane];
    for (int base = idx * 4; base < BB * TT; base += stride4) {
      const int4 q4 = *(const int4*)(question + base);
      const int4 r4 = *(const int4*)(response + base);
      const float4 m4 = *(const float4*)(mask + base);
      const float* __restrict__ v0 = v_emb + ((size_t)q4.x + (size_t)QN * r4.x) * 64;
      const float* __restrict__ v1 = v_emb + ((size_t)q4.y + (size_t)QN * r4.y) * 64;
      const float* __restrict__ v2 = v_emb + ((size_t)q4.z + (size_t)QN * r4.z) * 64;
      const float* __restrict__ v3 = v_emb + ((size_t)q4.w + (size_t)QN * r4.w) * 64;
      float e00 = eb, e01 = 0.f, e10 = eb, e11 = 0.f;
      float e20 = eb, e21 = 0.f, e30 = eb, e31 = 0.f;
#pragma unroll
      for (int i = 0; i < 64; i += 4) {
        const float4 a0 = *(const float4*)(v0 + i);      // 4 independent
        const float4 a1 = *(const float4*)(v1 + i);      // s_loadx4 chains
        const float4 a2 = *(const float4*)(v2 + i);
        const float4 a3 = *(const float4*)(v3 + i);
        e00 = fmaf(a0.x, ew[i], e00);     e01 = fmaf(a0.y, ew[i + 1], e01);
        e00 = fmaf(a0.z, ew[i + 2], e00); e01 = fmaf(a0.w, ew[i + 3], e01);
        e10 = fmaf(a1.x, ew[i], e10);     e11 = fmaf(a1.y, ew[i + 1], e11);
        e10 = fmaf(a1.z, ew[i + 2], e10); e11 = fmaf(a1.w, ew[i + 3], e11);
        e20 = fmaf(a2.x, ew[i], e20);     e21 = fmaf(a2.y, ew[i + 1], e21);
        e20 = fmaf(a2.z, ew[i + 2], e20); e21 = fmaf(a2.w, ew[i + 3], e21);
        e30 = fmaf(a3.x, ew[i], e30);     e31 = fmaf(a3.y, ew[i + 1], e31);
        e30 = fmaf(a3.z, ew[i + 2], e30); e31 = fmaf(a3.w, ew[i + 3], e31);
      }
      const float mf0 = (m4.x == 1.0f) ? 1.0f : 0.0f;
      const float mf1 = (m4.y == 1.0f) ? 1.0f : 0.0f;
      const float mf2 = (m4.z == 1.0f) ? 1.0f : 0.0f;
      const float mf3 = (m4.w == 1.0f) ? 1.0f : 0.0f;
      e_buf[(size_t)(base + 0) * 64 + lane] = mf0 / (1.f + __expf(-(e00 + e01)));
      e_buf[(size_t)(base + 1) * 64 + lane] = mf1 / (1.f + __expf(-(e10 + e11)));
      e_buf[(size_t)(base + 2) * 64 + lane] = mf2 / (1.f + __expf(-(e20 + e21)));
      e_buf[(size_t)(base + 3) * 64 + lane] = mf3 / (1.f + __expf(-(e30 + e31)));
    }
  } else {                                // ---- role: a, 4 rows/iter, float4
    float aw[64];
#pragma unroll
    for (int i = 0; i < 64; ++i) aw[i] = a_W[i * 64 + lane];
    const float ab = a_b[lane];
    for (int base = idx * 4; base < BB * TT; base += stride4) {
      const int4 q4 = *(const int4*)(question + base);
      const int4 r4 = *(const int4*)(response + base);
      const float4 m4 = *(const float4*)(mask + base);
      const float* __restrict__ v0 = v_emb + ((size_t)q4.x + (size_t)QN * r4.x) * 64;
      const float* __restrict__ v1 = v_emb + ((size_t)q4.y + (size_t)QN * r4.y) * 64;
      const float* __restrict__ v2 = v_emb + ((size_t)q4.z + (size_t)QN * r4.z) * 64;
      const float* __restrict__ v3 = v_emb + ((size_t)q4.w + (size_t)QN * r4.w) * 64;
      float a00 = ab, a01 = 0.f, a10 = ab, a11 = 0.f;
      float a20 = ab, a21 = 0.f, a30 = ab, a31 = 0.f;
#pragma unroll
      for (int i = 0; i < 64; i += 4) {
        const float4 x0 = *(const float4*)(v0 + i);
        const float4 x1 = *(const float4*)(v1 + i);
        const float4 x2 = *(const float4*)(v2 + i);
        const float4 x3 = *(const float4*)(v3 + i);
        a00 = fmaf(x0.x, aw[i], a00);     a01 = fmaf(x0.y, aw[i + 1], a01);
        a00 = fmaf(x0.z, aw[i + 2], a00); a01 = fmaf(x0.w, aw[i + 3], a01);
        a10 = fmaf(x1.x, aw[i], a10);     a11 = fmaf(x1.y, aw[i + 1], a11);
        a10 = fmaf(x1.z, aw[i + 2], a10); a11 = fmaf(x1.w, aw[i + 3], a11);
        a20 = fmaf(x2.x, aw[i], a20);     a21 = fmaf(x2.y, aw[i + 1], a21);
        a20 = fmaf(x2.z, aw[i + 2], a20); a21 = fmaf(x2.w, aw[i + 3], a21);
        a30 = fmaf(x3.x, aw[i], a30);     a31 = fmaf(x3.y, aw[i + 1], a31);
        a30 = fmaf(x3.z, aw[i + 2], a30); a31 = fmaf(x3.w, aw[i + 3], a31);
      }
      const float mf0 = (m4.x == 1.0f) ? 1.0f : 0.0f;
      const float mf1 = (m4.y == 1.0f) ? 1.0f : 0.0f;
      const float mf2 = (m4.z == 1.0f) ? 1.0f : 0.0f;
      const float mf3 = (m4.w == 1.0f) ? 1.0f : 0.0f;
      const float s0 = a00 + a01, s1 = a10 + a11, s2 = a20 + a21, s3 = a30 + a31;
      a_buf[(size_t)(base + 0) * 64 + lane] = mf0 * (1.f - 2.f / (__expf(2.f * s0) + 1.f));
      a_buf[(size_t)(base + 1) * 64 + lane] = mf1 * (1.f - 2.f / (__expf(2.f * s1) + 1.f));
      a_buf[(size_t)(base + 2) * 64 + lane] = mf2 * (1.f - 2.f / (__expf(2.f * s2) + 1.f));
      a_buf[(size_t)(base + 3) * 64 + lane] = mf3 * (1.f - 2.f / (__expf(2.f * s3) + 1.f));
    }
  }
}

// ===========================================================================
// W-tile staging helper (kA16/kC16) -- R12 verbatim (kept: small win).
// ===========================================================================
#define STAGE_W(wl_row, rowbase)                                            \
  {                                                                         \
    const float* __restrict__ wsrc = w_buf + (rowbase) * WPAD;              \
    _Pragma("unroll") for (int k = 0; k < 13; ++k) {                        \
      const int idx = lane + k * 64;               /* 0..831 */             \
      const int row = idx / 52;                                             \
      const int col = idx - row * 52;                                       \
      (wl_row)[row * 56 + col + (col >= 25 ? 3 : 0)] = wsrc[idx];           \
    }                                                                       \
  }

#define LOAD_WM(wm, wl_row, j, g)                                           \
  const float* __restrict__ wj_##j = (wl_row) + (j) * 56 + (g) * 28;        \
  const float4 q0_##j = *(const float4*)(wj_##j + 0);                       \
  const float4 q1_##j = *(const float4*)(wj_##j + 4);                       \
  const float4 q2_##j = *(const float4*)(wj_##j + 8);                       \
  const float4 q3_##j = *(const float4*)(wj_##j + 12);                      \
  const float4 q4_##j = *(const float4*)(wj_##j + 16);                      \
  const float4 q5_##j = *(const float4*)(wj_##j + 20);                      \
  const float4 q6_##j = *(const float4*)(wj_##j + 24);                      \
  const float wm[MG] = {q0_##j.x, q0_##j.y, q0_##j.z, q0_##j.w,             \
                        q1_##j.x, q1_##j.y, q1_##j.z, q1_##j.w,             \
                        q2_##j.x, q2_##j.y, q2_##j.z, q2_##j.w,             \
                        q3_##j.x, q3_##j.y, q3_##j.z, q3_##j.w,             \
                        q4_##j.x, q4_##j.y, q4_##j.z, q4_##j.w,             \
                        q5_##j.x, q5_##j.y, q5_##j.z, q5_##j.w, q6_##j.x};

// ===========================================================================
// kA16: C=32 compose, w from staged LDS. (R12 verbatim)
// ===========================================================================
__global__ __launch_bounds__(256) void kA16(
    const float* __restrict__ w_buf, const float* __restrict__ e_buf,
    const float* __restrict__ a_buf, float* __restrict__ AB) {
  __shared__ float wl[4][16 * 56];                     // 14,336 B
  const int lane = (int)(threadIdx.x & 63);
  const int wslot = __builtin_amdgcn_readfirstlane((int)(threadIdx.x >> 6));
  const int u2 = blockIdx.x * 4 + wslot;
  if (u2 >= BB * 32 * 2) return;
  const int g = u2 & 1;
  const int unit = u2 >> 1;                            // b*32 + c
  const int b = unit >> 5;
  const int c = unit & 31;
  const size_t rowbase = (size_t)b * TT + c * 16;
  const size_t eb0 = rowbase * 64 + lane;

  float ev[16], av[16];
#pragma unroll
  for (int j = 0; j < 16; ++j) {
    ev[j] = e_buf[eb0 + (size_t)j * 64];
    av[j] = a_buf[eb0 + (size_t)j * 64];
  }
  STAGE_W(wl[wslot], rowbase)                          // wave-private: no barrier

  float Am[MG], Bm[MG];
#pragma unroll
  for (int m = 0; m < MG; ++m) { Am[m] = 1.f; Bm[m] = 0.f; }

#pragma unroll
  for (int j = 0; j < 16; ++j) {
    LOAD_WM(wm, wl[wslot], j, g)
#pragma unroll
    for (int m = 0; m < MG; ++m) {
      const float al = fmaf(-wm[m], ev[j], 1.0f);
      const float be = wm[m] * av[j];
      Am[m] *= al;
      Bm[m] = fmaf(Bm[m], al, be);
    }
  }
  float* __restrict__ abp = AB + (size_t)unit * 6400 + (g * MG) * 128 + lane * 2;
#pragma unroll
  for (int m = 0; m < MG; ++m) {
    float2 o; o.x = Am[m]; o.y = Bm[m];
    *(float2*)(abp + m * 128) = o;
  }
}

// ===========================================================================
// kB: sequential over C chunks, parallel over B*M*D. (R12 verbatim)
// ===========================================================================
__global__ __launch_bounds__(256) void kB_entry(
    const float* __restrict__ AB, const float* __restrict__ Mv0,
    float* __restrict__ entry, int C) {
  const int NT = gridDim.x * 256;
  for (int idx = blockIdx.x * 256 + (int)threadIdx.x; idx < BB * MM * 64;
       idx += NT) {
    const int b = idx / (MM * 64);
    const int r = idx - b * (MM * 64);                 // m*64 + d
    float s = Mv0[r];
    const float* __restrict__ abp = AB + (size_t)b * C * 6400 + (size_t)r * 2;
    float* __restrict__ ep = entry + (size_t)b * C * 3200 + r;
    if (C == 32) {
      float2 ab[32];
#pragma unroll
      for (int c = 0; c < 32; ++c)
        ab[c] = *(const float2*)(abp + (size_t)c * 6400);
#pragma unroll
      for (int c = 0; c < 32; ++c) {
        ep[(size_t)c * 3200] = s;
        s = fmaf(ab[c].x, s, ab[c].y);
      }
    } else {
      float2 cur = *(const float2*)(abp);
      for (int c = 0; c < C; ++c) {
        ep[(size_t)c * 3200] = s;
        float2 nxt; nxt.x = 1.f; nxt.y = 0.f;
        if (c + 1 < C) nxt = *(const float2*)(abp + (size_t)(c + 1) * 6400);
        s = fmaf(cur.x, s, cur.y);
        cur = nxt;
      }
    }
  }
}

// ===========================================================================
// kC16: C=32 replay, w from staged LDS. (R12 verbatim)
// ===========================================================================
__global__ __launch_bounds__(256) void kC16(
    const float* __restrict__ w_buf, const float* __restrict__ e_buf,
    const float* __restrict__ a_buf, const float* __restrict__ entry,
    float* __restrict__ read2) {
  __shared__ float wl[4][16 * 56];                     // 14,336 B
  const int lane = (int)(threadIdx.x & 63);
  const int wslot = __builtin_amdgcn_readfirstlane((int)(threadIdx.x >> 6));
  const int u2 = blockIdx.x * 4 + wslot;
  if (u2 >= BB * 32 * 2) return;
  const int g = u2 & 1;
  const int unit = u2 >> 1;                            // b*32 + c
  const int b = unit >> 5;
  const int c = unit & 31;
  const size_t RN = (size_t)BB * (TT - 1) * 64;
  const size_t rowbase = (size_t)b * TT + c * 16;
  const size_t eb0 = rowbase * 64 + lane;

  float ev[16], av[16];
#pragma unroll
  for (int j = 0; j < 16; ++j) {
    ev[j] = e_buf[eb0 + (size_t)j * 64];
    av[j] = a_buf[eb0 + (size_t)j * 64];
  }
  float s[MG];
  {
    const float* __restrict__ ep =
        entry + (size_t)unit * 3200 + (g * MG) * 64 + lane;
#pragma unroll
    for (int m = 0; m < MG; ++m) s[m] = ep[m * 64];    // 25 independent loads
  }
  STAGE_W(wl[wslot], rowbase)                          // wave-private: no barrier

  const int t0 = c * 16;
  float* __restrict__ rb = read2 + (size_t)g * RN;
#pragma unroll
  for (int j = 0; j < 16; ++j) {
    const int t = t0 + j;
    LOAD_WM(wm, wl[wslot], j, g)
    if (t >= 1) {                                      // false only c==0,j==0
      float a0 = 0.f, a1 = 0.f;
#pragma unroll
      for (int m = 0; m < MG - 1; m += 2) {
        a0 = fmaf(wm[m], s[m], a0);
        a1 = fmaf(wm[m + 1], s[m + 1], a1);
      }
      a0 = fmaf(wm[MG - 1], s[MG - 1], a0);            // MG=25 is odd
      rb[((size_t)b * (TT - 1) + (t - 1)) * 64 + lane] = a0 + a1;
    }
#pragma unroll
    for (int m = 0; m < MG; ++m)
      s[m] = fmaf(wm[m], fmaf(-s[m], ev[j], av[j]), s[m]);
  }
}

// ===========================================================================
// Generic fallback scan kernels (used only if C != 32). (R12 verbatim)
// ===========================================================================
__global__ __launch_bounds__(256) void kA_chunk(
    const float* __restrict__ w_buf, const float* __restrict__ e_buf,
    const float* __restrict__ a_buf, float* __restrict__ AB, int logC, int L) {
  const int lane = (int)(threadIdx.x & 63);
  const int wslot = __builtin_amdgcn_readfirstlane((int)(threadIdx.x >> 6));
  const int NW = gridDim.x * 4;
  const int C = 1 << logC;
  for (int u2 = blockIdx.x * 4 + wslot; u2 < BB * C * 2; u2 += NW) {
    const int g = u2 & 1;
    const int unit = u2 >> 1;
    const int b = unit >> logC;
    const int c = unit & (C - 1);
    float Am[MG], Bm[MG];
#pragma unroll
    for (int m = 0; m < MG; ++m) { Am[m] = 1.f; Bm[m] = 0.f; }
    const size_t rowbase = (size_t)b * TT + c * L;
#pragma unroll 2
    for (int j = 0; j < L; ++j) {
      const size_t row = rowbase + j;
      const float ed = e_buf[row * 64 + lane];
      const float ad = a_buf[row * 64 + lane];
      const float* __restrict__ wr = w_buf + row * WPAD + g * MG;
#pragma unroll
      for (int m = 0; m < MG; ++m) {
        const float wm = wr[m];
        const float al = fmaf(-wm, ed, 1.0f);
        const float be = wm * ad;
        Am[m] *= al;
        Bm[m] = fmaf(Bm[m], al, be);
      }
    }
    float* __restrict__ abp = AB + (size_t)unit * 6400 + (g * MG) * 128 + lane * 2;
#pragma unroll
    for (int m = 0; m < MG; ++m) {
      float2 o; o.x = Am[m]; o.y = Bm[m];
      *(float2*)(abp + m * 128) = o;
    }
  }
}

__global__ __launch_bounds__(256) void kC_read(
    const float* __restrict__ w_buf, const float* __restrict__ e_buf,
    const float* __restrict__ a_buf, const float* __restrict__ entry,
    const float* __restrict__ Mv0, float* __restrict__ read2,
    int logC, int L, int use_mv0) {
  const int lane = (int)(threadIdx.x & 63);
  const int wslot = __builtin_amdgcn_readfirstlane((int)(threadIdx.x >> 6));
  const int NW = gridDim.x * 4;
  const int C = 1 << logC;
  const size_t RN = (size_t)BB * (TT - 1) * 64;
  for (int u2 = blockIdx.x * 4 + wslot; u2 < BB * C * 2; u2 += NW) {
    const int g = u2 & 1;
    const int unit = u2 >> 1;
    const int b = unit >> logC;
    const int c = unit & (C - 1);
    float s[MG];
    if (use_mv0) {
#pragma unroll
      for (int m = 0; m < MG; ++m) s[m] = Mv0[(g * MG + m) * 64 + lane];
    } else {
      const float* __restrict__ ep =
          entry + (size_t)unit * 3200 + (g * MG) * 64 + lane;
#pragma unroll
      for (int m = 0; m < MG; ++m) s[m] = ep[m * 64];
    }
    const int t0 = c * L;
    float* __restrict__ rb = read2 + (size_t)g * RN;
    for (int j = 0; j < L; ++j) {
      const int t = t0 + j;
      const size_t row = (size_t)b * TT + t;
      const float ed = e_buf[row * 64 + lane];
      const float ad = a_buf[row * 64 + lane];
      const float* __restrict__ wr = w_buf + row * WPAD + g * MG;
      if (t >= 1) {
        float a0 = 0.f, a1 = 0.f;
#pragma unroll
        for (int m = 0; m < MG - 1; m += 2) {
          a0 = fmaf(wr[m], s[m], a0);
          a1 = fmaf(wr[m + 1], s[m + 1], a1);
        }
        a0 = fmaf(wr[MG - 1], s[MG - 1], a0);
        rb[((size_t)b * (TT - 1) + (t - 1)) * 64 + lane] = a0 + a1;
      }
#pragma unroll
      for (int m = 0; m < MG; ++m)
        s[m] = fmaf(wr[m], fmaf(-s[m], ed, ad), s[m]);
    }
  }
}

// ===========================================================================
// k3: WAVE-PAIR split of the MLP (R2 phaseD pattern, correctness-proven).
// Wave g of a pair holds only fw[64] (g=0: read-half, g=1: k-half), halving
// VGPR (~150 -> ~95) so ~2x more waves are resident and the read2/k_emb
// latency is hidden. g=0 loads read2 (2 loads), g=1 loads question+k_emb
// gather -- load traffic split per wave. Partial dot exchanged via
// parity-double-buffered LDS; g=0 finishes tanh + p-dot + store.
// 1-deep cross-row prefetch kept from R9. __syncthreads is uniform: iters
// is grid-constant, every thread runs the same trip count.
// ===========================================================================
__global__ __launch_bounds__(256) void k3_out(
    const int* __restrict__ question, const float* __restrict__ k_emb,
    const float* __restrict__ read2,
    const float* __restrict__ f_W, const float* __restrict__ f_b,
    const float* __restrict__ p_W, const float* __restrict__ p_b,
    float* __restrict__ out) {
  __shared__ float pbuf[2][2][64];                     // [parity][pair][lane]
  __shared__ float stg[4][64];                         // per-wave staging
  const int lane = (int)(threadIdx.x & 63);
  const int ws = __builtin_amdgcn_readfirstlane((int)(threadIdx.x >> 6));
  const int pair = ws >> 1;                            // 0,1
  const int g = ws & 1;                                // 0: read-half, 1: k-half
  const int NP = gridDim.x * 2;                        // row-workers
  const size_t RN = (size_t)BB * (TT - 1) * 64;
  const int R = BB * (TT - 1);
  const int iters = (R + NP - 1) / NP;

  float fw[64];
#pragma unroll
  for (int i = 0; i < 64; ++i) fw[i] = f_W[(g * 64 + i) * 64 + lane];
  PIN(fw, 64)
  const float fb = f_b[lane];
  const float pw = p_W[lane];
  const float pb = p_b[0];

  int row = blockIdx.x * 2 + pair;
  float cur = 0.f;
  if (row < R) {                                       // prologue load
    if (g == 0) {
      cur = read2[(size_t)row * 64 + lane] + read2[RN + (size_t)row * 64 + lane];
    } else {
      const int b = row / (TT - 1);
      const int tp = row - b * (TT - 1);
      const int qn = question[b * TT + tp + 1];
      cur = k_emb[(size_t)qn * 64 + lane];
    }
  }
  for (int it = 0; it < iters; ++it) {
    const int nrow = row + NP;
    float nxt = 0.f;
    if (nrow < R) {                                    // issue next-row loads
      if (g == 0) {
        nxt = read2[(size_t)nrow * 64 + lane] +
              read2[RN + (size_t)nrow * 64 + lane];
      } else {
        const int nb = nrow / (TT - 1);
        const int ntp = nrow - nb * (TT - 1);
        const int nqn = question[nb * TT + ntp + 1];
        nxt = k_emb[(size_t)nqn * 64 + lane];
      }
    }
    const bool active = (row < R);
    float partial = 0.f;
    if (active) {
      stg[ws][lane] = cur;                             // wave-private slot
      float f0 = (g == 0) ? fb : 0.f, f1 = 0.f, f2 = 0.f, f3 = 0.f;
#pragma unroll
      for (int i = 0; i < 64; i += 4) {
        const float4 xv = *(const float4*)&stg[ws][i]; // LDS broadcast
        f0 = fmaf(xv.x, fw[i], f0);
        f1 = fmaf(xv.y, fw[i + 1], f1);
        f2 = fmaf(xv.z, fw[i + 2], f2);
        f3 = fmaf(xv.w, fw[i + 3], f3);
      }
      partial = (f0 + f1) + (f2 + f3);
    }
    const int pr = it & 1;                             // LDS parity dbuf
    if (active && g == 1) pbuf[pr][pair][lane] = partial;
    __syncthreads();
    if (active && g == 0) {
      const float f = partial + pbuf[pr][pair][lane];
      const float t2 = __expf(2.f * f);
      const float fv = 1.f - 2.f / (t2 + 1.f);         // tanh
      float acc = fv * pw;
#pragma unroll
      for (int off = 32; off > 0; off >>= 1) acc += __shfl_xor(acc, off);
      if (lane == 0) out[row] = acc + pb;
    }
    row = nrow; cur = nxt;
  }
}

// ---------------------------------------------------------------------------
extern "C" void kernel_launch(void* const* d_in, const int* in_sizes, int n_in,
                              void* d_out, int out_size, void* d_ws, size_t ws_size,
                              hipStream_t stream) {
  const int*   question = (const int*)d_in[0];
  const int*   response = (const int*)d_in[1];
  const float* mask     = (const float*)d_in[2];
  const float* k_emb    = (const float*)d_in[3];
  const float* v_emb    = (const float*)d_in[4];
  const float* Mk       = (const float*)d_in[5];
  const float* Mv0      = (const float*)d_in[6];
  const float* e_W      = (const float*)d_in[7];
  const float* e_b      = (const float*)d_in[8];
  const float* a_W      = (const float*)d_in[9];
  const float* a_b      = (const float*)d_in[10];
  const float* f_W      = (const float*)d_in[11];
  const float* f_b      = (const float*)d_in[12];
  const float* p_W      = (const float*)d_in[13];
  const float* p_b      = (const float*)d_in[14];
  float* out = (float*)d_out;

  // workspace layout (floats)
  const size_t wN  = (size_t)BB * TT * WPAD;       // 1,703,936
  const size_t eN  = (size_t)BB * TT * 64;         // 2,097,152
  const size_t r2N = 2ull * BB * (TT - 1) * 64;    // 4,186,112
  float* ws = (float*)d_ws;
  float* w_buf  = ws;
  float* e_buf  = w_buf + wN;
  float* a_buf  = e_buf + eN;
  float* read2  = a_buf + eN;
  float* AB_arr = read2 + r2N;
  const size_t baseN = wN + 2 * eN + r2N;          // 10,084,352 floats

  // choose the largest chunk count C that fits the workspace
  int C = 32, logC = 5;
  while (C >= 2) {
    const size_t need = (baseN + 9600ull * BB * C) * sizeof(float);
    if (need <= ws_size) break;
    C >>= 1; logC -= 1;
  }
  int useChunks = (C >= 2);
  if (!useChunks) { C = 1; logC = 0; }
  const int L = TT / C;
  float* entry = AB_arr + 6400ull * BB * C;

  hipLaunchKernelGGL(kPre, dim3(2048), dim3(256), 0, stream,
                     question, response, mask, k_emb, v_emb, Mk,
                     e_W, e_b, a_W, a_b, w_buf, e_buf, a_buf);

  if (C == 32) {
    hipLaunchKernelGGL(kA16, dim3(1024), dim3(256), 0, stream,
                       w_buf, e_buf, a_buf, AB_arr);
    hipLaunchKernelGGL(kB_entry, dim3((BB * MM * 64 + 255) / 256), dim3(256),
                       0, stream, AB_arr, Mv0, entry, C);
    hipLaunchKernelGGL(kC16, dim3(1024), dim3(256), 0, stream,
                       w_buf, e_buf, a_buf, entry, read2);
  } else {
    if (useChunks) {
      const int ublocksA = (BB * C * 2 + 3) / 4;
      hipLaunchKernelGGL(kA_chunk, dim3(ublocksA), dim3(256), 0, stream,
                         w_buf, e_buf, a_buf, AB_arr, logC, L);
      hipLaunchKernelGGL(kB_entry, dim3((BB * MM * 64 + 255) / 256), dim3(256),
                         0, stream, AB_arr, Mv0, entry, C);
    }
    const int ublocksC = (BB * C * 2 + 3) / 4;
    hipLaunchKernelGGL(kC_read, dim3(ublocksC), dim3(256), 0, stream,
                       w_buf, e_buf, a_buf, entry, Mv0, read2,
                       logC, L, useChunks ? 0 : 1);
  }

  hipLaunchKernelGGL(k3_out, dim3(1024), dim3(256), 0, stream,
                     question, k_emb, read2, f_W, f_b, p_W, p_b, out);
}

// Round 15
// 188.071 us; speedup vs baseline: 1.6519x; 1.0223x over previous
//
#include <hip/hip_runtime.h>
#include <cstddef>

// Problem constants (from reference)
#define QN 10000
#define DD 64
#define MM 50
#define BB 64
#define TT 512
#define WPAD 52   // padded w row stride in floats (208 B -> 16B-aligned rows)
#define MG 25     // m's per wave in the 2-way m-split scan kernels

// Pin a float array in VGPRs (k3 only; proven -17us there in R9).
#define PIN(arr, n)                                        \
  _Pragma("unroll") for (int _p = 0; _p < (n); ++_p)       \
      asm volatile("" : "+v"((arr)[_p]));

// ===========================================================================
// kPre: R14 version with REBALANCED roles: w:e:a = 4:3:3 (was 1/3 each).
// The w-role does ~1.3x the per-row work (softmax reduce + divide on top of
// the 64-fma dot), so equal thirds left w as the critical path (3x1.3=3.9
// units vs 3.0). 40/30/30 equalizes at ~3.3. Row->wave assignment only;
// per-row arithmetic bit-identical.
// ===========================================================================
__global__ __launch_bounds__(256) void kPre(
    const int* __restrict__ question, const int* __restrict__ response,
    const float* __restrict__ mask,
    const float* __restrict__ k_emb, const float* __restrict__ v_emb,
    const float* __restrict__ Mk,
    const float* __restrict__ e_W, const float* __restrict__ e_b,
    const float* __restrict__ a_W, const float* __restrict__ a_b,
    float* __restrict__ w_buf, float* __restrict__ e_buf,
    float* __restrict__ a_buf) {
  const int lane = (int)(threadIdx.x & 63);
  const int wslot = __builtin_amdgcn_readfirstlane((int)(threadIdx.x >> 6));
  const int gw = blockIdx.x * 4 + wslot;
  const int NW = gridDim.x * 4;
  const int wq = (NW * 2) / 5;            // 40% of waves -> w role
  const int eq = (NW * 3) / 10;           // 30% -> e role
  const int aq = NW - wq - eq;            // 30% -> a role

  if (gw < wq) {                          // ---- role: w (softmax), 4 rows/iter
    const int idx = gw;
    const int stride4 = wq * 4;
    float mk[64];
    const int mrow = lane < MM ? lane : (MM - 1);
#pragma unroll
    for (int i = 0; i < 64; i += 4) {
      const float4 t4 = *(const float4*)(Mk + mrow * 64 + i);
      mk[i] = t4.x; mk[i + 1] = t4.y; mk[i + 2] = t4.z; mk[i + 3] = t4.w;
    }
    for (int base = idx * 4; base < BB * TT; base += stride4) {
      const int4 q4 = *(const int4*)(question + base);   // 4 indices, 1 load
      const float* __restrict__ kr0 = k_emb + (size_t)q4.x * 64;
      const float* __restrict__ kr1 = k_emb + (size_t)q4.y * 64;
      const float* __restrict__ kr2 = k_emb + (size_t)q4.z * 64;
      const float* __restrict__ kr3 = k_emb + (size_t)q4.w * 64;
      float l00=0.f,l01=0.f,l02=0.f,l03=0.f;   // row 0, 4-way split
      float l10=0.f,l11=0.f,l12=0.f,l13=0.f;   // row 1
      float l20=0.f,l21=0.f,l22=0.f,l23=0.f;   // row 2
      float l30=0.f,l31=0.f,l32=0.f,l33=0.f;   // row 3
#pragma unroll
      for (int i = 0; i < 64; i += 4) {
        const float4 k0 = *(const float4*)(kr0 + i);     // 4 independent
        const float4 k1 = *(const float4*)(kr1 + i);     // s_load chains
        const float4 k2 = *(const float4*)(kr2 + i);
        const float4 k3 = *(const float4*)(kr3 + i);
        l00 = fmaf(k0.x, mk[i], l00); l01 = fmaf(k0.y, mk[i+1], l01);
        l02 = fmaf(k0.z, mk[i+2], l02); l03 = fmaf(k0.w, mk[i+3], l03);
        l10 = fmaf(k1.x, mk[i], l10); l11 = fmaf(k1.y, mk[i+1], l11);
        l12 = fmaf(k1.z, mk[i+2], l12); l13 = fmaf(k1.w, mk[i+3], l13);
        l20 = fmaf(k2.x, mk[i], l20); l21 = fmaf(k2.y, mk[i+1], l21);
        l22 = fmaf(k2.z, mk[i+2], l22); l23 = fmaf(k2.w, mk[i+3], l23);
        l30 = fmaf(k3.x, mk[i], l30); l31 = fmaf(k3.y, mk[i+1], l31);
        l32 = fmaf(k3.z, mk[i+2], l32); l33 = fmaf(k3.w, mk[i+3], l33);
      }
      float lm[4];
      lm[0] = (l00 + l01) + (l02 + l03);
      lm[1] = (l10 + l11) + (l12 + l13);
      lm[2] = (l20 + l21) + (l22 + l23);
      lm[3] = (l30 + l31) + (l32 + l33);
#pragma unroll
      for (int r = 0; r < 4; ++r) {
        float lv = (lane < MM) ? lm[r] : -3.4e38f;
#pragma unroll
        for (int off = 32; off > 0; off >>= 1) lv = fmaxf(lv, __shfl_xor(lv, off));
        float pe = (lane < MM) ? __expf(lm[r] - lv) : 0.f;
        float ss = pe;
#pragma unroll
        for (int off = 32; off > 0; off >>= 1) ss += __shfl_xor(ss, off);
        if (lane < MM) w_buf[(size_t)(base + r) * WPAD + lane] = pe / ss;
      }
    }
  } else if (gw < wq + eq) {              // ---- role: e, 4 rows/iter, float4
    const int idx = gw - wq;
    const int stride4 = eq * 4;
    float ew[64];
#pragma unroll
    for (int i = 0; i < 64; ++i) ew[i] = e_W[i * 64 + lane];
    const float eb = e_b[lane];
    for (int base = idx * 4; base < BB * TT; base += stride4) {
      const int4 q4 = *(const int4*)(question + base);
      const int4 r4 = *(const int4*)(response + base);
      const float4 m4 = *(const float4*)(mask + base);
      const float* __restrict__ v0 = v_emb + ((size_t)q4.x + (size_t)QN * r4.x) * 64;
      const float* __restrict__ v1 = v_emb + ((size_t)q4.y + (size_t)QN * r4.y) * 64;
      const float* __restrict__ v2 = v_emb + ((size_t)q4.z + (size_t)QN * r4.z) * 64;
      const float* __restrict__ v3 = v_emb + ((size_t)q4.w + (size_t)QN * r4.w) * 64;
      float e00 = eb, e01 = 0.f, e10 = eb, e11 = 0.f;
      float e20 = eb, e21 = 0.f, e30 = eb, e31 = 0.f;
#pragma unroll
      for (int i = 0; i < 64; i += 4) {
        const float4 a0 = *(const float4*)(v0 + i);      // 4 independent
        const float4 a1 = *(const float4*)(v1 + i);      // s_loadx4 chains
        const float4 a2 = *(const float4*)(v2 + i);
        const float4 a3 = *(const float4*)(v3 + i);
        e00 = fmaf(a0.x, ew[i], e00);     e01 = fmaf(a0.y, ew[i + 1], e01);
        e00 = fmaf(a0.z, ew[i + 2], e00); e01 = fmaf(a0.w, ew[i + 3], e01);
        e10 = fmaf(a1.x, ew[i], e10);     e11 = fmaf(a1.y, ew[i + 1], e11);
        e10 = fmaf(a1.z, ew[i + 2], e10); e11 = fmaf(a1.w, ew[i + 3], e11);
        e20 = fmaf(a2.x, ew[i], e20);     e21 = fmaf(a2.y, ew[i + 1], e21);
        e20 = fmaf(a2.z, ew[i + 2], e20); e21 = fmaf(a2.w, ew[i + 3], e21);
        e30 = fmaf(a3.x, ew[i], e30);     e31 = fmaf(a3.y, ew[i + 1], e31);
        e30 = fmaf(a3.z, ew[i + 2], e30); e31 = fmaf(a3.w, ew[i + 3], e31);
      }
      const float mf0 = (m4.x == 1.0f) ? 1.0f : 0.0f;
      const float mf1 = (m4.y == 1.0f) ? 1.0f : 0.0f;
      const float mf2 = (m4.z == 1.0f) ? 1.0f : 0.0f;
      const float mf3 = (m4.w == 1.0f) ? 1.0f : 0.0f;
      e_buf[(size_t)(base + 0) * 64 + lane] = mf0 / (1.f + __expf(-(e00 + e01)));
      e_buf[(size_t)(base + 1) * 64 + lane] = mf1 / (1.f + __expf(-(e10 + e11)));
      e_buf[(size_t)(base + 2) * 64 + lane] = mf2 / (1.f + __expf(-(e20 + e21)));
      e_buf[(size_t)(base + 3) * 64 + lane] = mf3 / (1.f + __expf(-(e30 + e31)));
    }
  } else {                                // ---- role: a, 4 rows/iter, float4
    const int idx = gw - wq - eq;
    const int stride4 = aq * 4;
    float aw[64];
#pragma unroll
    for (int i = 0; i < 64; ++i) aw[i] = a_W[i * 64 + lane];
    const float ab = a_b[lane];
    for (int base = idx * 4; base < BB * TT; base += stride4) {
      const int4 q4 = *(const int4*)(question + base);
      const int4 r4 = *(const int4*)(response + base);
      const float4 m4 = *(const float4*)(mask + base);
      const float* __restrict__ v0 = v_emb + ((size_t)q4.x + (size_t)QN * r4.x) * 64;
      const float* __restrict__ v1 = v_emb + ((size_t)q4.y + (size_t)QN * r4.y) * 64;
      const float* __restrict__ v2 = v_emb + ((size_t)q4.z + (size_t)QN * r4.z) * 64;
      const float* __restrict__ v3 = v_emb + ((size_t)q4.w + (size_t)QN * r4.w) * 64;
      float a00 = ab, a01 = 0.f, a10 = ab, a11 = 0.f;
      float a20 = ab, a21 = 0.f, a30 = ab, a31 = 0.f;
#pragma unroll
      for (int i = 0; i < 64; i += 4) {
        const float4 x0 = *(const float4*)(v0 + i);
        const float4 x1 = *(const float4*)(v1 + i);
        const float4 x2 = *(const float4*)(v2 + i);
        const float4 x3 = *(const float4*)(v3 + i);
        a00 = fmaf(x0.x, aw[i], a00);     a01 = fmaf(x0.y, aw[i + 1], a01);
        a00 = fmaf(x0.z, aw[i + 2], a00); a01 = fmaf(x0.w, aw[i + 3], a01);
        a10 = fmaf(x1.x, aw[i], a10);     a11 = fmaf(x1.y, aw[i + 1], a11);
        a10 = fmaf(x1.z, aw[i + 2], a10); a11 = fmaf(x1.w, aw[i + 3], a11);
        a20 = fmaf(x2.x, aw[i], a20);     a21 = fmaf(x2.y, aw[i + 1], a21);
        a20 = fmaf(x2.z, aw[i + 2], a20); a21 = fmaf(x2.w, aw[i + 3], a21);
        a30 = fmaf(x3.x, aw[i], a30);     a31 = fmaf(x3.y, aw[i + 1], a31);
        a30 = fmaf(x3.z, aw[i + 2], a30); a31 = fmaf(x3.w, aw[i + 3], a31);
      }
      const float mf0 = (m4.x == 1.0f) ? 1.0f : 0.0f;
      const float mf1 = (m4.y == 1.0f) ? 1.0f : 0.0f;
      const float mf2 = (m4.z == 1.0f) ? 1.0f : 0.0f;
      const float mf3 = (m4.w == 1.0f) ? 1.0f : 0.0f;
      const float s0 = a00 + a01, s1 = a10 + a11, s2 = a20 + a21, s3 = a30 + a31;
      a_buf[(size_t)(base + 0) * 64 + lane] = mf0 * (1.f - 2.f / (__expf(2.f * s0) + 1.f));
      a_buf[(size_t)(base + 1) * 64 + lane] = mf1 * (1.f - 2.f / (__expf(2.f * s1) + 1.f));
      a_buf[(size_t)(base + 2) * 64 + lane] = mf2 * (1.f - 2.f / (__expf(2.f * s2) + 1.f));
      a_buf[(size_t)(base + 3) * 64 + lane] = mf3 * (1.f - 2.f / (__expf(2.f * s3) + 1.f));
    }
  }
}

// ===========================================================================
// W-tile staging helper (kA16/kC16) -- R12 verbatim.
// ===========================================================================
#define STAGE_W(wl_row, rowbase)                                            \
  {                                                                         \
    const float* __restrict__ wsrc = w_buf + (rowbase) * WPAD;              \
    _Pragma("unroll") for (int k = 0; k < 13; ++k) {                        \
      const int idx = lane + k * 64;               /* 0..831 */             \
      const int row = idx / 52;                                             \
      const int col = idx - row * 52;                                       \
      (wl_row)[row * 56 + col + (col >= 25 ? 3 : 0)] = wsrc[idx];           \
    }                                                                       \
  }

#define LOAD_WM(wm, wl_row, j, g)                                           \
  const float* __restrict__ wj_##j = (wl_row) + (j) * 56 + (g) * 28;        \
  const float4 q0_##j = *(const float4*)(wj_##j + 0);                       \
  const float4 q1_##j = *(const float4*)(wj_##j + 4);                       \
  const float4 q2_##j = *(const float4*)(wj_##j + 8);                       \
  const float4 q3_##j = *(const float4*)(wj_##j + 12);                      \
  const float4 q4_##j = *(const float4*)(wj_##j + 16);                      \
  const float4 q5_##j = *(const float4*)(wj_##j + 20);                      \
  const float4 q6_##j = *(const float4*)(wj_##j + 24);                      \
  const float wm[MG] = {q0_##j.x, q0_##j.y, q0_##j.z, q0_##j.w,             \
                        q1_##j.x, q1_##j.y, q1_##j.z, q1_##j.w,             \
                        q2_##j.x, q2_##j.y, q2_##j.z, q2_##j.w,             \
                        q3_##j.x, q3_##j.y, q3_##j.z, q3_##j.w,             \
                        q4_##j.x, q4_##j.y, q4_##j.z, q4_##j.w,             \
                        q5_##j.x, q5_##j.y, q5_##j.z, q5_##j.w, q6_##j.x};

// ===========================================================================
// kA16: C=32 compose, w from staged LDS. (R12 verbatim)
// ===========================================================================
__global__ __launch_bounds__(256) void kA16(
    const float* __restrict__ w_buf, const float* __restrict__ e_buf,
    const float* __restrict__ a_buf, float* __restrict__ AB) {
  __shared__ float wl[4][16 * 56];                     // 14,336 B
  const int lane = (int)(threadIdx.x & 63);
  const int wslot = __builtin_amdgcn_readfirstlane((int)(threadIdx.x >> 6));
  const int u2 = blockIdx.x * 4 + wslot;
  if (u2 >= BB * 32 * 2) return;
  const int g = u2 & 1;
  const int unit = u2 >> 1;                            // b*32 + c
  const int b = unit >> 5;
  const int c = unit & 31;
  const size_t rowbase = (size_t)b * TT + c * 16;
  const size_t eb0 = rowbase * 64 + lane;

  float ev[16], av[16];
#pragma unroll
  for (int j = 0; j < 16; ++j) {
    ev[j] = e_buf[eb0 + (size_t)j * 64];
    av[j] = a_buf[eb0 + (size_t)j * 64];
  }
  STAGE_W(wl[wslot], rowbase)                          // wave-private: no barrier

  float Am[MG], Bm[MG];
#pragma unroll
  for (int m = 0; m < MG; ++m) { Am[m] = 1.f; Bm[m] = 0.f; }

#pragma unroll
  for (int j = 0; j < 16; ++j) {
    LOAD_WM(wm, wl[wslot], j, g)
#pragma unroll
    for (int m = 0; m < MG; ++m) {
      const float al = fmaf(-wm[m], ev[j], 1.0f);
      const float be = wm[m] * av[j];
      Am[m] *= al;
      Bm[m] = fmaf(Bm[m], al, be);
    }
  }
  float* __restrict__ abp = AB + (size_t)unit * 6400 + (g * MG) * 128 + lane * 2;
#pragma unroll
  for (int m = 0; m < MG; ++m) {
    float2 o; o.x = Am[m]; o.y = Bm[m];
    *(float2*)(abp + m * 128) = o;
  }
}

// ===========================================================================
// kB: sequential over C chunks, parallel over B*M*D. (R12 verbatim)
// ===========================================================================
__global__ __launch_bounds__(256) void kB_entry(
    const float* __restrict__ AB, const float* __restrict__ Mv0,
    float* __restrict__ entry, int C) {
  const int NT = gridDim.x * 256;
  for (int idx = blockIdx.x * 256 + (int)threadIdx.x; idx < BB * MM * 64;
       idx += NT) {
    const int b = idx / (MM * 64);
    const int r = idx - b * (MM * 64);                 // m*64 + d
    float s = Mv0[r];
    const float* __restrict__ abp = AB + (size_t)b * C * 6400 + (size_t)r * 2;
    float* __restrict__ ep = entry + (size_t)b * C * 3200 + r;
    if (C == 32) {
      float2 ab[32];
#pragma unroll
      for (int c = 0; c < 32; ++c)
        ab[c] = *(const float2*)(abp + (size_t)c * 6400);
#pragma unroll
      for (int c = 0; c < 32; ++c) {
        ep[(size_t)c * 3200] = s;
        s = fmaf(ab[c].x, s, ab[c].y);
      }
    } else {
      float2 cur = *(const float2*)(abp);
      for (int c = 0; c < C; ++c) {
        ep[(size_t)c * 3200] = s;
        float2 nxt; nxt.x = 1.f; nxt.y = 0.f;
        if (c + 1 < C) nxt = *(const float2*)(abp + (size_t)(c + 1) * 6400);
        s = fmaf(cur.x, s, cur.y);
        cur = nxt;
      }
    }
  }
}

// ===========================================================================
// kC16: C=32 replay, w from staged LDS. (R12 verbatim)
// ===========================================================================
__global__ __launch_bounds__(256) void kC16(
    const float* __restrict__ w_buf, const float* __restrict__ e_buf,
    const float* __restrict__ a_buf, const float* __restrict__ entry,
    float* __restrict__ read2) {
  __shared__ float wl[4][16 * 56];                     // 14,336 B
  const int lane = (int)(threadIdx.x & 63);
  const int wslot = __builtin_amdgcn_readfirstlane((int)(threadIdx.x >> 6));
  const int u2 = blockIdx.x * 4 + wslot;
  if (u2 >= BB * 32 * 2) return;
  const int g = u2 & 1;
  const int unit = u2 >> 1;                            // b*32 + c
  const int b = unit >> 5;
  const int c = unit & 31;
  const size_t RN = (size_t)BB * (TT - 1) * 64;
  const size_t rowbase = (size_t)b * TT + c * 16;
  const size_t eb0 = rowbase * 64 + lane;

  float ev[16], av[16];
#pragma unroll
  for (int j = 0; j < 16; ++j) {
    ev[j] = e_buf[eb0 + (size_t)j * 64];
    av[j] = a_buf[eb0 + (size_t)j * 64];
  }
  float s[MG];
  {
    const float* __restrict__ ep =
        entry + (size_t)unit * 3200 + (g * MG) * 64 + lane;
#pragma unroll
    for (int m = 0; m < MG; ++m) s[m] = ep[m * 64];    // 25 independent loads
  }
  STAGE_W(wl[wslot], rowbase)                          // wave-private: no barrier

  const int t0 = c * 16;
  float* __restrict__ rb = read2 + (size_t)g * RN;
#pragma unroll
  for (int j = 0; j < 16; ++j) {
    const int t = t0 + j;
    LOAD_WM(wm, wl[wslot], j, g)
    if (t >= 1) {                                      // false only c==0,j==0
      float a0 = 0.f, a1 = 0.f;
#pragma unroll
      for (int m = 0; m < MG - 1; m += 2) {
        a0 = fmaf(wm[m], s[m], a0);
        a1 = fmaf(wm[m + 1], s[m + 1], a1);
      }
      a0 = fmaf(wm[MG - 1], s[MG - 1], a0);            // MG=25 is odd
      rb[((size_t)b * (TT - 1) + (t - 1)) * 64 + lane] = a0 + a1;
    }
#pragma unroll
    for (int m = 0; m < MG; ++m)
      s[m] = fmaf(wm[m], fmaf(-s[m], ev[j], av[j]), s[m]);
  }
}

// ===========================================================================
// Generic fallback scan kernels (used only if C != 32). (R12 verbatim)
// ===========================================================================
__global__ __launch_bounds__(256) void kA_chunk(
    const float* __restrict__ w_buf, const float* __restrict__ e_buf,
    const float* __restrict__ a_buf, float* __restrict__ AB, int logC, int L) {
  const int lane = (int)(threadIdx.x & 63);
  const int wslot = __builtin_amdgcn_readfirstlane((int)(threadIdx.x >> 6));
  const int NW = gridDim.x * 4;
  const int C = 1 << logC;
  for (int u2 = blockIdx.x * 4 + wslot; u2 < BB * C * 2; u2 += NW) {
    const int g = u2 & 1;
    const int unit = u2 >> 1;
    const int b = unit >> logC;
    const int c = unit & (C - 1);
    float Am[MG], Bm[MG];
#pragma unroll
    for (int m = 0; m < MG; ++m) { Am[m] = 1.f; Bm[m] = 0.f; }
    const size_t rowbase = (size_t)b * TT + c * L;
#pragma unroll 2
    for (int j = 0; j < L; ++j) {
      const size_t row = rowbase + j;
      const float ed = e_buf[row * 64 + lane];
      const float ad = a_buf[row * 64 + lane];
      const float* __restrict__ wr = w_buf + row * WPAD + g * MG;
#pragma unroll
      for (int m = 0; m < MG; ++m) {
        const float wm = wr[m];
        const float al = fmaf(-wm, ed, 1.0f);
        const float be = wm * ad;
        Am[m] *= al;
        Bm[m] = fmaf(Bm[m], al, be);
      }
    }
    float* __restrict__ abp = AB + (size_t)unit * 6400 + (g * MG) * 128 + lane * 2;
#pragma unroll
    for (int m = 0; m < MG; ++m) {
      float2 o; o.x = Am[m]; o.y = Bm[m];
      *(float2*)(abp + m * 128) = o;
    }
  }
}

__global__ __launch_bounds__(256) void kC_read(
    const float* __restrict__ w_buf, const float* __restrict__ e_buf,
    const float* __restrict__ a_buf, const float* __restrict__ entry,
    const float* __restrict__ Mv0, float* __restrict__ read2,
    int logC, int L, int use_mv0) {
  const int lane = (int)(threadIdx.x & 63);
  const int wslot = __builtin_amdgcn_readfirstlane((int)(threadIdx.x >> 6));
  const int NW = gridDim.x * 4;
  const int C = 1 << logC;
  const size_t RN = (size_t)BB * (TT - 1) * 64;
  for (int u2 = blockIdx.x * 4 + wslot; u2 < BB * C * 2; u2 += NW) {
    const int g = u2 & 1;
    const int unit = u2 >> 1;
    const int b = unit >> logC;
    const int c = unit & (C - 1);
    float s[MG];
    if (use_mv0) {
#pragma unroll
      for (int m = 0; m < MG; ++m) s[m] = Mv0[(g * MG + m) * 64 + lane];
    } else {
      const float* __restrict__ ep =
          entry + (size_t)unit * 3200 + (g * MG) * 64 + lane;
#pragma unroll
      for (int m = 0; m < MG; ++m) s[m] = ep[m * 64];
    }
    const int t0 = c * L;
    float* __restrict__ rb = read2 + (size_t)g * RN;
    for (int j = 0; j < L; ++j) {
      const int t = t0 + j;
      const size_t row = (size_t)b * TT + t;
      const float ed = e_buf[row * 64 + lane];
      const float ad = a_buf[row * 64 + lane];
      const float* __restrict__ wr = w_buf + row * WPAD + g * MG;
      if (t >= 1) {
        float a0 = 0.f, a1 = 0.f;
#pragma unroll
        for (int m = 0; m < MG - 1; m += 2) {
          a0 = fmaf(wr[m], s[m], a0);
          a1 = fmaf(wr[m + 1], s[m + 1], a1);
        }
        a0 = fmaf(wr[MG - 1], s[MG - 1], a0);
        rb[((size_t)b * (TT - 1) + (t - 1)) * 64 + lane] = a0 + a1;
      }
#pragma unroll
      for (int m = 0; m < MG; ++m)
        s[m] = fmaf(wr[m], fmaf(-s[m], ed, ad), s[m]);
    }
  }
}

// ===========================================================================
// k3: R14 wave-pair version verbatim (measured best).
// ===========================================================================
__global__ __launch_bounds__(256) void k3_out(
    const int* __restrict__ question, const float* __restrict__ k_emb,
    const float* __restrict__ read2,
    const float* __restrict__ f_W, const float* __restrict__ f_b,
    const float* __restrict__ p_W, const float* __restrict__ p_b,
    float* __restrict__ out) {
  __shared__ float pbuf[2][2][64];                     // [parity][pair][lane]
  __shared__ float stg[4][64];                         // per-wave staging
  const int lane = (int)(threadIdx.x & 63);
  const int ws = __builtin_amdgcn_readfirstlane((int)(threadIdx.x >> 6));
  const int pair = ws >> 1;                            // 0,1
  const int g = ws & 1;                                // 0: read-half, 1: k-half
  const int NP = gridDim.x * 2;                        // row-workers
  const size_t RN = (size_t)BB * (TT - 1) * 64;
  const int R = BB * (TT - 1);
  const int iters = (R + NP - 1) / NP;

  float fw[64];
#pragma unroll
  for (int i = 0; i < 64; ++i) fw[i] = f_W[(g * 64 + i) * 64 + lane];
  PIN(fw, 64)
  const float fb = f_b[lane];
  const float pw = p_W[lane];
  const float pb = p_b[0];

  int row = blockIdx.x * 2 + pair;
  float cur = 0.f;
  if (row < R) {                                       // prologue load
    if (g == 0) {
      cur = read2[(size_t)row * 64 + lane] + read2[RN + (size_t)row * 64 + lane];
    } else {
      const int b = row / (TT - 1);
      const int tp = row - b * (TT - 1);
      const int qn = question[b * TT + tp + 1];
      cur = k_emb[(size_t)qn * 64 + lane];
    }
  }
  for (int it = 0; it < iters; ++it) {
    const int nrow = row + NP;
    float nxt = 0.f;
    if (nrow < R) {                                    // issue next-row loads
      if (g == 0) {
        nxt = read2[(size_t)nrow * 64 + lane] +
              read2[RN + (size_t)nrow * 64 + lane];
      } else {
        const int nb = nrow / (TT - 1);
        const int ntp = nrow - nb * (TT - 1);
        const int nqn = question[nb * TT + ntp + 1];
        nxt = k_emb[(size_t)nqn * 64 + lane];
      }
    }
    const bool active = (row < R);
    float partial = 0.f;
    if (active) {
      stg[ws][lane] = cur;                             // wave-private slot
      float f0 = (g == 0) ? fb : 0.f, f1 = 0.f, f2 = 0.f, f3 = 0.f;
#pragma unroll
      for (int i = 0; i < 64; i += 4) {
        const float4 xv = *(const float4*)&stg[ws][i]; // LDS broadcast
        f0 = fmaf(xv.x, fw[i], f0);
        f1 = fmaf(xv.y, fw[i + 1], f1);
        f2 = fmaf(xv.z, fw[i + 2], f2);
        f3 = fmaf(xv.w, fw[i + 3], f3);
      }
      partial = (f0 + f1) + (f2 + f3);
    }
    const int pr = it & 1;                             // LDS parity dbuf
    if (active && g == 1) pbuf[pr][pair][lane] = partial;
    __syncthreads();
    if (active && g == 0) {
      const float f = partial + pbuf[pr][pair][lane];
      const float t2 = __expf(2.f * f);
      const float fv = 1.f - 2.f / (t2 + 1.f);         // tanh
      float acc = fv * pw;
#pragma unroll
      for (int off = 32; off > 0; off >>= 1) acc += __shfl_xor(acc, off);
      if (lane == 0) out[row] = acc + pb;
    }
    row = nrow; cur = nxt;
  }
}

// ---------------------------------------------------------------------------
extern "C" void kernel_launch(void* const* d_in, const int* in_sizes, int n_in,
                              void* d_out, int out_size, void* d_ws, size_t ws_size,
                              hipStream_t stream) {
  const int*   question = (const int*)d_in[0];
  const int*   response = (const int*)d_in[1];
  const float* mask     = (const float*)d_in[2];
  const float* k_emb    = (const float*)d_in[3];
  const float* v_emb    = (const float*)d_in[4];
  const float* Mk       = (const float*)d_in[5];
  const float* Mv0      = (const float*)d_in[6];
  const float* e_W      = (const float*)d_in[7];
  const float* e_b      = (const float*)d_in[8];
  const float* a_W      = (const float*)d_in[9];
  const float* a_b      = (const float*)d_in[10];
  const float* f_W      = (const float*)d_in[11];
  const float* f_b      = (const float*)d_in[12];
  const float* p_W      = (const float*)d_in[13];
  const float* p_b      = (const float*)d_in[14];
  float* out = (float*)d_out;

  // workspace layout (floats)
  const size_t wN  = (size_t)BB * TT * WPAD;       // 1,703,936
  const size_t eN  = (size_t)BB * TT * 64;         // 2,097,152
  const size_t r2N = 2ull * BB * (TT - 1) * 64;    // 4,186,112
  float* ws = (float*)d_ws;
  float* w_buf  = ws;
  float* e_buf  = w_buf + wN;
  float* a_buf  = e_buf + eN;
  float* read2  = a_buf + eN;
  float* AB_arr = read2 + r2N;
  const size_t baseN = wN + 2 * eN + r2N;          // 10,084,352 floats

  // choose the largest chunk count C that fits the workspace
  int C = 32, logC = 5;
  while (C >= 2) {
    const size_t need = (baseN + 9600ull * BB * C) * sizeof(float);
    if (need <= ws_size) break;
    C >>= 1; logC -= 1;
  }
  int useChunks = (C >= 2);
  if (!useChunks) { C = 1; logC = 0; }
  const int L = TT / C;
  float* entry = AB_arr + 6400ull * BB * C;

  hipLaunchKernelGGL(kPre, dim3(2048), dim3(256), 0, stream,
                     question, response, mask, k_emb, v_emb, Mk,
                     e_W, e_b, a_W, a_b, w_buf, e_buf, a_buf);

  if (C == 32) {
    hipLaunchKernelGGL(kA16, dim3(1024), dim3(256), 0, stream,
                       w_buf, e_buf, a_buf, AB_arr);
    hipLaunchKernelGGL(kB_entry, dim3((BB * MM * 64 + 255) / 256), dim3(256),
                       0, stream, AB_arr, Mv0, entry, C);
    hipLaunchKernelGGL(kC16, dim3(1024), dim3(256), 0, stream,
                       w_buf, e_buf, a_buf, entry, read2);
  } else {
    if (useChunks) {
      const int ublocksA = (BB * C * 2 + 3) / 4;
      hipLaunchKernelGGL(kA_chunk, dim3(ublocksA), dim3(256), 0, stream,
                         w_buf, e_buf, a_buf, AB_arr, logC, L);
      hipLaunchKernelGGL(kB_entry, dim3((BB * MM * 64 + 255) / 256), dim3(256),
                         0, stream, AB_arr, Mv0, entry, C);
    }
    const int ublocksC = (BB * C * 2 + 3) / 4;
    hipLaunchKernelGGL(kC_read, dim3(ublocksC), dim3(256), 0, stream,
                       w_buf, e_buf, a_buf, entry, Mv0, read2,
                       logC, L, useChunks ? 0 : 1);
  }

  hipLaunchKernelGGL(k3_out, dim3(1024), dim3(256), 0, stream,
                     question, k_emb, read2, f_W, f_b, p_W, p_b, out);
}

// Round 16
// 181.154 us; speedup vs baseline: 1.7150x; 1.0382x over previous
//
#include <hip/hip_runtime.h>
#include <cstddef>

// Problem constants (from reference)
#define QN 10000
#define DD 64
#define MM 50
#define BB 64
#define TT 512
#define WPAD 52   // padded w row stride in floats (208 B -> 16B-aligned rows)
#define MG 25     // m's per wave in the 2-way m-split scan kernels

// Pin a float array in VGPRs (k3 only; proven -17us there in R9).
#define PIN(arr, n)                                        \
  _Pragma("unroll") for (int _p = 0; _p < (n); ++_p)       \
      asm volatile("" : "+v"((arr)[_p]));

// ===========================================================================
// kPre: R15 version verbatim (rebalanced roles w:e:a = 4:3:3, -4.2us).
// ===========================================================================
__global__ __launch_bounds__(256) void kPre(
    const int* __restrict__ question, const int* __restrict__ response,
    const float* __restrict__ mask,
    const float* __restrict__ k_emb, const float* __restrict__ v_emb,
    const float* __restrict__ Mk,
    const float* __restrict__ e_W, const float* __restrict__ e_b,
    const float* __restrict__ a_W, const float* __restrict__ a_b,
    float* __restrict__ w_buf, float* __restrict__ e_buf,
    float* __restrict__ a_buf) {
  const int lane = (int)(threadIdx.x & 63);
  const int wslot = __builtin_amdgcn_readfirstlane((int)(threadIdx.x >> 6));
  const int gw = blockIdx.x * 4 + wslot;
  const int NW = gridDim.x * 4;
  const int wq = (NW * 2) / 5;            // 40% of waves -> w role
  const int eq = (NW * 3) / 10;           // 30% -> e role
  const int aq = NW - wq - eq;            // 30% -> a role

  if (gw < wq) {                          // ---- role: w (softmax), 4 rows/iter
    const int idx = gw;
    const int stride4 = wq * 4;
    float mk[64];
    const int mrow = lane < MM ? lane : (MM - 1);
#pragma unroll
    for (int i = 0; i < 64; i += 4) {
      const float4 t4 = *(const float4*)(Mk + mrow * 64 + i);
      mk[i] = t4.x; mk[i + 1] = t4.y; mk[i + 2] = t4.z; mk[i + 3] = t4.w;
    }
    for (int base = idx * 4; base < BB * TT; base += stride4) {
      const int4 q4 = *(const int4*)(question + base);   // 4 indices, 1 load
      const float* __restrict__ kr0 = k_emb + (size_t)q4.x * 64;
      const float* __restrict__ kr1 = k_emb + (size_t)q4.y * 64;
      const float* __restrict__ kr2 = k_emb + (size_t)q4.z * 64;
      const float* __restrict__ kr3 = k_emb + (size_t)q4.w * 64;
      float l00=0.f,l01=0.f,l02=0.f,l03=0.f;   // row 0, 4-way split
      float l10=0.f,l11=0.f,l12=0.f,l13=0.f;   // row 1
      float l20=0.f,l21=0.f,l22=0.f,l23=0.f;   // row 2
      float l30=0.f,l31=0.f,l32=0.f,l33=0.f;   // row 3
#pragma unroll
      for (int i = 0; i < 64; i += 4) {
        const float4 k0 = *(const float4*)(kr0 + i);     // 4 independent
        const float4 k1 = *(const float4*)(kr1 + i);     // s_load chains
        const float4 k2 = *(const float4*)(kr2 + i);
        const float4 k3 = *(const float4*)(kr3 + i);
        l00 = fmaf(k0.x, mk[i], l00); l01 = fmaf(k0.y, mk[i+1], l01);
        l02 = fmaf(k0.z, mk[i+2], l02); l03 = fmaf(k0.w, mk[i+3], l03);
        l10 = fmaf(k1.x, mk[i], l10); l11 = fmaf(k1.y, mk[i+1], l11);
        l12 = fmaf(k1.z, mk[i+2], l12); l13 = fmaf(k1.w, mk[i+3], l13);
        l20 = fmaf(k2.x, mk[i], l20); l21 = fmaf(k2.y, mk[i+1], l21);
        l22 = fmaf(k2.z, mk[i+2], l22); l23 = fmaf(k2.w, mk[i+3], l23);
        l30 = fmaf(k3.x, mk[i], l30); l31 = fmaf(k3.y, mk[i+1], l31);
        l32 = fmaf(k3.z, mk[i+2], l32); l33 = fmaf(k3.w, mk[i+3], l33);
      }
      float lm[4];
      lm[0] = (l00 + l01) + (l02 + l03);
      lm[1] = (l10 + l11) + (l12 + l13);
      lm[2] = (l20 + l21) + (l22 + l23);
      lm[3] = (l30 + l31) + (l32 + l33);
#pragma unroll
      for (int r = 0; r < 4; ++r) {
        float lv = (lane < MM) ? lm[r] : -3.4e38f;
#pragma unroll
        for (int off = 32; off > 0; off >>= 1) lv = fmaxf(lv, __shfl_xor(lv, off));
        float pe = (lane < MM) ? __expf(lm[r] - lv) : 0.f;
        float ss = pe;
#pragma unroll
        for (int off = 32; off > 0; off >>= 1) ss += __shfl_xor(ss, off);
        if (lane < MM) w_buf[(size_t)(base + r) * WPAD + lane] = pe / ss;
      }
    }
  } else if (gw < wq + eq) {              // ---- role: e, 4 rows/iter, float4
    const int idx = gw - wq;
    const int stride4 = eq * 4;
    float ew[64];
#pragma unroll
    for (int i = 0; i < 64; ++i) ew[i] = e_W[i * 64 + lane];
    const float eb = e_b[lane];
    for (int base = idx * 4; base < BB * TT; base += stride4) {
      const int4 q4 = *(const int4*)(question + base);
      const int4 r4 = *(const int4*)(response + base);
      const float4 m4 = *(const float4*)(mask + base);
      const float* __restrict__ v0 = v_emb + ((size_t)q4.x + (size_t)QN * r4.x) * 64;
      const float* __restrict__ v1 = v_emb + ((size_t)q4.y + (size_t)QN * r4.y) * 64;
      const float* __restrict__ v2 = v_emb + ((size_t)q4.z + (size_t)QN * r4.z) * 64;
      const float* __restrict__ v3 = v_emb + ((size_t)q4.w + (size_t)QN * r4.w) * 64;
      float e00 = eb, e01 = 0.f, e10 = eb, e11 = 0.f;
      float e20 = eb, e21 = 0.f, e30 = eb, e31 = 0.f;
#pragma unroll
      for (int i = 0; i < 64; i += 4) {
        const float4 a0 = *(const float4*)(v0 + i);      // 4 independent
        const float4 a1 = *(const float4*)(v1 + i);      // s_loadx4 chains
        const float4 a2 = *(const float4*)(v2 + i);
        const float4 a3 = *(const float4*)(v3 + i);
        e00 = fmaf(a0.x, ew[i], e00);     e01 = fmaf(a0.y, ew[i + 1], e01);
        e00 = fmaf(a0.z, ew[i + 2], e00); e01 = fmaf(a0.w, ew[i + 3], e01);
        e10 = fmaf(a1.x, ew[i], e10);     e11 = fmaf(a1.y, ew[i + 1], e11);
        e10 = fmaf(a1.z, ew[i + 2], e10); e11 = fmaf(a1.w, ew[i + 3], e11);
        e20 = fmaf(a2.x, ew[i], e20);     e21 = fmaf(a2.y, ew[i + 1], e21);
        e20 = fmaf(a2.z, ew[i + 2], e20); e21 = fmaf(a2.w, ew[i + 3], e21);
        e30 = fmaf(a3.x, ew[i], e30);     e31 = fmaf(a3.y, ew[i + 1], e31);
        e30 = fmaf(a3.z, ew[i + 2], e30); e31 = fmaf(a3.w, ew[i + 3], e31);
      }
      const float mf0 = (m4.x == 1.0f) ? 1.0f : 0.0f;
      const float mf1 = (m4.y == 1.0f) ? 1.0f : 0.0f;
      const float mf2 = (m4.z == 1.0f) ? 1.0f : 0.0f;
      const float mf3 = (m4.w == 1.0f) ? 1.0f : 0.0f;
      e_buf[(size_t)(base + 0) * 64 + lane] = mf0 / (1.f + __expf(-(e00 + e01)));
      e_buf[(size_t)(base + 1) * 64 + lane] = mf1 / (1.f + __expf(-(e10 + e11)));
      e_buf[(size_t)(base + 2) * 64 + lane] = mf2 / (1.f + __expf(-(e20 + e21)));
      e_buf[(size_t)(base + 3) * 64 + lane] = mf3 / (1.f + __expf(-(e30 + e31)));
    }
  } else {                                // ---- role: a, 4 rows/iter, float4
    const int idx = gw - wq - eq;
    const int stride4 = aq * 4;
    float aw[64];
#pragma unroll
    for (int i = 0; i < 64; ++i) aw[i] = a_W[i * 64 + lane];
    const float ab = a_b[lane];
    for (int base = idx * 4; base < BB * TT; base += stride4) {
      const int4 q4 = *(const int4*)(question + base);
      const int4 r4 = *(const int4*)(response + base);
      const float4 m4 = *(const float4*)(mask + base);
      const float* __restrict__ v0 = v_emb + ((size_t)q4.x + (size_t)QN * r4.x) * 64;
      const float* __restrict__ v1 = v_emb + ((size_t)q4.y + (size_t)QN * r4.y) * 64;
      const float* __restrict__ v2 = v_emb + ((size_t)q4.z + (size_t)QN * r4.z) * 64;
      const float* __restrict__ v3 = v_emb + ((size_t)q4.w + (size_t)QN * r4.w) * 64;
      float a00 = ab, a01 = 0.f, a10 = ab, a11 = 0.f;
      float a20 = ab, a21 = 0.f, a30 = ab, a31 = 0.f;
#pragma unroll
      for (int i = 0; i < 64; i += 4) {
        const float4 x0 = *(const float4*)(v0 + i);
        const float4 x1 = *(const float4*)(v1 + i);
        const float4 x2 = *(const float4*)(v2 + i);
        const float4 x3 = *(const float4*)(v3 + i);
        a00 = fmaf(x0.x, aw[i], a00);     a01 = fmaf(x0.y, aw[i + 1], a01);
        a00 = fmaf(x0.z, aw[i + 2], a00); a01 = fmaf(x0.w, aw[i + 3], a01);
        a10 = fmaf(x1.x, aw[i], a10);     a11 = fmaf(x1.y, aw[i + 1], a11);
        a10 = fmaf(x1.z, aw[i + 2], a10); a11 = fmaf(x1.w, aw[i + 3], a11);
        a20 = fmaf(x2.x, aw[i], a20);     a21 = fmaf(x2.y, aw[i + 1], a21);
        a20 = fmaf(x2.z, aw[i + 2], a20); a21 = fmaf(x2.w, aw[i + 3], a21);
        a30 = fmaf(x3.x, aw[i], a30);     a31 = fmaf(x3.y, aw[i + 1], a31);
        a30 = fmaf(x3.z, aw[i + 2], a30); a31 = fmaf(x3.w, aw[i + 3], a31);
      }
      const float mf0 = (m4.x == 1.0f) ? 1.0f : 0.0f;
      const float mf1 = (m4.y == 1.0f) ? 1.0f : 0.0f;
      const float mf2 = (m4.z == 1.0f) ? 1.0f : 0.0f;
      const float mf3 = (m4.w == 1.0f) ? 1.0f : 0.0f;
      const float s0 = a00 + a01, s1 = a10 + a11, s2 = a20 + a21, s3 = a30 + a31;
      a_buf[(size_t)(base + 0) * 64 + lane] = mf0 * (1.f - 2.f / (__expf(2.f * s0) + 1.f));
      a_buf[(size_t)(base + 1) * 64 + lane] = mf1 * (1.f - 2.f / (__expf(2.f * s1) + 1.f));
      a_buf[(size_t)(base + 2) * 64 + lane] = mf2 * (1.f - 2.f / (__expf(2.f * s2) + 1.f));
      a_buf[(size_t)(base + 3) * 64 + lane] = mf3 * (1.f - 2.f / (__expf(2.f * s3) + 1.f));
    }
  }
}

// ===========================================================================
// W-tile staging helper (kA16/kC16) -- R12 verbatim.
// ===========================================================================
#define STAGE_W(wl_row, rowbase)                                            \
  {                                                                         \
    const float* __restrict__ wsrc = w_buf + (rowbase) * WPAD;              \
    _Pragma("unroll") for (int k = 0; k < 13; ++k) {                        \
      const int idx = lane + k * 64;               /* 0..831 */             \
      const int row = idx / 52;                                             \
      const int col = idx - row * 52;                                       \
      (wl_row)[row * 56 + col + (col >= 25 ? 3 : 0)] = wsrc[idx];           \
    }                                                                       \
  }

#define LOAD_WM(wm, wl_row, j, g)                                           \
  const float* __restrict__ wj_##j = (wl_row) + (j) * 56 + (g) * 28;        \
  const float4 q0_##j = *(const float4*)(wj_##j + 0);                       \
  const float4 q1_##j = *(const float4*)(wj_##j + 4);                       \
  const float4 q2_##j = *(const float4*)(wj_##j + 8);                       \
  const float4 q3_##j = *(const float4*)(wj_##j + 12);                      \
  const float4 q4_##j = *(const float4*)(wj_##j + 16);                      \
  const float4 q5_##j = *(const float4*)(wj_##j + 20);                      \
  const float4 q6_##j = *(const float4*)(wj_##j + 24);                      \
  const float wm[MG] = {q0_##j.x, q0_##j.y, q0_##j.z, q0_##j.w,             \
                        q1_##j.x, q1_##j.y, q1_##j.z, q1_##j.w,             \
                        q2_##j.x, q2_##j.y, q2_##j.z, q2_##j.w,             \
                        q3_##j.x, q3_##j.y, q3_##j.z, q3_##j.w,             \
                        q4_##j.x, q4_##j.y, q4_##j.z, q4_##j.w,             \
                        q5_##j.x, q5_##j.y, q5_##j.z, q5_##j.w, q6_##j.x};

// ===========================================================================
// kA16: C=32 compose, w from staged LDS. (R15 verbatim)
// ===========================================================================
__global__ __launch_bounds__(256) void kA16(
    const float* __restrict__ w_buf, const float* __restrict__ e_buf,
    const float* __restrict__ a_buf, float* __restrict__ AB) {
  __shared__ float wl[4][16 * 56];                     // 14,336 B
  const int lane = (int)(threadIdx.x & 63);
  const int wslot = __builtin_amdgcn_readfirstlane((int)(threadIdx.x >> 6));
  const int u2 = blockIdx.x * 4 + wslot;
  if (u2 >= BB * 32 * 2) return;
  const int g = u2 & 1;
  const int unit = u2 >> 1;                            // b*32 + c
  const int b = unit >> 5;
  const int c = unit & 31;
  const size_t rowbase = (size_t)b * TT + c * 16;
  const size_t eb0 = rowbase * 64 + lane;

  float ev[16], av[16];
#pragma unroll
  for (int j = 0; j < 16; ++j) {
    ev[j] = e_buf[eb0 + (size_t)j * 64];
    av[j] = a_buf[eb0 + (size_t)j * 64];
  }
  STAGE_W(wl[wslot], rowbase)                          // wave-private: no barrier

  float Am[MG], Bm[MG];
#pragma unroll
  for (int m = 0; m < MG; ++m) { Am[m] = 1.f; Bm[m] = 0.f; }

#pragma unroll
  for (int j = 0; j < 16; ++j) {
    LOAD_WM(wm, wl[wslot], j, g)
#pragma unroll
    for (int m = 0; m < MG; ++m) {
      const float al = fmaf(-wm[m], ev[j], 1.0f);
      const float be = wm[m] * av[j];
      Am[m] *= al;
      Bm[m] = fmaf(Bm[m], al, be);
    }
  }
  float* __restrict__ abp = AB + (size_t)unit * 6400 + (g * MG) * 128 + lane * 2;
#pragma unroll
  for (int m = 0; m < MG; ++m) {
    float2 o; o.x = Am[m]; o.y = Bm[m];
    *(float2*)(abp + m * 128) = o;
  }
}

// ===========================================================================
// kB: sequential over C chunks, parallel over B*M*D. (R15 verbatim)
// ===========================================================================
__global__ __launch_bounds__(256) void kB_entry(
    const float* __restrict__ AB, const float* __restrict__ Mv0,
    float* __restrict__ entry, int C) {
  const int NT = gridDim.x * 256;
  for (int idx = blockIdx.x * 256 + (int)threadIdx.x; idx < BB * MM * 64;
       idx += NT) {
    const int b = idx / (MM * 64);
    const int r = idx - b * (MM * 64);                 // m*64 + d
    float s = Mv0[r];
    const float* __restrict__ abp = AB + (size_t)b * C * 6400 + (size_t)r * 2;
    float* __restrict__ ep = entry + (size_t)b * C * 3200 + r;
    if (C == 32) {
      float2 ab[32];
#pragma unroll
      for (int c = 0; c < 32; ++c)
        ab[c] = *(const float2*)(abp + (size_t)c * 6400);
#pragma unroll
      for (int c = 0; c < 32; ++c) {
        ep[(size_t)c * 3200] = s;
        s = fmaf(ab[c].x, s, ab[c].y);
      }
    } else {
      float2 cur = *(const float2*)(abp);
      for (int c = 0; c < C; ++c) {
        ep[(size_t)c * 3200] = s;
        float2 nxt; nxt.x = 1.f; nxt.y = 0.f;
        if (c + 1 < C) nxt = *(const float2*)(abp + (size_t)(c + 1) * 6400);
        s = fmaf(cur.x, s, cur.y);
        cur = nxt;
      }
    }
  }
}

// ===========================================================================
// kC16sum: C=32 replay; partial read rows go to LDS, pair-summed in-block,
// ONE combined read_buf written (halves read2's 33MB write+read round-trip;
// the two m-group waves of a unit are adjacent wslots in the same block).
// Grid is exactly 1024 blocks x 4 waves = 4096 = BB*32*2 units -> every wave
// handles exactly one unit, and the single __syncthreads is uniform.
// Sum order p0+p1 matches what k3 computed before (bit-identical).
// ===========================================================================
__global__ __launch_bounds__(256) void kC16sum(
    const float* __restrict__ w_buf, const float* __restrict__ e_buf,
    const float* __restrict__ a_buf, const float* __restrict__ entry,
    float* __restrict__ read_buf) {
  __shared__ float wl[4][16 * 56];                     // 14,336 B
  __shared__ float p_lds[4][16][64];                   // 16,384 B
  const int lane = (int)(threadIdx.x & 63);
  const int wslot = __builtin_amdgcn_readfirstlane((int)(threadIdx.x >> 6));
  const int u2 = blockIdx.x * 4 + wslot;               // < 4096 always
  const int g = u2 & 1;
  const int unit = u2 >> 1;                            // b*32 + c
  const int b = unit >> 5;
  const int c = unit & 31;
  const size_t rowbase = (size_t)b * TT + c * 16;
  const size_t eb0 = rowbase * 64 + lane;

  float ev[16], av[16];
#pragma unroll
  for (int j = 0; j < 16; ++j) {
    ev[j] = e_buf[eb0 + (size_t)j * 64];
    av[j] = a_buf[eb0 + (size_t)j * 64];
  }
  float s[MG];
  {
    const float* __restrict__ ep =
        entry + (size_t)unit * 3200 + (g * MG) * 64 + lane;
#pragma unroll
    for (int m = 0; m < MG; ++m) s[m] = ep[m * 64];    // 25 independent loads
  }
  STAGE_W(wl[wslot], rowbase)                          // wave-private: no barrier

#pragma unroll
  for (int j = 0; j < 16; ++j) {
    LOAD_WM(wm, wl[wslot], j, g)
    float a0 = 0.f, a1 = 0.f;
#pragma unroll
    for (int m = 0; m < MG - 1; m += 2) {
      a0 = fmaf(wm[m], s[m], a0);
      a1 = fmaf(wm[m + 1], s[m + 1], a1);
    }
    a0 = fmaf(wm[MG - 1], s[MG - 1], a0);              // MG=25 is odd
    p_lds[wslot][j][lane] = a0 + a1;                   // partial read row
#pragma unroll
    for (int m = 0; m < MG; ++m)
      s[m] = fmaf(wm[m], fmaf(-s[m], ev[j], av[j]), s[m]);
  }
  __syncthreads();                                     // uniform: no returns

  // pair-sum + write: each wave writes 8 of its unit's 16 rows.
  // pair p = wslot>>1 owns unit up = blockIdx*2+p; its partials are in
  // p_lds[2p] (g=0) and p_lds[2p+1] (g=1). This wave writes rows
  // j = g*8 .. g*8+7.
  {
    const int p = wslot >> 1;
    const int uown = blockIdx.x * 2 + p;
    const int ob = uown >> 5;
    const int oc = uown & 31;
    const int t0 = oc * 16;
    const int j0 = (oc == 0 && g == 0) ? 1 : g * 8;    // t=0 emits no read
    const int j1 = g * 8 + 8;
    for (int j = j0; j < j1; ++j) {
      const int t = t0 + j;
      const float r = p_lds[2 * p][j][lane] + p_lds[2 * p + 1][j][lane];
      read_buf[((size_t)ob * (TT - 1) + (t - 1)) * 64 + lane] = r;
    }
  }
}

// ===========================================================================
// Fallback scan kernels (used only if C != 32). (R15 verbatim; write read2
// two-part, consumed by k3_out2.)
// ===========================================================================
__global__ __launch_bounds__(256) void kA_chunk(
    const float* __restrict__ w_buf, const float* __restrict__ e_buf,
    const float* __restrict__ a_buf, float* __restrict__ AB, int logC, int L) {
  const int lane = (int)(threadIdx.x & 63);
  const int wslot = __builtin_amdgcn_readfirstlane((int)(threadIdx.x >> 6));
  const int NW = gridDim.x * 4;
  const int C = 1 << logC;
  for (int u2 = blockIdx.x * 4 + wslot; u2 < BB * C * 2; u2 += NW) {
    const int g = u2 & 1;
    const int unit = u2 >> 1;
    const int b = unit >> logC;
    const int c = unit & (C - 1);
    float Am[MG], Bm[MG];
#pragma unroll
    for (int m = 0; m < MG; ++m) { Am[m] = 1.f; Bm[m] = 0.f; }
    const size_t rowbase = (size_t)b * TT + c * L;
#pragma unroll 2
    for (int j = 0; j < L; ++j) {
      const size_t row = rowbase + j;
      const float ed = e_buf[row * 64 + lane];
      const float ad = a_buf[row * 64 + lane];
      const float* __restrict__ wr = w_buf + row * WPAD + g * MG;
#pragma unroll
      for (int m = 0; m < MG; ++m) {
        const float wm = wr[m];
        const float al = fmaf(-wm, ed, 1.0f);
        const float be = wm * ad;
        Am[m] *= al;
        Bm[m] = fmaf(Bm[m], al, be);
      }
    }
    float* __restrict__ abp = AB + (size_t)unit * 6400 + (g * MG) * 128 + lane * 2;
#pragma unroll
    for (int m = 0; m < MG; ++m) {
      float2 o; o.x = Am[m]; o.y = Bm[m];
      *(float2*)(abp + m * 128) = o;
    }
  }
}

__global__ __launch_bounds__(256) void kC_read(
    const float* __restrict__ w_buf, const float* __restrict__ e_buf,
    const float* __restrict__ a_buf, const float* __restrict__ entry,
    const float* __restrict__ Mv0, float* __restrict__ read2,
    int logC, int L, int use_mv0) {
  const int lane = (int)(threadIdx.x & 63);
  const int wslot = __builtin_amdgcn_readfirstlane((int)(threadIdx.x >> 6));
  const int NW = gridDim.x * 4;
  const int C = 1 << logC;
  const size_t RN = (size_t)BB * (TT - 1) * 64;
  for (int u2 = blockIdx.x * 4 + wslot; u2 < BB * C * 2; u2 += NW) {
    const int g = u2 & 1;
    const int unit = u2 >> 1;
    const int b = unit >> logC;
    const int c = unit & (C - 1);
    float s[MG];
    if (use_mv0) {
#pragma unroll
      for (int m = 0; m < MG; ++m) s[m] = Mv0[(g * MG + m) * 64 + lane];
    } else {
      const float* __restrict__ ep =
          entry + (size_t)unit * 3200 + (g * MG) * 64 + lane;
#pragma unroll
      for (int m = 0; m < MG; ++m) s[m] = ep[m * 64];
    }
    const int t0 = c * L;
    float* __restrict__ rb = read2 + (size_t)g * RN;
    for (int j = 0; j < L; ++j) {
      const int t = t0 + j;
      const size_t row = (size_t)b * TT + t;
      const float ed = e_buf[row * 64 + lane];
      const float ad = a_buf[row * 64 + lane];
      const float* __restrict__ wr = w_buf + row * WPAD + g * MG;
      if (t >= 1) {
        float a0 = 0.f, a1 = 0.f;
#pragma unroll
        for (int m = 0; m < MG - 1; m += 2) {
          a0 = fmaf(wr[m], s[m], a0);
          a1 = fmaf(wr[m + 1], s[m + 1], a1);
        }
        a0 = fmaf(wr[MG - 1], s[MG - 1], a0);
        rb[((size_t)b * (TT - 1) + (t - 1)) * 64 + lane] = a0 + a1;
      }
#pragma unroll
      for (int m = 0; m < MG; ++m)
        s[m] = fmaf(wr[m], fmaf(-s[m], ed, ad), s[m]);
    }
  }
}

// ===========================================================================
// k3_out: wave-pair MLP (R14/R15 structure), SINGLE read_buf input (kC16sum
// pre-sums the partials -> g=0 wave issues ONE load per row, was two).
// ===========================================================================
__global__ __launch_bounds__(256) void k3_out(
    const int* __restrict__ question, const float* __restrict__ k_emb,
    const float* __restrict__ read_buf,
    const float* __restrict__ f_W, const float* __restrict__ f_b,
    const float* __restrict__ p_W, const float* __restrict__ p_b,
    float* __restrict__ out) {
  __shared__ float pbuf[2][2][64];                     // [parity][pair][lane]
  __shared__ float stg[4][64];                         // per-wave staging
  const int lane = (int)(threadIdx.x & 63);
  const int ws = __builtin_amdgcn_readfirstlane((int)(threadIdx.x >> 6));
  const int pair = ws >> 1;                            // 0,1
  const int g = ws & 1;                                // 0: read-half, 1: k-half
  const int NP = gridDim.x * 2;                        // row-workers
  const int R = BB * (TT - 1);
  const int iters = (R + NP - 1) / NP;

  float fw[64];
#pragma unroll
  for (int i = 0; i < 64; ++i) fw[i] = f_W[(g * 64 + i) * 64 + lane];
  PIN(fw, 64)
  const float fb = f_b[lane];
  const float pw = p_W[lane];
  const float pb = p_b[0];

  int row = blockIdx.x * 2 + pair;
  float cur = 0.f;
  if (row < R) {                                       // prologue load
    if (g == 0) {
      cur = read_buf[(size_t)row * 64 + lane];
    } else {
      const int b = row / (TT - 1);
      const int tp = row - b * (TT - 1);
      const int qn = question[b * TT + tp + 1];
      cur = k_emb[(size_t)qn * 64 + lane];
    }
  }
  for (int it = 0; it < iters; ++it) {
    const int nrow = row + NP;
    float nxt = 0.f;
    if (nrow < R) {                                    // issue next-row loads
      if (g == 0) {
        nxt = read_buf[(size_t)nrow * 64 + lane];
      } else {
        const int nb = nrow / (TT - 1);
        const int ntp = nrow - nb * (TT - 1);
        const int nqn = question[nb * TT + ntp + 1];
        nxt = k_emb[(size_t)nqn * 64 + lane];
      }
    }
    const bool active = (row < R);
    float partial = 0.f;
    if (active) {
      stg[ws][lane] = cur;                             // wave-private slot
      float f0 = (g == 0) ? fb : 0.f, f1 = 0.f, f2 = 0.f, f3 = 0.f;
#pragma unroll
      for (int i = 0; i < 64; i += 4) {
        const float4 xv = *(const float4*)&stg[ws][i]; // LDS broadcast
        f0 = fmaf(xv.x, fw[i], f0);
        f1 = fmaf(xv.y, fw[i + 1], f1);
        f2 = fmaf(xv.z, fw[i + 2], f2);
        f3 = fmaf(xv.w, fw[i + 3], f3);
      }
      partial = (f0 + f1) + (f2 + f3);
    }
    const int pr = it & 1;                             // LDS parity dbuf
    if (active && g == 1) pbuf[pr][pair][lane] = partial;
    __syncthreads();
    if (active && g == 0) {
      const float f = partial + pbuf[pr][pair][lane];
      const float t2 = __expf(2.f * f);
      const float fv = 1.f - 2.f / (t2 + 1.f);         // tanh
      float acc = fv * pw;
#pragma unroll
      for (int off = 32; off > 0; off >>= 1) acc += __shfl_xor(acc, off);
      if (lane == 0) out[row] = acc + pb;
    }
    row = nrow; cur = nxt;
  }
}

// ===========================================================================
// k3_out2: fallback-only variant reading the TWO-part read2 (C != 32 path).
// ===========================================================================
__global__ __launch_bounds__(256) void k3_out2(
    const int* __restrict__ question, const float* __restrict__ k_emb,
    const float* __restrict__ read2,
    const float* __restrict__ f_W, const float* __restrict__ f_b,
    const float* __restrict__ p_W, const float* __restrict__ p_b,
    float* __restrict__ out) {
  __shared__ float pbuf[2][2][64];
  __shared__ float stg[4][64];
  const int lane = (int)(threadIdx.x & 63);
  const int ws = __builtin_amdgcn_readfirstlane((int)(threadIdx.x >> 6));
  const int pair = ws >> 1;
  const int g = ws & 1;
  const int NP = gridDim.x * 2;
  const size_t RN = (size_t)BB * (TT - 1) * 64;
  const int R = BB * (TT - 1);
  const int iters = (R + NP - 1) / NP;

  float fw[64];
#pragma unroll
  for (int i = 0; i < 64; ++i) fw[i] = f_W[(g * 64 + i) * 64 + lane];
  PIN(fw, 64)
  const float fb = f_b[lane];
  const float pw = p_W[lane];
  const float pb = p_b[0];

  int row = blockIdx.x * 2 + pair;
  float cur = 0.f;
  if (row < R) {
    if (g == 0) {
      cur = read2[(size_t)row * 64 + lane] + read2[RN + (size_t)row * 64 + lane];
    } else {
      const int b = row / (TT - 1);
      const int tp = row - b * (TT - 1);
      const int qn = question[b * TT + tp + 1];
      cur = k_emb[(size_t)qn * 64 + lane];
    }
  }
  for (int it = 0; it < iters; ++it) {
    const int nrow = row + NP;
    float nxt = 0.f;
    if (nrow < R) {
      if (g == 0) {
        nxt = read2[(size_t)nrow * 64 + lane] +
              read2[RN + (size_t)nrow * 64 + lane];
      } else {
        const int nb = nrow / (TT - 1);
        const int ntp = nrow - nb * (TT - 1);
        const int nqn = question[nb * TT + ntp + 1];
        nxt = k_emb[(size_t)nqn * 64 + lane];
      }
    }
    const bool active = (row < R);
    float partial = 0.f;
    if (active) {
      stg[ws][lane] = cur;
      float f0 = (g == 0) ? fb : 0.f, f1 = 0.f, f2 = 0.f, f3 = 0.f;
#pragma unroll
      for (int i = 0; i < 64; i += 4) {
        const float4 xv = *(const float4*)&stg[ws][i];
        f0 = fmaf(xv.x, fw[i], f0);
        f1 = fmaf(xv.y, fw[i + 1], f1);
        f2 = fmaf(xv.z, fw[i + 2], f2);
        f3 = fmaf(xv.w, fw[i + 3], f3);
      }
      partial = (f0 + f1) + (f2 + f3);
    }
    const int pr = it & 1;
    if (active && g == 1) pbuf[pr][pair][lane] = partial;
    __syncthreads();
    if (active && g == 0) {
      const float f = partial + pbuf[pr][pair][lane];
      const float t2 = __expf(2.f * f);
      const float fv = 1.f - 2.f / (t2 + 1.f);
      float acc = fv * pw;
#pragma unroll
      for (int off = 32; off > 0; off >>= 1) acc += __shfl_xor(acc, off);
      if (lane == 0) out[row] = acc + pb;
    }
    row = nrow; cur = nxt;
  }
}

// ---------------------------------------------------------------------------
extern "C" void kernel_launch(void* const* d_in, const int* in_sizes, int n_in,
                              void* d_out, int out_size, void* d_ws, size_t ws_size,
                              hipStream_t stream) {
  const int*   question = (const int*)d_in[0];
  const int*   response = (const int*)d_in[1];
  const float* mask     = (const float*)d_in[2];
  const float* k_emb    = (const float*)d_in[3];
  const float* v_emb    = (const float*)d_in[4];
  const float* Mk       = (const float*)d_in[5];
  const float* Mv0      = (const float*)d_in[6];
  const float* e_W      = (const float*)d_in[7];
  const float* e_b      = (const float*)d_in[8];
  const float* a_W      = (const float*)d_in[9];
  const float* a_b      = (const float*)d_in[10];
  const float* f_W      = (const float*)d_in[11];
  const float* f_b      = (const float*)d_in[12];
  const float* p_W      = (const float*)d_in[13];
  const float* p_b      = (const float*)d_in[14];
  float* out = (float*)d_out;

  // workspace layout (floats); r2N region holds EITHER the single read_buf
  // (main path, first half) OR the two-part read2 (fallback).
  const size_t wN  = (size_t)BB * TT * WPAD;       // 1,703,936
  const size_t eN  = (size_t)BB * TT * 64;         // 2,097,152
  const size_t r2N = 2ull * BB * (TT - 1) * 64;    // 4,186,112
  float* ws = (float*)d_ws;
  float* w_buf  = ws;
  float* e_buf  = w_buf + wN;
  float* a_buf  = e_buf + eN;
  float* readws = a_buf + eN;                      // read_buf / read2
  float* AB_arr = readws + r2N;
  const size_t baseN = wN + 2 * eN + r2N;          // 10,084,352 floats

  // choose the largest chunk count C that fits the workspace
  int C = 32, logC = 5;
  while (C >= 2) {
    const size_t need = (baseN + 9600ull * BB * C) * sizeof(float);
    if (need <= ws_size) break;
    C >>= 1; logC -= 1;
  }
  int useChunks = (C >= 2);
  if (!useChunks) { C = 1; logC = 0; }
  const int L = TT / C;
  float* entry = AB_arr + 6400ull * BB * C;

  hipLaunchKernelGGL(kPre, dim3(2048), dim3(256), 0, stream,
                     question, response, mask, k_emb, v_emb, Mk,
                     e_W, e_b, a_W, a_b, w_buf, e_buf, a_buf);

  if (C == 32) {
    hipLaunchKernelGGL(kA16, dim3(1024), dim3(256), 0, stream,
                       w_buf, e_buf, a_buf, AB_arr);
    hipLaunchKernelGGL(kB_entry, dim3((BB * MM * 64 + 255) / 256), dim3(256),
                       0, stream, AB_arr, Mv0, entry, C);
    hipLaunchKernelGGL(kC16sum, dim3(1024), dim3(256), 0, stream,
                       w_buf, e_buf, a_buf, entry, readws);
    hipLaunchKernelGGL(k3_out, dim3(1024), dim3(256), 0, stream,
                       question, k_emb, readws, f_W, f_b, p_W, p_b, out);
  } else {
    if (useChunks) {
      const int ublocksA = (BB * C * 2 + 3) / 4;
      hipLaunchKernelGGL(kA_chunk, dim3(ublocksA), dim3(256), 0, stream,
                         w_buf, e_buf, a_buf, AB_arr, logC, L);
      hipLaunchKernelGGL(kB_entry, dim3((BB * MM * 64 + 255) / 256), dim3(256),
                         0, stream, AB_arr, Mv0, entry, C);
    }
    const int ublocksC = (BB * C * 2 + 3) / 4;
    hipLaunchKernelGGL(kC_read, dim3(ublocksC), dim3(256), 0, stream,
                       w_buf, e_buf, a_buf, entry, Mv0, readws,
                       logC, L, useChunks ? 0 : 1);
    hipLaunchKernelGGL(k3_out2, dim3(1024), dim3(256), 0, stream,
                       question, k_emb, readws, f_W, f_b, p_W, p_b, out);
  }
}

// Round 17
// 171.183 us; speedup vs baseline: 1.8149x; 1.0582x over previous
//
#include <hip/hip_runtime.h>
#include <cstddef>

// Problem constants (from reference)
#define QN 10000
#define DD 64
#define MM 50
#define BB 64
#define TT 512
#define WPAD 52   // padded w row stride in floats (208 B -> 16B-aligned rows)
#define MG 25     // m's per wave in the 2-way m-split scan kernels

// Pin a float array in VGPRs (MLP fw only; proven -17us in R9).
#define PIN(arr, n)                                        \
  _Pragma("unroll") for (int _p = 0; _p < (n); ++_p)       \
      asm volatile("" : "+v"((arr)[_p]));

// ===========================================================================
// kPre: R15/R16 version verbatim (rebalanced roles w:e:a = 4:3:3).
// ===========================================================================
__global__ __launch_bounds__(256) void kPre(
    const int* __restrict__ question, const int* __restrict__ response,
    const float* __restrict__ mask,
    const float* __restrict__ k_emb, const float* __restrict__ v_emb,
    const float* __restrict__ Mk,
    const float* __restrict__ e_W, const float* __restrict__ e_b,
    const float* __restrict__ a_W, const float* __restrict__ a_b,
    float* __restrict__ w_buf, float* __restrict__ e_buf,
    float* __restrict__ a_buf) {
  const int lane = (int)(threadIdx.x & 63);
  const int wslot = __builtin_amdgcn_readfirstlane((int)(threadIdx.x >> 6));
  const int gw = blockIdx.x * 4 + wslot;
  const int NW = gridDim.x * 4;
  const int wq = (NW * 2) / 5;            // 40% of waves -> w role
  const int eq = (NW * 3) / 10;           // 30% -> e role
  const int aq = NW - wq - eq;            // 30% -> a role

  if (gw < wq) {                          // ---- role: w (softmax), 4 rows/iter
    const int idx = gw;
    const int stride4 = wq * 4;
    float mk[64];
    const int mrow = lane < MM ? lane : (MM - 1);
#pragma unroll
    for (int i = 0; i < 64; i += 4) {
      const float4 t4 = *(const float4*)(Mk + mrow * 64 + i);
      mk[i] = t4.x; mk[i + 1] = t4.y; mk[i + 2] = t4.z; mk[i + 3] = t4.w;
    }
    for (int base = idx * 4; base < BB * TT; base += stride4) {
      const int4 q4 = *(const int4*)(question + base);   // 4 indices, 1 load
      const float* __restrict__ kr0 = k_emb + (size_t)q4.x * 64;
      const float* __restrict__ kr1 = k_emb + (size_t)q4.y * 64;
      const float* __restrict__ kr2 = k_emb + (size_t)q4.z * 64;
      const float* __restrict__ kr3 = k_emb + (size_t)q4.w * 64;
      float l00=0.f,l01=0.f,l02=0.f,l03=0.f;   // row 0, 4-way split
      float l10=0.f,l11=0.f,l12=0.f,l13=0.f;   // row 1
      float l20=0.f,l21=0.f,l22=0.f,l23=0.f;   // row 2
      float l30=0.f,l31=0.f,l32=0.f,l33=0.f;   // row 3
#pragma unroll
      for (int i = 0; i < 64; i += 4) {
        const float4 k0 = *(const float4*)(kr0 + i);     // 4 independent
        const float4 k1 = *(const float4*)(kr1 + i);     // s_load chains
        const float4 k2 = *(const float4*)(kr2 + i);
        const float4 k3 = *(const float4*)(kr3 + i);
        l00 = fmaf(k0.x, mk[i], l00); l01 = fmaf(k0.y, mk[i+1], l01);
        l02 = fmaf(k0.z, mk[i+2], l02); l03 = fmaf(k0.w, mk[i+3], l03);
        l10 = fmaf(k1.x, mk[i], l10); l11 = fmaf(k1.y, mk[i+1], l11);
        l12 = fmaf(k1.z, mk[i+2], l12); l13 = fmaf(k1.w, mk[i+3], l13);
        l20 = fmaf(k2.x, mk[i], l20); l21 = fmaf(k2.y, mk[i+1], l21);
        l22 = fmaf(k2.z, mk[i+2], l22); l23 = fmaf(k2.w, mk[i+3], l23);
        l30 = fmaf(k3.x, mk[i], l30); l31 = fmaf(k3.y, mk[i+1], l31);
        l32 = fmaf(k3.z, mk[i+2], l32); l33 = fmaf(k3.w, mk[i+3], l33);
      }
      float lm[4];
      lm[0] = (l00 + l01) + (l02 + l03);
      lm[1] = (l10 + l11) + (l12 + l13);
      lm[2] = (l20 + l21) + (l22 + l23);
      lm[3] = (l30 + l31) + (l32 + l33);
#pragma unroll
      for (int r = 0; r < 4; ++r) {
        float lv = (lane < MM) ? lm[r] : -3.4e38f;
#pragma unroll
        for (int off = 32; off > 0; off >>= 1) lv = fmaxf(lv, __shfl_xor(lv, off));
        float pe = (lane < MM) ? __expf(lm[r] - lv) : 0.f;
        float ss = pe;
#pragma unroll
        for (int off = 32; off > 0; off >>= 1) ss += __shfl_xor(ss, off);
        if (lane < MM) w_buf[(size_t)(base + r) * WPAD + lane] = pe / ss;
      }
    }
  } else if (gw < wq + eq) {              // ---- role: e, 4 rows/iter, float4
    const int idx = gw - wq;
    const int stride4 = eq * 4;
    float ew[64];
#pragma unroll
    for (int i = 0; i < 64; ++i) ew[i] = e_W[i * 64 + lane];
    const float eb = e_b[lane];
    for (int base = idx * 4; base < BB * TT; base += stride4) {
      const int4 q4 = *(const int4*)(question + base);
      const int4 r4 = *(const int4*)(response + base);
      const float4 m4 = *(const float4*)(mask + base);
      const float* __restrict__ v0 = v_emb + ((size_t)q4.x + (size_t)QN * r4.x) * 64;
      const float* __restrict__ v1 = v_emb + ((size_t)q4.y + (size_t)QN * r4.y) * 64;
      const float* __restrict__ v2 = v_emb + ((size_t)q4.z + (size_t)QN * r4.z) * 64;
      const float* __restrict__ v3 = v_emb + ((size_t)q4.w + (size_t)QN * r4.w) * 64;
      float e00 = eb, e01 = 0.f, e10 = eb, e11 = 0.f;
      float e20 = eb, e21 = 0.f, e30 = eb, e31 = 0.f;
#pragma unroll
      for (int i = 0; i < 64; i += 4) {
        const float4 a0 = *(const float4*)(v0 + i);      // 4 independent
        const float4 a1 = *(const float4*)(v1 + i);      // s_loadx4 chains
        const float4 a2 = *(const float4*)(v2 + i);
        const float4 a3 = *(const float4*)(v3 + i);
        e00 = fmaf(a0.x, ew[i], e00);     e01 = fmaf(a0.y, ew[i + 1], e01);
        e00 = fmaf(a0.z, ew[i + 2], e00); e01 = fmaf(a0.w, ew[i + 3], e01);
        e10 = fmaf(a1.x, ew[i], e10);     e11 = fmaf(a1.y, ew[i + 1], e11);
        e10 = fmaf(a1.z, ew[i + 2], e10); e11 = fmaf(a1.w, ew[i + 3], e11);
        e20 = fmaf(a2.x, ew[i], e20);     e21 = fmaf(a2.y, ew[i + 1], e21);
        e20 = fmaf(a2.z, ew[i + 2], e20); e21 = fmaf(a2.w, ew[i + 3], e21);
        e30 = fmaf(a3.x, ew[i], e30);     e31 = fmaf(a3.y, ew[i + 1], e31);
        e30 = fmaf(a3.z, ew[i + 2], e30); e31 = fmaf(a3.w, ew[i + 3], e31);
      }
      const float mf0 = (m4.x == 1.0f) ? 1.0f : 0.0f;
      const float mf1 = (m4.y == 1.0f) ? 1.0f : 0.0f;
      const float mf2 = (m4.z == 1.0f) ? 1.0f : 0.0f;
      const float mf3 = (m4.w == 1.0f) ? 1.0f : 0.0f;
      e_buf[(size_t)(base + 0) * 64 + lane] = mf0 / (1.f + __expf(-(e00 + e01)));
      e_buf[(size_t)(base + 1) * 64 + lane] = mf1 / (1.f + __expf(-(e10 + e11)));
      e_buf[(size_t)(base + 2) * 64 + lane] = mf2 / (1.f + __expf(-(e20 + e21)));
      e_buf[(size_t)(base + 3) * 64 + lane] = mf3 / (1.f + __expf(-(e30 + e31)));
    }
  } else {                                // ---- role: a, 4 rows/iter, float4
    const int idx = gw - wq - eq;
    const int stride4 = aq * 4;
    float aw[64];
#pragma unroll
    for (int i = 0; i < 64; ++i) aw[i] = a_W[i * 64 + lane];
    const float ab = a_b[lane];
    for (int base = idx * 4; base < BB * TT; base += stride4) {
      const int4 q4 = *(const int4*)(question + base);
      const int4 r4 = *(const int4*)(response + base);
      const float4 m4 = *(const float4*)(mask + base);
      const float* __restrict__ v0 = v_emb + ((size_t)q4.x + (size_t)QN * r4.x) * 64;
      const float* __restrict__ v1 = v_emb + ((size_t)q4.y + (size_t)QN * r4.y) * 64;
      const float* __restrict__ v2 = v_emb + ((size_t)q4.z + (size_t)QN * r4.z) * 64;
      const float* __restrict__ v3 = v_emb + ((size_t)q4.w + (size_t)QN * r4.w) * 64;
      float a00 = ab, a01 = 0.f, a10 = ab, a11 = 0.f;
      float a20 = ab, a21 = 0.f, a30 = ab, a31 = 0.f;
#pragma unroll
      for (int i = 0; i < 64; i += 4) {
        const float4 x0 = *(const float4*)(v0 + i);
        const float4 x1 = *(const float4*)(v1 + i);
        const float4 x2 = *(const float4*)(v2 + i);
        const float4 x3 = *(const float4*)(v3 + i);
        a00 = fmaf(x0.x, aw[i], a00);     a01 = fmaf(x0.y, aw[i + 1], a01);
        a00 = fmaf(x0.z, aw[i + 2], a00); a01 = fmaf(x0.w, aw[i + 3], a01);
        a10 = fmaf(x1.x, aw[i], a10);     a11 = fmaf(x1.y, aw[i + 1], a11);
        a10 = fmaf(x1.z, aw[i + 2], a10); a11 = fmaf(x1.w, aw[i + 3], a11);
        a20 = fmaf(x2.x, aw[i], a20);     a21 = fmaf(x2.y, aw[i + 1], a21);
        a20 = fmaf(x2.z, aw[i + 2], a20); a21 = fmaf(x2.w, aw[i + 3], a21);
        a30 = fmaf(x3.x, aw[i], a30);     a31 = fmaf(x3.y, aw[i + 1], a31);
        a30 = fmaf(x3.z, aw[i + 2], a30); a31 = fmaf(x3.w, aw[i + 3], a31);
      }
      const float mf0 = (m4.x == 1.0f) ? 1.0f : 0.0f;
      const float mf1 = (m4.y == 1.0f) ? 1.0f : 0.0f;
      const float mf2 = (m4.z == 1.0f) ? 1.0f : 0.0f;
      const float mf3 = (m4.w == 1.0f) ? 1.0f : 0.0f;
      const float s0 = a00 + a01, s1 = a10 + a11, s2 = a20 + a21, s3 = a30 + a31;
      a_buf[(size_t)(base + 0) * 64 + lane] = mf0 * (1.f - 2.f / (__expf(2.f * s0) + 1.f));
      a_buf[(size_t)(base + 1) * 64 + lane] = mf1 * (1.f - 2.f / (__expf(2.f * s1) + 1.f));
      a_buf[(size_t)(base + 2) * 64 + lane] = mf2 * (1.f - 2.f / (__expf(2.f * s2) + 1.f));
      a_buf[(size_t)(base + 3) * 64 + lane] = mf3 * (1.f - 2.f / (__expf(2.f * s3) + 1.f));
    }
  }
}

// ===========================================================================
// W-tile staging helper (kA16/kCD2) -- R12 verbatim.
// ===========================================================================
#define STAGE_W(wl_row, rowbase)                                            \
  {                                                                         \
    const float* __restrict__ wsrc = w_buf + (rowbase) * WPAD;              \
    _Pragma("unroll") for (int k = 0; k < 13; ++k) {                        \
      const int idx = lane + k * 64;               /* 0..831 */             \
      const int row = idx / 52;                                             \
      const int col = idx - row * 52;                                       \
      (wl_row)[row * 56 + col + (col >= 25 ? 3 : 0)] = wsrc[idx];           \
    }                                                                       \
  }

#define LOAD_WM(wm, wl_row, j, g)                                           \
  const float* __restrict__ wj_##j = (wl_row) + (j) * 56 + (g) * 28;        \
  const float4 q0_##j = *(const float4*)(wj_##j + 0);                       \
  const float4 q1_##j = *(const float4*)(wj_##j + 4);                       \
  const float4 q2_##j = *(const float4*)(wj_##j + 8);                       \
  const float4 q3_##j = *(const float4*)(wj_##j + 12);                      \
  const float4 q4_##j = *(const float4*)(wj_##j + 16);                      \
  const float4 q5_##j = *(const float4*)(wj_##j + 20);                      \
  const float4 q6_##j = *(const float4*)(wj_##j + 24);                      \
  const float wm[MG] = {q0_##j.x, q0_##j.y, q0_##j.z, q0_##j.w,             \
                        q1_##j.x, q1_##j.y, q1_##j.z, q1_##j.w,             \
                        q2_##j.x, q2_##j.y, q2_##j.z, q2_##j.w,             \
                        q3_##j.x, q3_##j.y, q3_##j.z, q3_##j.w,             \
                        q4_##j.x, q4_##j.y, q4_##j.z, q4_##j.w,             \
                        q5_##j.x, q5_##j.y, q5_##j.z, q5_##j.w, q6_##j.x};

// ===========================================================================
// kA16: C=32 compose, w from staged LDS. (R16 verbatim)
// ===========================================================================
__global__ __launch_bounds__(256) void kA16(
    const float* __restrict__ w_buf, const float* __restrict__ e_buf,
    const float* __restrict__ a_buf, float* __restrict__ AB) {
  __shared__ float wl[4][16 * 56];                     // 14,336 B
  const int lane = (int)(threadIdx.x & 63);
  const int wslot = __builtin_amdgcn_readfirstlane((int)(threadIdx.x >> 6));
  const int u2 = blockIdx.x * 4 + wslot;
  if (u2 >= BB * 32 * 2) return;
  const int g = u2 & 1;
  const int unit = u2 >> 1;                            // b*32 + c
  const int b = unit >> 5;
  const int c = unit & 31;
  const size_t rowbase = (size_t)b * TT + c * 16;
  const size_t eb0 = rowbase * 64 + lane;

  float ev[16], av[16];
#pragma unroll
  for (int j = 0; j < 16; ++j) {
    ev[j] = e_buf[eb0 + (size_t)j * 64];
    av[j] = a_buf[eb0 + (size_t)j * 64];
  }
  STAGE_W(wl[wslot], rowbase)                          // wave-private: no barrier

  float Am[MG], Bm[MG];
#pragma unroll
  for (int m = 0; m < MG; ++m) { Am[m] = 1.f; Bm[m] = 0.f; }

#pragma unroll
  for (int j = 0; j < 16; ++j) {
    LOAD_WM(wm, wl[wslot], j, g)
#pragma unroll
    for (int m = 0; m < MG; ++m) {
      const float al = fmaf(-wm[m], ev[j], 1.0f);
      const float be = wm[m] * av[j];
      Am[m] *= al;
      Bm[m] = fmaf(Bm[m], al, be);
    }
  }
  float* __restrict__ abp = AB + (size_t)unit * 6400 + (g * MG) * 128 + lane * 2;
#pragma unroll
  for (int m = 0; m < MG; ++m) {
    float2 o; o.x = Am[m]; o.y = Bm[m];
    *(float2*)(abp + m * 128) = o;
  }
}

// ===========================================================================
// kB: sequential over C chunks, parallel over B*M*D. (R16 verbatim)
// ===========================================================================
__global__ __launch_bounds__(256) void kB_entry(
    const float* __restrict__ AB, const float* __restrict__ Mv0,
    float* __restrict__ entry, int C) {
  const int NT = gridDim.x * 256;
  for (int idx = blockIdx.x * 256 + (int)threadIdx.x; idx < BB * MM * 64;
       idx += NT) {
    const int b = idx / (MM * 64);
    const int r = idx - b * (MM * 64);                 // m*64 + d
    float s = Mv0[r];
    const float* __restrict__ abp = AB + (size_t)b * C * 6400 + (size_t)r * 2;
    float* __restrict__ ep = entry + (size_t)b * C * 3200 + r;
    if (C == 32) {
      float2 ab[32];
#pragma unroll
      for (int c = 0; c < 32; ++c)
        ab[c] = *(const float2*)(abp + (size_t)c * 6400);
#pragma unroll
      for (int c = 0; c < 32; ++c) {
        ep[(size_t)c * 3200] = s;
        s = fmaf(ab[c].x, s, ab[c].y);
      }
    } else {
      float2 cur = *(const float2*)(abp);
      for (int c = 0; c < C; ++c) {
        ep[(size_t)c * 3200] = s;
        float2 nxt; nxt.x = 1.f; nxt.y = 0.f;
        if (c + 1 < C) nxt = *(const float2*)(abp + (size_t)(c + 1) * 6400);
        s = fmaf(cur.x, s, cur.y);
        cur = nxt;
      }
    }
  }
}

// ===========================================================================
// kCD2: fused replay + pair-sum + output MLP (kC16sum + k3_out in one
// dispatch -- removes the 33MB read_buf round-trip AND one dispatch gap).
// Phase 1 (scan): kC16sum verbatim; partial read rows -> p_lds; ONE uniform
//   barrier (grid = exactly 1024 blocks x 4 waves = 4096 units, no returns).
// Phase 2 (MLP): R14-proven wave-pair split on the block's OWN 16 rows:
//   pair p owns unit blockIdx*2+p; wave g=0 reads rd = p_lds[2p]+p_lds[2p+1]
//   (LDS, not HBM), g=1 gathers k_emb with 1-deep prefetch; partials
//   exchanged via parity-dbuf pbuf; 16 uniform barriers (same count k3 had).
// NOT the R4 failure (MLP inline in scan loop) nor R7 (role-serialized
// block): scan runs at full width first, MLP is a row-parallel tail whose
// blocks overlap across CUs. Arithmetic bit-identical to R16.
// ===========================================================================
__global__ __launch_bounds__(256) void kCD2(
    const int* __restrict__ question,
    const float* __restrict__ w_buf, const float* __restrict__ e_buf,
    const float* __restrict__ a_buf, const float* __restrict__ entry,
    const float* __restrict__ k_emb,
    const float* __restrict__ f_W, const float* __restrict__ f_b,
    const float* __restrict__ p_W, const float* __restrict__ p_b,
    float* __restrict__ out) {
  __shared__ float wl[4][16 * 56];                     // 14,336 B
  __shared__ float p_lds[4][16][64];                   // 16,384 B
  __shared__ float pbuf[2][2][64];                     // 1,024 B
  __shared__ float stg[4][64];                         // 1,024 B
  const int lane = (int)(threadIdx.x & 63);
  const int wslot = __builtin_amdgcn_readfirstlane((int)(threadIdx.x >> 6));
  const int u2 = blockIdx.x * 4 + wslot;               // < 4096 always
  const int g = u2 & 1;
  const int unit = u2 >> 1;                            // b*32 + c
  const int b = unit >> 5;
  const int c = unit & 31;
  const size_t rowbase = (size_t)b * TT + c * 16;
  const size_t eb0 = rowbase * 64 + lane;

  // ---- phase 1: scan (kC16sum verbatim)
  {
    float ev[16], av[16];
#pragma unroll
    for (int j = 0; j < 16; ++j) {
      ev[j] = e_buf[eb0 + (size_t)j * 64];
      av[j] = a_buf[eb0 + (size_t)j * 64];
    }
    float s[MG];
    const float* __restrict__ ep =
        entry + (size_t)unit * 3200 + (g * MG) * 64 + lane;
#pragma unroll
    for (int m = 0; m < MG; ++m) s[m] = ep[m * 64];    // 25 independent loads
    STAGE_W(wl[wslot], rowbase)                        // wave-private

#pragma unroll
    for (int j = 0; j < 16; ++j) {
      LOAD_WM(wm, wl[wslot], j, g)
      float a0 = 0.f, a1 = 0.f;
#pragma unroll
      for (int m = 0; m < MG - 1; m += 2) {
        a0 = fmaf(wm[m], s[m], a0);
        a1 = fmaf(wm[m + 1], s[m + 1], a1);
      }
      a0 = fmaf(wm[MG - 1], s[MG - 1], a0);            // MG=25 is odd
      p_lds[wslot][j][lane] = a0 + a1;                 // partial read row
#pragma unroll
      for (int m = 0; m < MG; ++m)
        s[m] = fmaf(wm[m], fmaf(-s[m], ev[j], av[j]), s[m]);
    }
  }
  __syncthreads();                                     // uniform: no returns

  // ---- phase 2: wave-pair MLP on this block's 16 rows per pair
  const int p = wslot >> 1;                            // pair 0,1
  const int uown = blockIdx.x * 2 + p;
  const int ob = uown >> 5;
  const int oc = uown & 31;
  const int t0 = oc * 16;

  float fw[64];
#pragma unroll
  for (int i = 0; i < 64; ++i) fw[i] = f_W[(g * 64 + i) * 64 + lane];
  PIN(fw, 64)
  const float fb = f_b[lane];
  const float pw = p_W[lane];
  const float pb = p_b[0];

  float nxt_k = 0.f;
  if (g == 1) {                                        // prefetch row j=0 k
    const int qn = question[(size_t)ob * TT + t0];
    nxt_k = k_emb[(size_t)qn * 64 + lane];
  }
  for (int j = 0; j < 16; ++j) {
    const int t = t0 + j;
    float cur;
    if (g == 0) {
      cur = p_lds[2 * p][j][lane] + p_lds[2 * p + 1][j][lane];  // LDS rd
    } else {
      cur = nxt_k;
      if (j + 1 < 16) {                                // 1-deep k prefetch
        const int qn = question[(size_t)ob * TT + t + 1];
        nxt_k = k_emb[(size_t)qn * 64 + lane];
      }
    }
    stg[wslot][lane] = cur;                            // wave-private slot
    float f0 = (g == 0) ? fb : 0.f, f1 = 0.f, f2 = 0.f, f3 = 0.f;
#pragma unroll
    for (int i = 0; i < 64; i += 4) {
      const float4 xv = *(const float4*)&stg[wslot][i]; // LDS broadcast
      f0 = fmaf(xv.x, fw[i], f0);
      f1 = fmaf(xv.y, fw[i + 1], f1);
      f2 = fmaf(xv.z, fw[i + 2], f2);
      f3 = fmaf(xv.w, fw[i + 3], f3);
    }
    const float partial = (f0 + f1) + (f2 + f3);
    const int pr = j & 1;                              // LDS parity dbuf
    if (g == 1) pbuf[pr][p][lane] = partial;
    __syncthreads();                                   // uniform
    if (g == 0 && t >= 1) {                            // t=0 emits no output
      const float f = partial + pbuf[pr][p][lane];
      const float t2 = __expf(2.f * f);
      const float fv = 1.f - 2.f / (t2 + 1.f);         // tanh
      float acc = fv * pw;
#pragma unroll
      for (int off = 32; off > 0; off >>= 1) acc += __shfl_xor(acc, off);
      if (lane == 0) out[(size_t)ob * (TT - 1) + (t - 1)] = acc + pb;
    }
  }
}

// ===========================================================================
// Fallback scan kernels (used only if C != 32). (R16 verbatim)
// ===========================================================================
__global__ __launch_bounds__(256) void kA_chunk(
    const float* __restrict__ w_buf, const float* __restrict__ e_buf,
    const float* __restrict__ a_buf, float* __restrict__ AB, int logC, int L) {
  const int lane = (int)(threadIdx.x & 63);
  const int wslot = __builtin_amdgcn_readfirstlane((int)(threadIdx.x >> 6));
  const int NW = gridDim.x * 4;
  const int C = 1 << logC;
  for (int u2 = blockIdx.x * 4 + wslot; u2 < BB * C * 2; u2 += NW) {
    const int g = u2 & 1;
    const int unit = u2 >> 1;
    const int b = unit >> logC;
    const int c = unit & (C - 1);
    float Am[MG], Bm[MG];
#pragma unroll
    for (int m = 0; m < MG; ++m) { Am[m] = 1.f; Bm[m] = 0.f; }
    const size_t rowbase = (size_t)b * TT + c * L;
#pragma unroll 2
    for (int j = 0; j < L; ++j) {
      const size_t row = rowbase + j;
      const float ed = e_buf[row * 64 + lane];
      const float ad = a_buf[row * 64 + lane];
      const float* __restrict__ wr = w_buf + row * WPAD + g * MG;
#pragma unroll
      for (int m = 0; m < MG; ++m) {
        const float wm = wr[m];
        const float al = fmaf(-wm, ed, 1.0f);
        const float be = wm * ad;
        Am[m] *= al;
        Bm[m] = fmaf(Bm[m], al, be);
      }
    }
    float* __restrict__ abp = AB + (size_t)unit * 6400 + (g * MG) * 128 + lane * 2;
#pragma unroll
    for (int m = 0; m < MG; ++m) {
      float2 o; o.x = Am[m]; o.y = Bm[m];
      *(float2*)(abp + m * 128) = o;
    }
  }
}

__global__ __launch_bounds__(256) void kC_read(
    const float* __restrict__ w_buf, const float* __restrict__ e_buf,
    const float* __restrict__ a_buf, const float* __restrict__ entry,
    const float* __restrict__ Mv0, float* __restrict__ read2,
    int logC, int L, int use_mv0) {
  const int lane = (int)(threadIdx.x & 63);
  const int wslot = __builtin_amdgcn_readfirstlane((int)(threadIdx.x >> 6));
  const int NW = gridDim.x * 4;
  const int C = 1 << logC;
  const size_t RN = (size_t)BB * (TT - 1) * 64;
  for (int u2 = blockIdx.x * 4 + wslot; u2 < BB * C * 2; u2 += NW) {
    const int g = u2 & 1;
    const int unit = u2 >> 1;
    const int b = unit >> logC;
    const int c = unit & (C - 1);
    float s[MG];
    if (use_mv0) {
#pragma unroll
      for (int m = 0; m < MG; ++m) s[m] = Mv0[(g * MG + m) * 64 + lane];
    } else {
      const float* __restrict__ ep =
          entry + (size_t)unit * 3200 + (g * MG) * 64 + lane;
#pragma unroll
      for (int m = 0; m < MG; ++m) s[m] = ep[m * 64];
    }
    const int t0 = c * L;
    float* __restrict__ rb = read2 + (size_t)g * RN;
    for (int j = 0; j < L; ++j) {
      const int t = t0 + j;
      const size_t row = (size_t)b * TT + t;
      const float ed = e_buf[row * 64 + lane];
      const float ad = a_buf[row * 64 + lane];
      const float* __restrict__ wr = w_buf + row * WPAD + g * MG;
      if (t >= 1) {
        float a0 = 0.f, a1 = 0.f;
#pragma unroll
        for (int m = 0; m < MG - 1; m += 2) {
          a0 = fmaf(wr[m], s[m], a0);
          a1 = fmaf(wr[m + 1], s[m + 1], a1);
        }
        a0 = fmaf(wr[MG - 1], s[MG - 1], a0);
        rb[((size_t)b * (TT - 1) + (t - 1)) * 64 + lane] = a0 + a1;
      }
#pragma unroll
      for (int m = 0; m < MG; ++m)
        s[m] = fmaf(wr[m], fmaf(-s[m], ed, ad), s[m]);
    }
  }
}

// ===========================================================================
// k3_out2: fallback-only MLP reading the TWO-part read2 (C != 32 path).
// ===========================================================================
__global__ __launch_bounds__(256) void k3_out2(
    const int* __restrict__ question, const float* __restrict__ k_emb,
    const float* __restrict__ read2,
    const float* __restrict__ f_W, const float* __restrict__ f_b,
    const float* __restrict__ p_W, const float* __restrict__ p_b,
    float* __restrict__ out) {
  __shared__ float pbuf[2][2][64];
  __shared__ float stg[4][64];
  const int lane = (int)(threadIdx.x & 63);
  const int ws = __builtin_amdgcn_readfirstlane((int)(threadIdx.x >> 6));
  const int pair = ws >> 1;
  const int g = ws & 1;
  const int NP = gridDim.x * 2;
  const size_t RN = (size_t)BB * (TT - 1) * 64;
  const int R = BB * (TT - 1);
  const int iters = (R + NP - 1) / NP;

  float fw[64];
#pragma unroll
  for (int i = 0; i < 64; ++i) fw[i] = f_W[(g * 64 + i) * 64 + lane];
  PIN(fw, 64)
  const float fb = f_b[lane];
  const float pw = p_W[lane];
  const float pb = p_b[0];

  int row = blockIdx.x * 2 + pair;
  float cur = 0.f;
  if (row < R) {
    if (g == 0) {
      cur = read2[(size_t)row * 64 + lane] + read2[RN + (size_t)row * 64 + lane];
    } else {
      const int b = row / (TT - 1);
      const int tp = row - b * (TT - 1);
      const int qn = question[b * TT + tp + 1];
      cur = k_emb[(size_t)qn * 64 + lane];
    }
  }
  for (int it = 0; it < iters; ++it) {
    const int nrow = row + NP;
    float nxt = 0.f;
    if (nrow < R) {
      if (g == 0) {
        nxt = read2[(size_t)nrow * 64 + lane] +
              read2[RN + (size_t)nrow * 64 + lane];
      } else {
        const int nb = nrow / (TT - 1);
        const int ntp = nrow - nb * (TT - 1);
        const int nqn = question[nb * TT + ntp + 1];
        nxt = k_emb[(size_t)nqn * 64 + lane];
      }
    }
    const bool active = (row < R);
    float partial = 0.f;
    if (active) {
      stg[ws][lane] = cur;
      float f0 = (g == 0) ? fb : 0.f, f1 = 0.f, f2 = 0.f, f3 = 0.f;
#pragma unroll
      for (int i = 0; i < 64; i += 4) {
        const float4 xv = *(const float4*)&stg[ws][i];
        f0 = fmaf(xv.x, fw[i], f0);
        f1 = fmaf(xv.y, fw[i + 1], f1);
        f2 = fmaf(xv.z, fw[i + 2], f2);
        f3 = fmaf(xv.w, fw[i + 3], f3);
      }
      partial = (f0 + f1) + (f2 + f3);
    }
    const int pr = it & 1;
    if (active && g == 1) pbuf[pr][pair][lane] = partial;
    __syncthreads();
    if (active && g == 0) {
      const float f = partial + pbuf[pr][pair][lane];
      const float t2 = __expf(2.f * f);
      const float fv = 1.f - 2.f / (t2 + 1.f);
      float acc = fv * pw;
#pragma unroll
      for (int off = 32; off > 0; off >>= 1) acc += __shfl_xor(acc, off);
      if (lane == 0) out[row] = acc + pb;
    }
    row = nrow; cur = nxt;
  }
}

// ---------------------------------------------------------------------------
extern "C" void kernel_launch(void* const* d_in, const int* in_sizes, int n_in,
                              void* d_out, int out_size, void* d_ws, size_t ws_size,
                              hipStream_t stream) {
  const int*   question = (const int*)d_in[0];
  const int*   response = (const int*)d_in[1];
  const float* mask     = (const float*)d_in[2];
  const float* k_emb    = (const float*)d_in[3];
  const float* v_emb    = (const float*)d_in[4];
  const float* Mk       = (const float*)d_in[5];
  const float* Mv0      = (const float*)d_in[6];
  const float* e_W      = (const float*)d_in[7];
  const float* e_b      = (const float*)d_in[8];
  const float* a_W      = (const float*)d_in[9];
  const float* a_b      = (const float*)d_in[10];
  const float* f_W      = (const float*)d_in[11];
  const float* f_b      = (const float*)d_in[12];
  const float* p_W      = (const float*)d_in[13];
  const float* p_b      = (const float*)d_in[14];
  float* out = (float*)d_out;

  // workspace layout (floats); r2N region used only by the fallback path.
  const size_t wN  = (size_t)BB * TT * WPAD;       // 1,703,936
  const size_t eN  = (size_t)BB * TT * 64;         // 2,097,152
  const size_t r2N = 2ull * BB * (TT - 1) * 64;    // 4,186,112
  float* ws = (float*)d_ws;
  float* w_buf  = ws;
  float* e_buf  = w_buf + wN;
  float* a_buf  = e_buf + eN;
  float* readws = a_buf + eN;                      // fallback read2 only
  float* AB_arr = readws + r2N;
  const size_t baseN = wN + 2 * eN + r2N;          // 10,084,352 floats

  // choose the largest chunk count C that fits the workspace
  int C = 32, logC = 5;
  while (C >= 2) {
    const size_t need = (baseN + 9600ull * BB * C) * sizeof(float);
    if (need <= ws_size) break;
    C >>= 1; logC -= 1;
  }
  int useChunks = (C >= 2);
  if (!useChunks) { C = 1; logC = 0; }
  const int L = TT / C;
  float* entry = AB_arr + 6400ull * BB * C;

  hipLaunchKernelGGL(kPre, dim3(2048), dim3(256), 0, stream,
                     question, response, mask, k_emb, v_emb, Mk,
                     e_W, e_b, a_W, a_b, w_buf, e_buf, a_buf);

  if (C == 32) {
    // 4 dispatches: kPre -> kA16 -> kB -> kCD2 (scan+MLP fused)
    hipLaunchKernelGGL(kA16, dim3(1024), dim3(256), 0, stream,
                       w_buf, e_buf, a_buf, AB_arr);
    hipLaunchKernelGGL(kB_entry, dim3((BB * MM * 64 + 255) / 256), dim3(256),
                       0, stream, AB_arr, Mv0, entry, C);
    hipLaunchKernelGGL(kCD2, dim3(1024), dim3(256), 0, stream,
                       question, w_buf, e_buf, a_buf, entry, k_emb,
                       f_W, f_b, p_W, p_b, out);
  } else {
    if (useChunks) {
      const int ublocksA = (BB * C * 2 + 3) / 4;
      hipLaunchKernelGGL(kA_chunk, dim3(ublocksA), dim3(256), 0, stream,
                         w_buf, e_buf, a_buf, AB_arr, logC, L);
      hipLaunchKernelGGL(kB_entry, dim3((BB * MM * 64 + 255) / 256), dim3(256),
                         0, stream, AB_arr, Mv0, entry, C);
    }
    const int ublocksC = (BB * C * 2 + 3) / 4;
    hipLaunchKernelGGL(kC_read, dim3(ublocksC), dim3(256), 0, stream,
                       w_buf, e_buf, a_buf, entry, Mv0, readws,
                       logC, L, useChunks ? 0 : 1);
    hipLaunchKernelGGL(k3_out2, dim3(1024), dim3(256), 0, stream,
                       question, k_emb, readws, f_W, f_b, p_W, p_b, out);
  }
}